// Round 1
// baseline (621.860 us; speedup 1.0000x reference)
//
#include <hip/hip_runtime.h>

#define NN 100000
#define NE 1600000
#define HID 128

typedef float f32x4 __attribute__((ext_vector_type(4)));
typedef __bf16 bf16x8 __attribute__((ext_vector_type(8)));
typedef unsigned short u16x8 __attribute__((ext_vector_type(8)));

static __device__ __forceinline__ unsigned short f2bf(float f) {
  union { float f; unsigned u; } v; v.f = f;
  unsigned u = v.u;
  return (unsigned short)((u + 0x7FFFu + ((u >> 16) & 1u)) >> 16);
}

static __device__ __forceinline__ f32x4 mfma_bf16(u16x8 a, u16x8 b, f32x4 c) {
  return __builtin_amdgcn_mfma_f32_16x16x32_bf16(
      __builtin_bit_cast(bf16x8, a), __builtin_bit_cast(bf16x8, b), c, 0, 0, 0);
}

// edge_index may arrive as int32 or int64 (values < 2^31, little-endian).
static __device__ __forceinline__ int gidx(const int* __restrict__ ei, int is64, long long pos) {
  return is64 ? ei[pos * 2] : ei[pos];
}

// ---------------- dtype detection ----------------
__global__ void k_detect(const int* __restrict__ ei, int* __restrict__ flag) {
  unsigned long long b = __ballot(ei[2 * threadIdx.x + 1] == 0);
  if (threadIdx.x == 0) *flag = (b == ~0ull) ? 1 : 0;
}

// ---------------- encoder: h = relu(x @ W_enc + b_enc), store bf16 ----------------
__global__ __launch_bounds__(256) void k_encoder(const float* __restrict__ x,
    const float* __restrict__ Wenc, const float* __restrict__ benc,
    unsigned short* __restrict__ h) {
  __shared__ unsigned short Wt[128 * 136];    // W^T, bf16, padded
  __shared__ float bsh[128];
  __shared__ unsigned short bounce[4][16 * 136];
  int tid = threadIdx.x;
  for (int idx = tid; idx < 128 * 128; idx += 256) {
    int k = idx >> 7, j = idx & 127;
    Wt[j * 136 + k] = f2bf(Wenc[idx]);
  }
  if (tid < 128) bsh[tid] = benc[tid];
  __syncthreads();

  int wave = tid >> 6, lane = tid & 63;
  int l15 = lane & 15, lg = lane >> 4;
  int rowBase = blockIdx.x * 64 + wave * 16;
  int nodeA = rowBase + l15; if (nodeA > NN - 1) nodeA = NN - 1;

  u16x8 af[4];
#pragma unroll
  for (int kt = 0; kt < 4; ++kt) {
    const float* px = x + (long long)nodeA * HID + kt * 32 + lg * 8;
    f32x4 a0 = *(const f32x4*)px;
    f32x4 a1 = *(const f32x4*)(px + 4);
    u16x8 t;
    t[0] = f2bf(a0[0]); t[1] = f2bf(a0[1]); t[2] = f2bf(a0[2]); t[3] = f2bf(a0[3]);
    t[4] = f2bf(a1[0]); t[5] = f2bf(a1[1]); t[6] = f2bf(a1[2]); t[7] = f2bf(a1[3]);
    af[kt] = t;
  }
  f32x4 zero = {0.f, 0.f, 0.f, 0.f};
  f32x4 acc[8];
#pragma unroll
  for (int nt = 0; nt < 8; ++nt) acc[nt] = zero;
#pragma unroll
  for (int kt = 0; kt < 4; ++kt)
#pragma unroll
    for (int nt = 0; nt < 8; ++nt) {
      u16x8 bfv = *(const u16x8*)&Wt[(nt * 16 + l15) * 136 + kt * 32 + lg * 8];
      acc[nt] = mfma_bf16(af[kt], bfv, acc[nt]);
    }
#pragma unroll
  for (int nt = 0; nt < 8; ++nt) {
    int j = nt * 16 + l15;
    float bj = bsh[j];
#pragma unroll
    for (int r = 0; r < 4; ++r) {
      float v = acc[nt][r] + bj;
      v = v > 0.f ? v : 0.f;
      bounce[wave][(lg * 4 + r) * 136 + j] = f2bf(v);
    }
  }
  __syncthreads();
#pragma unroll
  for (int p = 0; p < 4; ++p) {
    int row = p * 4 + lg;
    int node = rowBase + row;
    if (node < NN) {
      u16x8 v = *(const u16x8*)&bounce[wave][row * 136 + l15 * 8];
      *(u16x8*)&h[(long long)node * HID + l15 * 8] = v;
    }
  }
}

// ---------------- CSR build ----------------
__global__ void k_hist(const int* __restrict__ ei, const int* __restrict__ flag,
                       int* __restrict__ deg) {
  int e = blockIdx.x * 256 + threadIdx.x;
  int is64 = *flag;
  int d = gidx(ei, is64, (long long)NE + e);
  atomicAdd(&deg[d], 1);
}

__global__ __launch_bounds__(1024) void k_scan1(const int* __restrict__ deg,
    int* __restrict__ offs, int* __restrict__ part) {
  __shared__ int sc[1024];
  int t = threadIdx.x;
  int i = blockIdx.x * 1024 + t;
  int v = (i < NN) ? deg[i] : 0;
  sc[t] = v;
  __syncthreads();
  for (int s = 1; s < 1024; s <<= 1) {
    int a = (t >= s) ? sc[t - s] : 0;
    __syncthreads();
    sc[t] += a;
    __syncthreads();
  }
  if (i < NN) offs[i] = sc[t] - v;
  if (t == 1023) part[blockIdx.x] = sc[t];
}

__global__ void k_scan2(const int* __restrict__ part, int* __restrict__ base) {
  __shared__ int sc[128];
  int t = threadIdx.x;
  int v = (t < 98) ? part[t] : 0;
  sc[t] = v;
  __syncthreads();
  for (int s = 1; s < 128; s <<= 1) {
    int a = (t >= s) ? sc[t - s] : 0;
    __syncthreads();
    sc[t] += a;
    __syncthreads();
  }
  if (t < 98) base[t] = sc[t] - v;
}

__global__ __launch_bounds__(1024) void k_scan3(int* __restrict__ offs,
    const int* __restrict__ base, int* __restrict__ cursor) {
  int t = threadIdx.x;
  int i = blockIdx.x * 1024 + t;
  if (i < NN) {
    int o = offs[i] + base[blockIdx.x];
    offs[i] = o;
    cursor[i] = o;
  }
}

__global__ void k_scatter(const int* __restrict__ ei, const float* __restrict__ ea,
                          const int* __restrict__ flag, int* __restrict__ cursor,
                          int* __restrict__ csr_src, float* __restrict__ csr_ea) {
  int e = blockIdx.x * 256 + threadIdx.x;
  int is64 = *flag;
  int s = gidx(ei, is64, e);
  int d = gidx(ei, is64, (long long)NE + e);
  int pos = atomicAdd(&cursor[d], 1);
  csr_src[pos] = s;
  csr_ea[pos] = ea[e];
}

// ---------------- message + segment-min: one node per wave ----------------
__global__ __launch_bounds__(256) void k_msg(const unsigned short* __restrict__ h,
    const float* __restrict__ Wmsg, const float* __restrict__ bmsg,
    const int* __restrict__ offs, const int* __restrict__ deg,
    const int* __restrict__ csr_src, const float* __restrict__ csr_ea,
    unsigned short* __restrict__ agg) {
  __shared__ unsigned short Wt[128 * 136];   // rows 0..127 of W_msg, transposed bf16
  __shared__ float wlast[128];               // W_msg[128][:]  (edge_attr row, fp32)
  __shared__ float bsh[128];
  __shared__ float arow[4][128];
  int tid = threadIdx.x;
  for (int idx = tid; idx < 128 * 128; idx += 256) {
    int k = idx >> 7, j = idx & 127;
    Wt[j * 136 + k] = f2bf(Wmsg[idx]);
  }
  if (tid < 128) { wlast[tid] = Wmsg[128 * 128 + tid]; bsh[tid] = bmsg[tid]; }
  __syncthreads();

  int wave = tid >> 6, lane = tid & 63;
  int l15 = lane & 15, lg = lane >> 4;
  f32x4 zero = {0.f, 0.f, 0.f, 0.f};
  f32x4 big  = {3.0e38f, 3.0e38f, 3.0e38f, 3.0e38f};

  for (int it = 0; it < 4; ++it) {
    int node = blockIdx.x * 16 + wave * 4 + it;
    int dg = deg[node];
    float aggv[8];
    if (dg > 0) {
      int off = offs[node];
      f32x4 rmin[8];
#pragma unroll
      for (int nt = 0; nt < 8; ++nt) rmin[nt] = big;
      int ntile = (dg + 15) >> 4;
      for (int t = 0; t < ntile; ++t) {
        int i = t * 16 + l15; if (i > dg - 1) i = dg - 1;  // pad = duplicate last edge
        int slot = off + i;
        int s = csr_src[slot];
        float eav = csr_ea[slot];
        u16x8 af[4];
#pragma unroll
        for (int kt = 0; kt < 4; ++kt)
          af[kt] = *(const u16x8*)&h[(long long)s * HID + kt * 32 + lg * 8];
        f32x4 acc[8];
#pragma unroll
        for (int nt = 0; nt < 8; ++nt) acc[nt] = zero;
#pragma unroll
        for (int kt = 0; kt < 4; ++kt)
#pragma unroll
          for (int nt = 0; nt < 8; ++nt) {
            u16x8 bfv = *(const u16x8*)&Wt[(nt * 16 + l15) * 136 + kt * 32 + lg * 8];
            acc[nt] = mfma_bf16(af[kt], bfv, acc[nt]);
          }
        // edge_attr rank-1 term (fp32), rows of C tile are edges (lg*4+r)
        float e0 = __shfl(eav, lg * 4 + 0);
        float e1 = __shfl(eav, lg * 4 + 1);
        float e2 = __shfl(eav, lg * 4 + 2);
        float e3 = __shfl(eav, lg * 4 + 3);
#pragma unroll
        for (int nt = 0; nt < 8; ++nt) {
          float w = wlast[nt * 16 + l15];
          acc[nt][0] += e0 * w; acc[nt][1] += e1 * w;
          acc[nt][2] += e2 * w; acc[nt][3] += e3 * w;
          rmin[nt][0] = fminf(rmin[nt][0], acc[nt][0]);
          rmin[nt][1] = fminf(rmin[nt][1], acc[nt][1]);
          rmin[nt][2] = fminf(rmin[nt][2], acc[nt][2]);
          rmin[nt][3] = fminf(rmin[nt][3], acc[nt][3]);
        }
      }
#pragma unroll
      for (int nt = 0; nt < 8; ++nt) {
        float m = fminf(fminf(rmin[nt][0], rmin[nt][1]), fminf(rmin[nt][2], rmin[nt][3]));
        m = fminf(m, __shfl_xor(m, 16));
        m = fminf(m, __shfl_xor(m, 32));
        aggv[nt] = m + bsh[nt * 16 + l15];
      }
    } else {
#pragma unroll
      for (int nt = 0; nt < 8; ++nt) aggv[nt] = 0.f;
    }
    if (lg == 0) {
#pragma unroll
      for (int nt = 0; nt < 8; ++nt) arow[wave][nt * 16 + l15] = aggv[nt];
    }
    // in-wave LDS RAW: compiler inserts lgkmcnt wait
    unsigned short b0 = f2bf(arow[wave][2 * lane]);
    unsigned short b1 = f2bf(arow[wave][2 * lane + 1]);
    unsigned pk = (unsigned)b0 | ((unsigned)b1 << 16);
    *(unsigned*)&agg[(long long)node * HID + 2 * lane] = pk;
  }
}

// ---------------- update + decoder fused ----------------
__global__ __launch_bounds__(256) void k_upd(const unsigned short* __restrict__ h,
    const unsigned short* __restrict__ agg,
    const float* __restrict__ Wupd, const float* __restrict__ bupd,
    const float* __restrict__ Wdec, const float* __restrict__ bdec,
    float* __restrict__ out) {
  __shared__ unsigned short Wt1[128 * 136];
  __shared__ unsigned short Wt2[128 * 136];
  __shared__ float bsh[128];
  __shared__ float wd[128];
  int tid = threadIdx.x;
  for (int idx = tid; idx < 128 * 128; idx += 256) {
    int k = idx >> 7, j = idx & 127;
    Wt1[j * 136 + k] = f2bf(Wupd[idx]);
    Wt2[j * 136 + k] = f2bf(Wupd[128 * 128 + idx]);
  }
  if (tid < 128) { bsh[tid] = bupd[tid]; wd[tid] = Wdec[tid]; }
  __syncthreads();

  int wave = tid >> 6, lane = tid & 63;
  int l15 = lane & 15, lg = lane >> 4;
  int rowBase = blockIdx.x * 64 + wave * 16;
  int nodeA = rowBase + l15; if (nodeA > NN - 1) nodeA = NN - 1;

  u16x8 a1[4], a2[4];
#pragma unroll
  for (int kt = 0; kt < 4; ++kt) {
    a1[kt] = *(const u16x8*)&h[(long long)nodeA * HID + kt * 32 + lg * 8];
    a2[kt] = *(const u16x8*)&agg[(long long)nodeA * HID + kt * 32 + lg * 8];
  }
  f32x4 zero = {0.f, 0.f, 0.f, 0.f};
  f32x4 acc[8];
#pragma unroll
  for (int nt = 0; nt < 8; ++nt) acc[nt] = zero;
#pragma unroll
  for (int kt = 0; kt < 4; ++kt)
#pragma unroll
    for (int nt = 0; nt < 8; ++nt) {
      u16x8 b1 = *(const u16x8*)&Wt1[(nt * 16 + l15) * 136 + kt * 32 + lg * 8];
      acc[nt] = mfma_bf16(a1[kt], b1, acc[nt]);
    }
#pragma unroll
  for (int kt = 0; kt < 4; ++kt)
#pragma unroll
    for (int nt = 0; nt < 8; ++nt) {
      u16x8 b2 = *(const u16x8*)&Wt2[(nt * 16 + l15) * 136 + kt * 32 + lg * 8];
      acc[nt] = mfma_bf16(a2[kt], b2, acc[nt]);
    }
  float ps0 = 0.f, ps1 = 0.f, ps2 = 0.f, ps3 = 0.f;
#pragma unroll
  for (int nt = 0; nt < 8; ++nt) {
    int j = nt * 16 + l15;
    float bu = bsh[j], w = wd[j];
    ps0 += (acc[nt][0] + bu) * w;
    ps1 += (acc[nt][1] + bu) * w;
    ps2 += (acc[nt][2] + bu) * w;
    ps3 += (acc[nt][3] + bu) * w;
  }
#pragma unroll
  for (int m = 1; m < 16; m <<= 1) {
    ps0 += __shfl_xor(ps0, m);
    ps1 += __shfl_xor(ps1, m);
    ps2 += __shfl_xor(ps2, m);
    ps3 += __shfl_xor(ps3, m);
  }
  if (l15 == 0) {
    float bd = *bdec;
    float v0 = 1.f / (1.f + expf(-(ps0 + bd)));
    float v1 = 1.f / (1.f + expf(-(ps1 + bd)));
    float v2 = 1.f / (1.f + expf(-(ps2 + bd)));
    float v3 = 1.f / (1.f + expf(-(ps3 + bd)));
    int n0 = rowBase + lg * 4;
    if (n0 + 3 < NN) {
      float4 st; st.x = v0; st.y = v1; st.z = v2; st.w = v3;
      *(float4*)&out[n0] = st;
    } else {
      if (n0 + 0 < NN) out[n0 + 0] = v0;
      if (n0 + 1 < NN) out[n0 + 1] = v1;
      if (n0 + 2 < NN) out[n0 + 2] = v2;
      if (n0 + 3 < NN) out[n0 + 3] = v3;
    }
  }
}

extern "C" void kernel_launch(void* const* d_in, const int* in_sizes, int n_in,
                              void* d_out, int out_size, void* d_ws, size_t ws_size,
                              hipStream_t stream) {
  const float* x    = (const float*)d_in[0];
  const int*   ei   = (const int*)d_in[1];
  const float* ea   = (const float*)d_in[2];
  const float* Wenc = (const float*)d_in[3];
  const float* benc = (const float*)d_in[4];
  const float* Wmsg = (const float*)d_in[5];
  const float* bmsg = (const float*)d_in[6];
  const float* Wupd = (const float*)d_in[7];
  const float* bupd = (const float*)d_in[8];
  const float* Wdec = (const float*)d_in[9];
  const float* bdec = (const float*)d_in[10];
  float* out = (float*)d_out;

  // workspace carve (total ~65.3 MB)
  char* w = (char*)d_ws;
  auto alloc = [&](size_t bytes) { char* p = w; w += (bytes + 255) & ~(size_t)255; return p; };
  unsigned short* h   = (unsigned short*)alloc((size_t)NN * HID * 2);
  unsigned short* agg = (unsigned short*)alloc((size_t)NN * HID * 2);
  int* deg    = (int*)alloc((size_t)NN * 4);
  int* offs   = (int*)alloc((size_t)NN * 4);
  int* cursor = (int*)alloc((size_t)NN * 4);
  int* part   = (int*)alloc(128 * 4);
  int* base   = (int*)alloc(128 * 4);
  int* flag   = (int*)alloc(256);
  int* csr_src  = (int*)alloc((size_t)NE * 4);
  float* csr_ea = (float*)alloc((size_t)NE * 4);

  k_detect<<<1, 64, 0, stream>>>(ei, flag);
  hipMemsetAsync(deg, 0, (size_t)NN * 4, stream);
  k_encoder<<<(NN + 63) / 64, 256, 0, stream>>>(x, Wenc, benc, h);
  k_hist<<<NE / 256, 256, 0, stream>>>(ei, flag, deg);
  k_scan1<<<98, 1024, 0, stream>>>(deg, offs, part);
  k_scan2<<<1, 128, 0, stream>>>(part, base);
  k_scan3<<<98, 1024, 0, stream>>>(offs, base, cursor);
  k_scatter<<<NE / 256, 256, 0, stream>>>(ei, ea, flag, cursor, csr_src, csr_ea);
  k_msg<<<NN / 16, 256, 0, stream>>>(h, Wmsg, bmsg, offs, deg, csr_src, csr_ea, agg);
  k_upd<<<(NN + 63) / 64, 256, 0, stream>>>(h, agg, Wupd, bupd, Wdec, bdec, out);
}

// Round 3
// 505.610 us; speedup vs baseline: 1.2299x; 1.2299x over previous
//
#include <hip/hip_runtime.h>

#define NN 100000
#define NE 1600000
#define HID 128
#define MSG_T 8   // 16-edge tiles per wave in k_msg

typedef float f32x4 __attribute__((ext_vector_type(4)));
typedef __bf16 bf16x8 __attribute__((ext_vector_type(8)));
typedef unsigned short u16x8 __attribute__((ext_vector_type(8)));

static __device__ __forceinline__ unsigned short f2bf(float f) {
  union { float f; unsigned u; } v; v.f = f;
  unsigned u = v.u;
  return (unsigned short)((u + 0x7FFFu + ((u >> 16) & 1u)) >> 16);
}

static __device__ __forceinline__ f32x4 mfma_bf16(u16x8 a, u16x8 b, f32x4 c) {
  return __builtin_amdgcn_mfma_f32_16x16x32_bf16(
      __builtin_bit_cast(bf16x8, a), __builtin_bit_cast(bf16x8, b), c, 0, 0, 0);
}

// 16-bit monotone code for bf16: unsigned compare == float compare.
// b = bf16 bits. pos -> b|0x8000, neg -> ~b. Sentinel 0xFFFF (= NaN) > all finite.
static __device__ __forceinline__ unsigned enc16_from_f32(float m) {
  // m is an exact bf16 value (min of bf16s) -> low 16 bits of its f32 are zero
  unsigned b = __float_as_uint(m) >> 16;
  return (b & 0x8000u) ? (~b & 0xFFFFu) : (b | 0x8000u);
}
static __device__ __forceinline__ float dec16f(unsigned e) {
  unsigned b = (e & 0x8000u) ? (e & 0x7FFFu) : (~e & 0xFFFFu);
  return __uint_as_float(b << 16);
}

// CAS-min on a u32 holding two independent 16-bit monotone codes (lo=col even, hi=col odd)
static __device__ __forceinline__ void cas_min_pair(unsigned* p, unsigned enc) {
  unsigned cur = *(volatile unsigned*)p;
  while (true) {
    unsigned lo = min(enc & 0xFFFFu, cur & 0xFFFFu);
    unsigned hi = min(enc >> 16, cur >> 16);
    unsigned nw = lo | (hi << 16);
    if (nw == cur) break;                 // nothing to improve
    unsigned prev = atomicCAS(p, cur, nw);
    if (prev == cur) break;               // we won
    cur = prev;                           // retry against fresh value
  }
}

// edge_index may arrive as int32 or int64 (values < 2^31, little-endian).
static __device__ __forceinline__ int gidx(const int* __restrict__ ei, int is64, long long pos) {
  return is64 ? ei[pos * 2] : ei[pos];
}

// ---------------- dtype detection ----------------
__global__ void k_detect(const int* __restrict__ ei, int* __restrict__ flag) {
  unsigned long long b = __ballot(ei[2 * threadIdx.x + 1] == 0);
  if (threadIdx.x == 0) *flag = (b == ~0ull) ? 1 : 0;
}

// ---------------- encoder: h = relu(x @ W_enc + b_enc), store bf16 ----------------
__global__ __launch_bounds__(256) void k_encoder(const float* __restrict__ x,
    const float* __restrict__ Wenc, const float* __restrict__ benc,
    unsigned short* __restrict__ h) {
  __shared__ unsigned short Wt[128 * 136];    // W^T, bf16, padded
  __shared__ float bsh[128];
  __shared__ unsigned short bounce[4][16 * 136];
  int tid = threadIdx.x;
  for (int idx = tid; idx < 128 * 128; idx += 256) {
    int k = idx >> 7, j = idx & 127;
    Wt[j * 136 + k] = f2bf(Wenc[idx]);
  }
  if (tid < 128) bsh[tid] = benc[tid];
  __syncthreads();

  int wave = tid >> 6, lane = tid & 63;
  int l15 = lane & 15, lg = lane >> 4;
  int rowBase = blockIdx.x * 64 + wave * 16;
  int nodeA = rowBase + l15; if (nodeA > NN - 1) nodeA = NN - 1;

  u16x8 af[4];
#pragma unroll
  for (int kt = 0; kt < 4; ++kt) {
    const float* px = x + (long long)nodeA * HID + kt * 32 + lg * 8;
    f32x4 a0 = *(const f32x4*)px;
    f32x4 a1 = *(const f32x4*)(px + 4);
    u16x8 t;
    t[0] = f2bf(a0[0]); t[1] = f2bf(a0[1]); t[2] = f2bf(a0[2]); t[3] = f2bf(a0[3]);
    t[4] = f2bf(a1[0]); t[5] = f2bf(a1[1]); t[6] = f2bf(a1[2]); t[7] = f2bf(a1[3]);
    af[kt] = t;
  }
  f32x4 zero = {0.f, 0.f, 0.f, 0.f};
  f32x4 acc[8];
#pragma unroll
  for (int nt = 0; nt < 8; ++nt) acc[nt] = zero;
#pragma unroll
  for (int kt = 0; kt < 4; ++kt)
#pragma unroll
    for (int nt = 0; nt < 8; ++nt) {
      u16x8 bfv = *(const u16x8*)&Wt[(nt * 16 + l15) * 136 + kt * 32 + lg * 8];
      acc[nt] = mfma_bf16(af[kt], bfv, acc[nt]);
    }
#pragma unroll
  for (int nt = 0; nt < 8; ++nt) {
    int j = nt * 16 + l15;
    float bj = bsh[j];
#pragma unroll
    for (int r = 0; r < 4; ++r) {
      float v = acc[nt][r] + bj;
      v = v > 0.f ? v : 0.f;
      bounce[wave][(lg * 4 + r) * 136 + j] = f2bf(v);
    }
  }
  __syncthreads();
#pragma unroll
  for (int p = 0; p < 4; ++p) {
    int row = p * 4 + lg;
    int node = rowBase + row;
    if (node < NN) {
      u16x8 v = *(const u16x8*)&bounce[wave][row * 136 + l15 * 8];
      *(u16x8*)&h[(long long)node * HID + l15 * 8] = v;
    }
  }
}

// ---------------- CSR build (segment-contiguous, order-free) ----------------
__global__ void k_hist(const int* __restrict__ ei, const int* __restrict__ flag,
                       int* __restrict__ degcur) {
  int e = blockIdx.x * 256 + threadIdx.x;
  int is64 = *flag;
  int d = gidx(ei, is64, (long long)NE + e);
  atomicAdd(&degcur[d], 1);
}

// in-place: degcur[i] becomes this node's base cursor
__global__ void k_assign(int* __restrict__ degcur, int* __restrict__ gc) {
  int i = blockIdx.x * 256 + threadIdx.x;
  if (i < NN) {
    int dgi = degcur[i];
    degcur[i] = atomicAdd(gc, dgi);
  }
}

// pack (src 17b | dst 17b | ea-bf16 16b) into u64 per CSR slot
__global__ void k_scatter(const int* __restrict__ ei, const float* __restrict__ ea,
                          const int* __restrict__ flag, int* __restrict__ degcur,
                          unsigned long long* __restrict__ csr) {
  int e = blockIdx.x * 256 + threadIdx.x;
  int is64 = *flag;
  int s = gidx(ei, is64, e);
  int d = gidx(ei, is64, (long long)NE + e);
  unsigned eab = f2bf(ea[e]);
  unsigned long long pk = (unsigned long long)(unsigned)s
                        | ((unsigned long long)(unsigned)d << 17)
                        | ((unsigned long long)eab << 34);
  int pos = atomicAdd(&degcur[d], 1);
  csr[pos] = pk;
}

// ---------------- edge-parallel message + segmented min + packed CAS-min ----------------
__global__ __launch_bounds__(256) void k_msg(const unsigned short* __restrict__ h,
    const float* __restrict__ Wmsg,
    const unsigned long long* __restrict__ csr, unsigned* __restrict__ aggp) {
  // W_msg rows 0..127 in bf16, chunk-major: chunk cc=k/8, col j, elem e=k%8
  __shared__ unsigned short Wc[16 * 128 * 8];         // 32 KB
  __shared__ float wlast[128];                        // edge_attr row of W_msg (fp32)
  __shared__ int dstsh[4][16];
  __shared__ unsigned short Cst[4][16 * 136];         // bf16 C staging, padded
  int tid = threadIdx.x;
  for (int idx = tid; idx < 128 * 128; idx += 256) {
    int k = idx >> 7, j = idx & 127;
    Wc[((k >> 3) * 128 + j) * 8 + (k & 7)] = f2bf(Wmsg[idx]);
  }
  if (tid < 128) wlast[tid] = Wmsg[128 * 128 + tid];
  __syncthreads();

  int wave = tid >> 6, lane = tid & 63;
  int l15 = lane & 15, lg = lane >> 4;
  f32x4 zero = {0.f, 0.f, 0.f, 0.f};
  int tile0 = (blockIdx.x * 4 + wave) * MSG_T;

  for (int t = 0; t < MSG_T; ++t) {
    int slot = (tile0 + t) * 16 + l15;                 // NE % 16 == 0, no tail
    unsigned long long pk = csr[slot];
    int s = (int)(pk & 0x1FFFFu);
    int d = (int)((pk >> 17) & 0x1FFFFu);
    float eav = __uint_as_float(((unsigned)(pk >> 34) & 0xFFFFu) << 16);
    if (lg == 0) dstsh[wave][l15] = d;
    u16x8 af[4];
#pragma unroll
    for (int kt = 0; kt < 4; ++kt)
      af[kt] = *(const u16x8*)&h[(size_t)s * HID + kt * 32 + lg * 8];
    f32x4 acc[8];
#pragma unroll
    for (int nt = 0; nt < 8; ++nt) acc[nt] = zero;
#pragma unroll
    for (int kt = 0; kt < 4; ++kt)
#pragma unroll
      for (int nt = 0; nt < 8; ++nt) {
        u16x8 bfv = *(const u16x8*)&Wc[((kt * 4 + lg) * 128 + nt * 16 + l15) * 8];
        acc[nt] = mfma_bf16(af[kt], bfv, acc[nt]);
      }
    // edge_attr rank-1 term (fp32); C rows are edges (lg*4+r), col = nt*16+l15
    float e0 = __shfl(eav, lg * 4 + 0);
    float e1 = __shfl(eav, lg * 4 + 1);
    float e2 = __shfl(eav, lg * 4 + 2);
    float e3 = __shfl(eav, lg * 4 + 3);
#pragma unroll
    for (int nt = 0; nt < 8; ++nt) {
      int col = nt * 16 + l15;
      float w = wlast[col];
      Cst[wave][(lg * 4 + 0) * 136 + col] = f2bf(acc[nt][0] + e0 * w);
      Cst[wave][(lg * 4 + 1) * 136 + col] = f2bf(acc[nt][1] + e1 * w);
      Cst[wave][(lg * 4 + 2) * 136 + col] = f2bf(acc[nt][2] + e2 * w);
      Cst[wave][(lg * 4 + 3) * 136 + col] = f2bf(acc[nt][3] + e3 * w);
    }
    // keep the DS writes above strictly before the DS reads below
    __builtin_amdgcn_sched_barrier(0);
    // in-wave segmented column-min over the 16 sorted rows; runs are contiguous.
    // bf16 rounding is monotone => min(round(x)) == round(min(x)).
    int c2 = 2 * lane;                                 // this lane owns cols c2, c2+1
    float m0 = 3.0e38f, m1 = 3.0e38f;
#pragma unroll
    for (int r = 0; r < 16; ++r) {
      unsigned u = *(const unsigned*)&Cst[wave][r * 136 + c2];
      float v0 = __uint_as_float(u << 16);
      float v1 = __uint_as_float(u & 0xFFFF0000u);
      m0 = fminf(m0, v0);
      m1 = fminf(m1, v1);
      int dr = dstsh[wave][r];
      int dn = (r < 15) ? dstsh[wave][r + 1] : -1;     // next tile may continue the run:
      if (dr != dn) {                                  // CAS-min is order-invariant
        unsigned enc = enc16_from_f32(m0) | (enc16_from_f32(m1) << 16);
        cas_min_pair(&aggp[(size_t)dr * 64 + lane], enc);
        m0 = 3.0e38f; m1 = 3.0e38f;
      }
    }
  }
}

// ---------------- update + decoder fused (decodes packed agg, adds b_msg) ----------------
__global__ __launch_bounds__(256) void k_upd(const unsigned short* __restrict__ h,
    const unsigned* __restrict__ aggp, const float* __restrict__ bmsg,
    const float* __restrict__ Wupd, const float* __restrict__ bupd,
    const float* __restrict__ Wdec, const float* __restrict__ bdec,
    float* __restrict__ out) {
  __shared__ unsigned short Wt1[128 * 136];
  __shared__ unsigned short Wt2[128 * 136];
  __shared__ float bsh[128];
  __shared__ float wd[128];
  __shared__ float bmsh[128];
  int tid = threadIdx.x;
  for (int idx = tid; idx < 128 * 128; idx += 256) {
    int k = idx >> 7, j = idx & 127;
    Wt1[j * 136 + k] = f2bf(Wupd[idx]);
    Wt2[j * 136 + k] = f2bf(Wupd[128 * 128 + idx]);
  }
  if (tid < 128) { bsh[tid] = bupd[tid]; wd[tid] = Wdec[tid]; bmsh[tid] = bmsg[tid]; }
  __syncthreads();

  int wave = tid >> 6, lane = tid & 63;
  int l15 = lane & 15, lg = lane >> 4;
  int rowBase = blockIdx.x * 64 + wave * 16;
  int nodeA = rowBase + l15; if (nodeA > NN - 1) nodeA = NN - 1;

  u16x8 a1[4], a2[4];
#pragma unroll
  for (int kt = 0; kt < 4; ++kt)
    a1[kt] = *(const u16x8*)&h[(long long)nodeA * HID + kt * 32 + lg * 8];
  const unsigned* ap = aggp + (size_t)nodeA * 64;
#pragma unroll
  for (int kt = 0; kt < 4; ++kt) {
    int j2 = kt * 16 + lg * 4;                // u32 index; covers cols 2*j2 .. 2*j2+7
    uint4 uq = *(const uint4*)&ap[j2];
    unsigned vv[4] = {uq.x, uq.y, uq.z, uq.w};
    u16x8 tt;
#pragma unroll
    for (int q = 0; q < 4; ++q) {
      unsigned lo = vv[q] & 0xFFFFu, hi = vv[q] >> 16;
      int cl = 2 * (j2 + q);
      float fl = (lo == 0xFFFFu) ? 0.f : (dec16f(lo) + bmsh[cl]);
      float fh = (hi == 0xFFFFu) ? 0.f : (dec16f(hi) + bmsh[cl + 1]);
      tt[2 * q] = f2bf(fl);
      tt[2 * q + 1] = f2bf(fh);
    }
    a2[kt] = tt;
  }
  f32x4 zero = {0.f, 0.f, 0.f, 0.f};
  f32x4 acc[8];
#pragma unroll
  for (int nt = 0; nt < 8; ++nt) acc[nt] = zero;
#pragma unroll
  for (int kt = 0; kt < 4; ++kt)
#pragma unroll
    for (int nt = 0; nt < 8; ++nt) {
      u16x8 b1 = *(const u16x8*)&Wt1[(nt * 16 + l15) * 136 + kt * 32 + lg * 8];
      acc[nt] = mfma_bf16(a1[kt], b1, acc[nt]);
    }
#pragma unroll
  for (int kt = 0; kt < 4; ++kt)
#pragma unroll
    for (int nt = 0; nt < 8; ++nt) {
      u16x8 b2 = *(const u16x8*)&Wt2[(nt * 16 + l15) * 136 + kt * 32 + lg * 8];
      acc[nt] = mfma_bf16(a2[kt], b2, acc[nt]);
    }
  float ps0 = 0.f, ps1 = 0.f, ps2 = 0.f, ps3 = 0.f;
#pragma unroll
  for (int nt = 0; nt < 8; ++nt) {
    int j = nt * 16 + l15;
    float bu = bsh[j], w = wd[j];
    ps0 += (acc[nt][0] + bu) * w;
    ps1 += (acc[nt][1] + bu) * w;
    ps2 += (acc[nt][2] + bu) * w;
    ps3 += (acc[nt][3] + bu) * w;
  }
#pragma unroll
  for (int m = 1; m < 16; m <<= 1) {
    ps0 += __shfl_xor(ps0, m);
    ps1 += __shfl_xor(ps1, m);
    ps2 += __shfl_xor(ps2, m);
    ps3 += __shfl_xor(ps3, m);
  }
  if (l15 == 0) {
    float bd = *bdec;
    float v0 = 1.f / (1.f + expf(-(ps0 + bd)));
    float v1 = 1.f / (1.f + expf(-(ps1 + bd)));
    float v2 = 1.f / (1.f + expf(-(ps2 + bd)));
    float v3 = 1.f / (1.f + expf(-(ps3 + bd)));
    int n0 = rowBase + lg * 4;
    if (n0 + 3 < NN) {
      float4 st; st.x = v0; st.y = v1; st.z = v2; st.w = v3;
      *(float4*)&out[n0] = st;
    } else {
      if (n0 + 0 < NN) out[n0 + 0] = v0;
      if (n0 + 1 < NN) out[n0 + 1] = v1;
      if (n0 + 2 < NN) out[n0 + 2] = v2;
      if (n0 + 3 < NN) out[n0 + 3] = v3;
    }
  }
}

extern "C" void kernel_launch(void* const* d_in, const int* in_sizes, int n_in,
                              void* d_out, int out_size, void* d_ws, size_t ws_size,
                              hipStream_t stream) {
  const float* x    = (const float*)d_in[0];
  const int*   ei   = (const int*)d_in[1];
  const float* ea   = (const float*)d_in[2];
  const float* Wenc = (const float*)d_in[3];
  const float* benc = (const float*)d_in[4];
  const float* Wmsg = (const float*)d_in[5];
  const float* bmsg = (const float*)d_in[6];
  const float* Wupd = (const float*)d_in[7];
  const float* bupd = (const float*)d_in[8];
  const float* Wdec = (const float*)d_in[9];
  const float* bdec = (const float*)d_in[10];
  float* out = (float*)d_out;

  // workspace carve (total ~61.4 MiB — below the empirically-safe 65.2 MB of round 1)
  char* w = (char*)d_ws;
  auto alloc = [&](size_t bytes) { char* p = w; w += (bytes + 255) & ~(size_t)255; return p; };
  unsigned short* h  = (unsigned short*)alloc((size_t)NN * HID * 2);        // 25.6 MB
  unsigned* aggp     = (unsigned*)alloc((size_t)NN * 64 * 4);               // 25.6 MB (2 bf16 codes / u32)
  int* degcur = (int*)alloc((size_t)NN * 4);                                // 0.4 MB
  int* gc     = (int*)alloc(256);
  int* flag   = (int*)alloc(256);
  unsigned long long* csr = (unsigned long long*)alloc((size_t)NE * 8);     // 12.8 MB

  k_detect<<<1, 64, 0, stream>>>(ei, flag);
  hipMemsetAsync(degcur, 0, (size_t)NN * 4, stream);
  hipMemsetAsync(gc, 0, 256, stream);
  hipMemsetAsync(aggp, 0xFF, (size_t)NN * 64 * 4, stream);   // 0xFFFF sentinel per 16-bit cell
  k_encoder<<<(NN + 63) / 64, 256, 0, stream>>>(x, Wenc, benc, h);
  k_hist<<<NE / 256, 256, 0, stream>>>(ei, flag, degcur);
  k_assign<<<(NN + 255) / 256, 256, 0, stream>>>(degcur, gc);
  k_scatter<<<NE / 256, 256, 0, stream>>>(ei, ea, flag, degcur, csr);
  k_msg<<<NE / (16 * 4 * MSG_T), 256, 0, stream>>>(h, Wmsg, csr, aggp);
  k_upd<<<(NN + 63) / 64, 256, 0, stream>>>(h, aggp, bmsg, Wupd, bupd, Wdec, bdec, out);
}

// Round 4
// 381.474 us; speedup vs baseline: 1.6301x; 1.3254x over previous
//
#include <hip/hip_runtime.h>

#define NN 100000
#define NE 1600000
#define HID 128

typedef float f32x4 __attribute__((ext_vector_type(4)));
typedef __bf16 bf16x8 __attribute__((ext_vector_type(8)));
typedef unsigned short u16x8 __attribute__((ext_vector_type(8)));

static __device__ __forceinline__ unsigned short f2bf(float f) {
  union { float f; unsigned u; } v; v.f = f;
  unsigned u = v.u;
  return (unsigned short)((u + 0x7FFFu + ((u >> 16) & 1u)) >> 16);
}

static __device__ __forceinline__ f32x4 mfma_bf16(u16x8 a, u16x8 b, f32x4 c) {
  return __builtin_amdgcn_mfma_f32_16x16x32_bf16(
      __builtin_bit_cast(bf16x8, a), __builtin_bit_cast(bf16x8, b), c, 0, 0, 0);
}

// 16-bit monotone code for bf16 bits: unsigned compare == float compare.
// Sentinel 0xFFFF > all finite codes.
static __device__ __forceinline__ unsigned encB(unsigned b) {
  return (b & 0x8000u) ? (~b & 0xFFFFu) : (b | 0x8000u);
}
static __device__ __forceinline__ float dec16f(unsigned e) {
  unsigned b = (e & 0x8000u) ? (e & 0x7FFFu) : (~e & 0xFFFFu);
  return __uint_as_float(b << 16);
}

// CAS-min on a u32 holding two independent 16-bit monotone codes
static __device__ __forceinline__ void cas_min_pair(unsigned* p, unsigned enc) {
  unsigned cur = *(volatile unsigned*)p;
  while (true) {
    unsigned lo = min(enc & 0xFFFFu, cur & 0xFFFFu);
    unsigned hi = min(enc >> 16, cur >> 16);
    unsigned nw = lo | (hi << 16);
    if (nw == cur) break;
    unsigned prev = atomicCAS(p, cur, nw);
    if (prev == cur) break;
    cur = prev;
  }
}

// edge_index may arrive as int32 or int64 (values < 2^31, little-endian).
static __device__ __forceinline__ int gidx(const int* __restrict__ ei, int is64, long long pos) {
  return is64 ? ei[pos * 2] : ei[pos];
}

// ---------------- dtype detection ----------------
__global__ void k_detect(const int* __restrict__ ei, int* __restrict__ flag) {
  unsigned long long b = __ballot(ei[2 * threadIdx.x + 1] == 0);
  if (threadIdx.x == 0) *flag = (b == ~0ull) ? 1 : 0;
}

// ---------------- encoder + message projection fused ----------------
// h = relu(x @ W_enc + b_enc)  (LDS only);  mN = h @ W_msg[0:128]  (global, bf16)
__global__ __launch_bounds__(512) void k_enc2(const float* __restrict__ x,
    const float* __restrict__ Wenc, const float* __restrict__ benc,
    const float* __restrict__ Wmsg, unsigned short* __restrict__ mN) {
  __shared__ unsigned short WtE[128 * 136];
  __shared__ unsigned short WtM[128 * 136];
  __shared__ float bshE[128];
  __shared__ unsigned short bounce[8][16 * 136];
  int tid = threadIdx.x;
  for (int idx = tid; idx < 128 * 128; idx += 512) {
    int k = idx >> 7, j = idx & 127;
    WtE[j * 136 + k] = f2bf(Wenc[idx]);
    WtM[j * 136 + k] = f2bf(Wmsg[idx]);
  }
  if (tid < 128) bshE[tid] = benc[tid];
  __syncthreads();

  int wave = tid >> 6, lane = tid & 63;
  int l15 = lane & 15, lg = lane >> 4;
  int rowBase = blockIdx.x * 128 + wave * 16;
  int nodeA = rowBase + l15; if (nodeA > NN - 1) nodeA = NN - 1;

  // ---- stage 1: h ----
  u16x8 af[4];
#pragma unroll
  for (int kt = 0; kt < 4; ++kt) {
    const float* px = x + (long long)nodeA * HID + kt * 32 + lg * 8;
    f32x4 a0 = *(const f32x4*)px;
    f32x4 a1 = *(const f32x4*)(px + 4);
    u16x8 t;
    t[0] = f2bf(a0[0]); t[1] = f2bf(a0[1]); t[2] = f2bf(a0[2]); t[3] = f2bf(a0[3]);
    t[4] = f2bf(a1[0]); t[5] = f2bf(a1[1]); t[6] = f2bf(a1[2]); t[7] = f2bf(a1[3]);
    af[kt] = t;
  }
  f32x4 zero = {0.f, 0.f, 0.f, 0.f};
  f32x4 acc[8];
#pragma unroll
  for (int nt = 0; nt < 8; ++nt) acc[nt] = zero;
#pragma unroll
  for (int kt = 0; kt < 4; ++kt)
#pragma unroll
    for (int nt = 0; nt < 8; ++nt) {
      u16x8 bfv = *(const u16x8*)&WtE[(nt * 16 + l15) * 136 + kt * 32 + lg * 8];
      acc[nt] = mfma_bf16(af[kt], bfv, acc[nt]);
    }
#pragma unroll
  for (int nt = 0; nt < 8; ++nt) {
    int j = nt * 16 + l15;
    float bj = bshE[j];
#pragma unroll
    for (int r = 0; r < 4; ++r) {
      float v = acc[nt][r] + bj;
      v = v > 0.f ? v : 0.f;
      bounce[wave][(lg * 4 + r) * 136 + j] = f2bf(v);
    }
  }
  // ---- stage 2: mN = h @ W_msg ----
  u16x8 ha[4];
#pragma unroll
  for (int kt = 0; kt < 4; ++kt)
    ha[kt] = *(const u16x8*)&bounce[wave][l15 * 136 + kt * 32 + lg * 8];
  asm volatile("s_waitcnt lgkmcnt(0)" ::: "memory");
  __builtin_amdgcn_sched_barrier(0);
  f32x4 acc2[8];
#pragma unroll
  for (int nt = 0; nt < 8; ++nt) acc2[nt] = zero;
#pragma unroll
  for (int kt = 0; kt < 4; ++kt)
#pragma unroll
    for (int nt = 0; nt < 8; ++nt) {
      u16x8 bfv = *(const u16x8*)&WtM[(nt * 16 + l15) * 136 + kt * 32 + lg * 8];
      acc2[nt] = mfma_bf16(ha[kt], bfv, acc2[nt]);
    }
#pragma unroll
  for (int nt = 0; nt < 8; ++nt) {
    int j = nt * 16 + l15;
#pragma unroll
    for (int r = 0; r < 4; ++r)
      bounce[wave][(lg * 4 + r) * 136 + j] = f2bf(acc2[nt][r]);
  }
#pragma unroll
  for (int p = 0; p < 4; ++p) {
    int row = p * 4 + lg;
    int node = rowBase + row;
    if (node < NN) {
      u16x8 v = *(const u16x8*)&bounce[wave][row * 136 + l15 * 8];
      *(u16x8*)&mN[(long long)node * HID + l15 * 8] = v;
    }
  }
}

// ---------------- CSR build (segment-contiguous, order-free) ----------------
__global__ void k_hist(const int* __restrict__ ei, const int* __restrict__ flag,
                       int* __restrict__ degcur) {
  int e = blockIdx.x * 256 + threadIdx.x;
  int is64 = *flag;
  int d = gidx(ei, is64, (long long)NE + e);
  atomicAdd(&degcur[d], 1);
}

__global__ void k_assign(int* __restrict__ degcur, int* __restrict__ gc) {
  int i = blockIdx.x * 256 + threadIdx.x;
  if (i < NN) {
    int dgi = degcur[i];
    degcur[i] = atomicAdd(gc, dgi);
  }
}

// pack (src 17b | dst 17b | ea-bf16 16b) into u64 per CSR slot
__global__ void k_scatter(const int* __restrict__ ei, const float* __restrict__ ea,
                          const int* __restrict__ flag, int* __restrict__ degcur,
                          unsigned long long* __restrict__ csr) {
  int e = blockIdx.x * 256 + threadIdx.x;
  int is64 = *flag;
  int s = gidx(ei, is64, e);
  int d = gidx(ei, is64, (long long)NE + e);
  unsigned eab = f2bf(ea[e]);
  unsigned long long pk = (unsigned long long)(unsigned)s
                        | ((unsigned long long)(unsigned)d << 17)
                        | ((unsigned long long)eab << 34);
  int pos = atomicAdd(&degcur[d], 1);
  csr[pos] = pk;
}

// ---------------- edge phase: gather mN[src] + ea*w_last, segmented min, CAS-min ----------------
// One wave owns 256 contiguous CSR slots. All edge control is wave-uniform (scalar);
// each lane owns output cols (2*lane, 2*lane+1) of the running min.
__global__ __launch_bounds__(256) void k_msg(const unsigned* __restrict__ mN32,
    const float* __restrict__ Wmsg,
    const unsigned long long* __restrict__ csr, unsigned* __restrict__ aggp) {
  int lane = threadIdx.x & 63;
  int wv = __builtin_amdgcn_readfirstlane(threadIdx.x >> 6);
  int wid = blockIdx.x * 4 + wv;
  if (wid >= NE / 256) return;
  float wl0 = Wmsg[128 * 128 + 2 * lane];
  float wl1 = Wmsg[128 * 128 + 2 * lane + 1];
  const unsigned long long* pc = csr + (size_t)wid * 256;
  float m0 = 3.0e38f, m1 = 3.0e38f;
  int cur_dst = -1;

  unsigned long long pkA[8], pkB[8];
  unsigned vA[8], vB[8];

#define LOADG(PK, VV, G) do { \
    _Pragma("unroll") for (int i_ = 0; i_ < 8; ++i_) PK[i_] = pc[(G) * 8 + i_]; \
    _Pragma("unroll") for (int i_ = 0; i_ < 8; ++i_) \
      VV[i_] = mN32[(size_t)((unsigned)(PK[i_] & 0x1FFFFu)) * 64 + lane]; \
  } while (0)

#define FLUSHRUN() do { \
    unsigned bb0 = f2bf(m0), bb1 = f2bf(m1); \
    unsigned ee = encB(bb0) | (encB(bb1) << 16); \
    cas_min_pair(&aggp[(size_t)cur_dst * 64 + lane], ee); \
    m0 = 3.0e38f; m1 = 3.0e38f; \
  } while (0)

#define CONSUME(PK, VV) do { \
    _Pragma("unroll") for (int i_ = 0; i_ < 8; ++i_) { \
      int d_ = (int)((PK[i_] >> 17) & 0x1FFFFu); \
      if (d_ != cur_dst) { if (cur_dst >= 0) FLUSHRUN(); cur_dst = d_; } \
      float ea_ = __uint_as_float((unsigned)((PK[i_] >> 34) & 0xFFFFu) << 16); \
      unsigned v_ = VV[i_]; \
      m0 = fminf(m0, fmaf(ea_, wl0, __uint_as_float(v_ << 16))); \
      m1 = fminf(m1, fmaf(ea_, wl1, __uint_as_float(v_ & 0xFFFF0000u))); \
    } \
  } while (0)

  LOADG(pkA, vA, 0);
  for (int g2 = 0; g2 < 16; ++g2) {
    LOADG(pkB, vB, 2 * g2 + 1);
    CONSUME(pkA, vA);
    if (g2 < 15) LOADG(pkA, vA, 2 * g2 + 2);
    CONSUME(pkB, vB);
  }
  FLUSHRUN();
#undef LOADG
#undef FLUSHRUN
#undef CONSUME
}

// ---------------- update + decoder fused (recomputes h from x) ----------------
__global__ __launch_bounds__(512) void k_upd(const float* __restrict__ x,
    const float* __restrict__ Wenc, const float* __restrict__ benc,
    const unsigned* __restrict__ aggp, const float* __restrict__ bmsg,
    const float* __restrict__ Wupd, const float* __restrict__ bupd,
    const float* __restrict__ Wdec, const float* __restrict__ bdec,
    float* __restrict__ out) {
  __shared__ unsigned short WtE[128 * 136];
  __shared__ unsigned short Wt1[128 * 136];
  __shared__ unsigned short Wt2[128 * 136];
  __shared__ float bshE[128];
  __shared__ float bsh[128];
  __shared__ float wd[128];
  __shared__ float bmsh[128];
  __shared__ unsigned short bounce[8][16 * 136];
  int tid = threadIdx.x;
  for (int idx = tid; idx < 128 * 128; idx += 512) {
    int k = idx >> 7, j = idx & 127;
    WtE[j * 136 + k] = f2bf(Wenc[idx]);
    Wt1[j * 136 + k] = f2bf(Wupd[idx]);
    Wt2[j * 136 + k] = f2bf(Wupd[128 * 128 + idx]);
  }
  if (tid < 128) { bshE[tid] = benc[tid]; bsh[tid] = bupd[tid]; wd[tid] = Wdec[tid]; bmsh[tid] = bmsg[tid]; }
  __syncthreads();

  int wave = tid >> 6, lane = tid & 63;
  int l15 = lane & 15, lg = lane >> 4;
  int rowBase = blockIdx.x * 128 + wave * 16;
  int nodeA = rowBase + l15; if (nodeA > NN - 1) nodeA = NN - 1;

  // ---- stage 1: recompute h -> bounce ----
  u16x8 af[4];
#pragma unroll
  for (int kt = 0; kt < 4; ++kt) {
    const float* px = x + (long long)nodeA * HID + kt * 32 + lg * 8;
    f32x4 a0 = *(const f32x4*)px;
    f32x4 a1 = *(const f32x4*)(px + 4);
    u16x8 t;
    t[0] = f2bf(a0[0]); t[1] = f2bf(a0[1]); t[2] = f2bf(a0[2]); t[3] = f2bf(a0[3]);
    t[4] = f2bf(a1[0]); t[5] = f2bf(a1[1]); t[6] = f2bf(a1[2]); t[7] = f2bf(a1[3]);
    af[kt] = t;
  }
  f32x4 zero = {0.f, 0.f, 0.f, 0.f};
  f32x4 acc[8];
#pragma unroll
  for (int nt = 0; nt < 8; ++nt) acc[nt] = zero;
#pragma unroll
  for (int kt = 0; kt < 4; ++kt)
#pragma unroll
    for (int nt = 0; nt < 8; ++nt) {
      u16x8 bfv = *(const u16x8*)&WtE[(nt * 16 + l15) * 136 + kt * 32 + lg * 8];
      acc[nt] = mfma_bf16(af[kt], bfv, acc[nt]);
    }
#pragma unroll
  for (int nt = 0; nt < 8; ++nt) {
    int j = nt * 16 + l15;
    float bj = bshE[j];
#pragma unroll
    for (int r = 0; r < 4; ++r) {
      float v = acc[nt][r] + bj;
      v = v > 0.f ? v : 0.f;
      bounce[wave][(lg * 4 + r) * 136 + j] = f2bf(v);
    }
  }
  // ---- stage 2: u = [h, agg] @ W_upd + b_upd; out = sigmoid(u @ W_dec + b_dec) ----
  u16x8 a1[4], a2[4];
#pragma unroll
  for (int kt = 0; kt < 4; ++kt)
    a1[kt] = *(const u16x8*)&bounce[wave][l15 * 136 + kt * 32 + lg * 8];
  const unsigned* ap = aggp + (size_t)nodeA * 64;
#pragma unroll
  for (int kt = 0; kt < 4; ++kt) {
    int j2 = kt * 16 + lg * 4;
    uint4 uq = *(const uint4*)&ap[j2];
    unsigned vv[4] = {uq.x, uq.y, uq.z, uq.w};
    u16x8 tt;
#pragma unroll
    for (int q = 0; q < 4; ++q) {
      unsigned lo = vv[q] & 0xFFFFu, hi = vv[q] >> 16;
      int cl = 2 * (j2 + q);
      float fl = (lo == 0xFFFFu) ? 0.f : (dec16f(lo) + bmsh[cl]);
      float fh = (hi == 0xFFFFu) ? 0.f : (dec16f(hi) + bmsh[cl + 1]);
      tt[2 * q] = f2bf(fl);
      tt[2 * q + 1] = f2bf(fh);
    }
    a2[kt] = tt;
  }
  f32x4 accu[8];
#pragma unroll
  for (int nt = 0; nt < 8; ++nt) accu[nt] = zero;
#pragma unroll
  for (int kt = 0; kt < 4; ++kt)
#pragma unroll
    for (int nt = 0; nt < 8; ++nt) {
      u16x8 b1 = *(const u16x8*)&Wt1[(nt * 16 + l15) * 136 + kt * 32 + lg * 8];
      accu[nt] = mfma_bf16(a1[kt], b1, accu[nt]);
    }
#pragma unroll
  for (int kt = 0; kt < 4; ++kt)
#pragma unroll
    for (int nt = 0; nt < 8; ++nt) {
      u16x8 b2 = *(const u16x8*)&Wt2[(nt * 16 + l15) * 136 + kt * 32 + lg * 8];
      accu[nt] = mfma_bf16(a2[kt], b2, accu[nt]);
    }
  float ps0 = 0.f, ps1 = 0.f, ps2 = 0.f, ps3 = 0.f;
#pragma unroll
  for (int nt = 0; nt < 8; ++nt) {
    int j = nt * 16 + l15;
    float bu = bsh[j], w = wd[j];
    ps0 += (accu[nt][0] + bu) * w;
    ps1 += (accu[nt][1] + bu) * w;
    ps2 += (accu[nt][2] + bu) * w;
    ps3 += (accu[nt][3] + bu) * w;
  }
#pragma unroll
  for (int m = 1; m < 16; m <<= 1) {
    ps0 += __shfl_xor(ps0, m);
    ps1 += __shfl_xor(ps1, m);
    ps2 += __shfl_xor(ps2, m);
    ps3 += __shfl_xor(ps3, m);
  }
  if (l15 == 0) {
    float bd = *bdec;
    float v0 = 1.f / (1.f + expf(-(ps0 + bd)));
    float v1 = 1.f / (1.f + expf(-(ps1 + bd)));
    float v2 = 1.f / (1.f + expf(-(ps2 + bd)));
    float v3 = 1.f / (1.f + expf(-(ps3 + bd)));
    int n0 = rowBase + lg * 4;
    if (n0 + 3 < NN) {
      float4 st; st.x = v0; st.y = v1; st.z = v2; st.w = v3;
      *(float4*)&out[n0] = st;
    } else {
      if (n0 + 0 < NN) out[n0 + 0] = v0;
      if (n0 + 1 < NN) out[n0 + 1] = v1;
      if (n0 + 2 < NN) out[n0 + 2] = v2;
      if (n0 + 3 < NN) out[n0 + 3] = v3;
    }
  }
}

extern "C" void kernel_launch(void* const* d_in, const int* in_sizes, int n_in,
                              void* d_out, int out_size, void* d_ws, size_t ws_size,
                              hipStream_t stream) {
  const float* x    = (const float*)d_in[0];
  const int*   ei   = (const int*)d_in[1];
  const float* ea   = (const float*)d_in[2];
  const float* Wenc = (const float*)d_in[3];
  const float* benc = (const float*)d_in[4];
  const float* Wmsg = (const float*)d_in[5];
  const float* bmsg = (const float*)d_in[6];
  const float* Wupd = (const float*)d_in[7];
  const float* bupd = (const float*)d_in[8];
  const float* Wdec = (const float*)d_in[9];
  const float* bdec = (const float*)d_in[10];
  float* out = (float*)d_out;

  // workspace carve (total ~61.4 MiB — matches passing round 3)
  char* w = (char*)d_ws;
  auto alloc = [&](size_t bytes) { char* p = w; w += (bytes + 255) & ~(size_t)255; return p; };
  unsigned short* mN = (unsigned short*)alloc((size_t)NN * HID * 2);        // 25.6 MB
  unsigned* aggp     = (unsigned*)alloc((size_t)NN * 64 * 4);               // 25.6 MB
  int* degcur = (int*)alloc((size_t)NN * 4);                                // 0.4 MB
  int* gc     = (int*)alloc(256);
  int* flag   = (int*)alloc(256);
  unsigned long long* csr = (unsigned long long*)alloc((size_t)NE * 8);     // 12.8 MB

  k_detect<<<1, 64, 0, stream>>>(ei, flag);
  hipMemsetAsync(degcur, 0, (size_t)NN * 4, stream);
  hipMemsetAsync(gc, 0, 256, stream);
  hipMemsetAsync(aggp, 0xFF, (size_t)NN * 64 * 4, stream);   // 0xFFFF sentinel per 16-bit cell
  k_enc2<<<(NN + 127) / 128, 512, 0, stream>>>(x, Wenc, benc, Wmsg, mN);
  k_hist<<<NE / 256, 256, 0, stream>>>(ei, flag, degcur);
  k_assign<<<(NN + 255) / 256, 256, 0, stream>>>(degcur, gc);
  k_scatter<<<NE / 256, 256, 0, stream>>>(ei, ea, flag, degcur, csr);
  k_msg<<<(NE / 256 + 3) / 4, 256, 0, stream>>>((const unsigned*)mN, Wmsg, csr, aggp);
  k_upd<<<(NN + 127) / 128, 512, 0, stream>>>(x, Wenc, benc, aggp, bmsg, Wupd, bupd, Wdec, bdec, out);
}

// Round 5
// 243.978 us; speedup vs baseline: 2.5488x; 1.5636x over previous
//
#include <hip/hip_runtime.h>

#define NN 100000
#define NE 1600000
#define HID 128
#define NBUCK 782           // ceil(NN/128)

typedef float f32x4 __attribute__((ext_vector_type(4)));
typedef __bf16 bf16x8 __attribute__((ext_vector_type(8)));
typedef unsigned short u16x8 __attribute__((ext_vector_type(8)));

static __device__ __forceinline__ unsigned short f2bf(float f) {
  union { float f; unsigned u; } v; v.f = f;
  unsigned u = v.u;
  return (unsigned short)((u + 0x7FFFu + ((u >> 16) & 1u)) >> 16);
}

static __device__ __forceinline__ f32x4 mfma_bf16(u16x8 a, u16x8 b, f32x4 c) {
  return __builtin_amdgcn_mfma_f32_16x16x32_bf16(
      __builtin_bit_cast(bf16x8, a), __builtin_bit_cast(bf16x8, b), c, 0, 0, 0);
}

// fp32 monotone code: unsigned compare == float compare. 0xFFFFFFFF = sentinel (> all finite).
static __device__ __forceinline__ unsigned fenc32(float f) {
  unsigned u = __float_as_uint(f);
  return (u >> 31) ? ~u : (u | 0x80000000u);
}
static __device__ __forceinline__ float fdec32(unsigned e) {
  unsigned u = (e & 0x80000000u) ? (e & 0x7FFFFFFFu) : ~e;
  return __uint_as_float(u);
}

// edge_index may arrive as int32 or int64 (values < 2^31, little-endian).
static __device__ __forceinline__ int gidx(const int* __restrict__ ei, int is64, long long pos) {
  return is64 ? ei[pos * 2] : ei[pos];
}

// ---------------- dtype detection ----------------
__global__ void k_detect(const int* __restrict__ ei, int* __restrict__ flag) {
  unsigned long long b = __ballot(ei[2 * threadIdx.x + 1] == 0);
  if (threadIdx.x == 0) *flag = (b == ~0ull) ? 1 : 0;
}

// ---------------- encoder + message projection fused ----------------
// h = relu(x @ W_enc + b_enc)  (LDS only);  mN = h @ W_msg[0:128]  (global, bf16)
__global__ __launch_bounds__(512) void k_enc2(const float* __restrict__ x,
    const float* __restrict__ Wenc, const float* __restrict__ benc,
    const float* __restrict__ Wmsg, unsigned short* __restrict__ mN) {
  __shared__ unsigned short WtE[128 * 136];
  __shared__ unsigned short WtM[128 * 136];
  __shared__ float bshE[128];
  __shared__ unsigned short bounce[8][16 * 136];
  int tid = threadIdx.x;
  for (int idx = tid; idx < 128 * 128; idx += 512) {
    int k = idx >> 7, j = idx & 127;
    WtE[j * 136 + k] = f2bf(Wenc[idx]);
    WtM[j * 136 + k] = f2bf(Wmsg[idx]);
  }
  if (tid < 128) bshE[tid] = benc[tid];
  __syncthreads();

  int wave = tid >> 6, lane = tid & 63;
  int l15 = lane & 15, lg = lane >> 4;
  int rowBase = blockIdx.x * 128 + wave * 16;
  int nodeA = rowBase + l15; if (nodeA > NN - 1) nodeA = NN - 1;

  // ---- stage 1: h ----
  u16x8 af[4];
#pragma unroll
  for (int kt = 0; kt < 4; ++kt) {
    const float* px = x + (long long)nodeA * HID + kt * 32 + lg * 8;
    f32x4 a0 = *(const f32x4*)px;
    f32x4 a1 = *(const f32x4*)(px + 4);
    u16x8 t;
    t[0] = f2bf(a0[0]); t[1] = f2bf(a0[1]); t[2] = f2bf(a0[2]); t[3] = f2bf(a0[3]);
    t[4] = f2bf(a1[0]); t[5] = f2bf(a1[1]); t[6] = f2bf(a1[2]); t[7] = f2bf(a1[3]);
    af[kt] = t;
  }
  f32x4 zero = {0.f, 0.f, 0.f, 0.f};
  f32x4 acc[8];
#pragma unroll
  for (int nt = 0; nt < 8; ++nt) acc[nt] = zero;
#pragma unroll
  for (int kt = 0; kt < 4; ++kt)
#pragma unroll
    for (int nt = 0; nt < 8; ++nt) {
      u16x8 bfv = *(const u16x8*)&WtE[(nt * 16 + l15) * 136 + kt * 32 + lg * 8];
      acc[nt] = mfma_bf16(af[kt], bfv, acc[nt]);
    }
#pragma unroll
  for (int nt = 0; nt < 8; ++nt) {
    int j = nt * 16 + l15;
    float bj = bshE[j];
#pragma unroll
    for (int r = 0; r < 4; ++r) {
      float v = acc[nt][r] + bj;
      v = v > 0.f ? v : 0.f;
      bounce[wave][(lg * 4 + r) * 136 + j] = f2bf(v);
    }
  }
  // ---- stage 2: mN = h @ W_msg ----
  u16x8 ha[4];
#pragma unroll
  for (int kt = 0; kt < 4; ++kt)
    ha[kt] = *(const u16x8*)&bounce[wave][l15 * 136 + kt * 32 + lg * 8];
  asm volatile("s_waitcnt lgkmcnt(0)" ::: "memory");
  __builtin_amdgcn_sched_barrier(0);
  f32x4 acc2[8];
#pragma unroll
  for (int nt = 0; nt < 8; ++nt) acc2[nt] = zero;
#pragma unroll
  for (int kt = 0; kt < 4; ++kt)
#pragma unroll
    for (int nt = 0; nt < 8; ++nt) {
      u16x8 bfv = *(const u16x8*)&WtM[(nt * 16 + l15) * 136 + kt * 32 + lg * 8];
      acc2[nt] = mfma_bf16(ha[kt], bfv, acc2[nt]);
    }
#pragma unroll
  for (int nt = 0; nt < 8; ++nt) {
    int j = nt * 16 + l15;
#pragma unroll
    for (int r = 0; r < 4; ++r)
      bounce[wave][(lg * 4 + r) * 136 + j] = f2bf(acc2[nt][r]);
  }
#pragma unroll
  for (int p = 0; p < 4; ++p) {
    int row = p * 4 + lg;
    int node = rowBase + row;
    if (node < NN) {
      u16x8 v = *(const u16x8*)&bounce[wave][row * 136 + l15 * 8];
      *(u16x8*)&mN[(long long)node * HID + l15 * 8] = v;
    }
  }
}

// ---------------- bucket histogram (LDS pre-aggregated) ----------------
__global__ __launch_bounds__(256) void k_hist(const int* __restrict__ ei,
    const int* __restrict__ flag, int* __restrict__ gh) {
  __shared__ unsigned cnt[NBUCK];
  int tid = threadIdx.x;
  for (int i = tid; i < NBUCK; i += 256) cnt[i] = 0;
  __syncthreads();
  int is64 = *flag;
  long long base = (long long)blockIdx.x * 4096;
  int n = (int)(((long long)NE - base < 4096) ? ((long long)NE - base) : 4096);
  for (int i = tid; i < n; i += 256) {
    int d = gidx(ei, is64, (long long)NE + base + i);
    atomicAdd(&cnt[d >> 7], 1u);
  }
  __syncthreads();
  for (int i = tid; i < NBUCK; i += 256)
    if (cnt[i]) atomicAdd(&gh[i], (int)cnt[i]);
}

// ---------------- scan 782 buckets -> offsets + cursors ----------------
__global__ __launch_bounds__(1024) void k_scan(const int* __restrict__ gh,
    int* __restrict__ offs, int* __restrict__ gcursor) {
  __shared__ int sc[1024];
  int t = threadIdx.x;
  int v = (t < NBUCK) ? gh[t] : 0;
  sc[t] = v;
  __syncthreads();
  for (int s = 1; s < 1024; s <<= 1) {
    int a = (t >= s) ? sc[t - s] : 0;
    __syncthreads();
    sc[t] += a;
    __syncthreads();
  }
  if (t < NBUCK) { int o = sc[t] - v; offs[t] = o; gcursor[t] = o; }
  if (t == NBUCK) offs[NBUCK] = NE;
}

// ---------------- chunk-sorted scatter: runs of ~10 edges appended per bucket ----------------
// entry u64: src(17) | local(7)<<17 | ea_bf16(16)<<24
__global__ __launch_bounds__(256) void k_sortscatter(const int* __restrict__ ei,
    const float* __restrict__ ea, const int* __restrict__ flag,
    int* __restrict__ gcursor, unsigned long long* __restrict__ csr) {
  __shared__ unsigned cnt[NBUCK];
  __shared__ unsigned gbase[NBUCK];
  int tid = threadIdx.x;
  long long base = (long long)blockIdx.x * 8192;
  int n = (int)(((long long)NE - base < 8192) ? ((long long)NE - base) : 8192);
  for (int i = tid; i < NBUCK; i += 256) cnt[i] = 0;
  __syncthreads();
  int is64 = *flag;
  // pass 1: count this chunk's bucket sizes
  for (int i = tid; i < n; i += 256) {
    int d = gidx(ei, is64, (long long)NE + base + i);
    atomicAdd(&cnt[d >> 7], 1u);
  }
  __syncthreads();
  // claim contiguous runs
  for (int b = tid; b < NBUCK; b += 256) {
    unsigned c = cnt[b];
    gbase[b] = c ? (unsigned)atomicAdd(&gcursor[b], (int)c) : 0u;
  }
  __syncthreads();
  for (int i = tid; i < NBUCK; i += 256) cnt[i] = 0;   // reuse as local cursor
  __syncthreads();
  // pass 2: write entries into the claimed runs
  for (int i = tid; i < n; i += 256) {
    int s = gidx(ei, is64, base + i);
    int d = gidx(ei, is64, (long long)NE + base + i);
    unsigned eab = f2bf(ea[base + i]);
    int b = d >> 7;
    unsigned lp = atomicAdd(&cnt[b], 1u);
    csr[gbase[b] + lp] = (unsigned long long)(unsigned)s
                       | ((unsigned long long)(unsigned)(d & 127) << 17)
                       | ((unsigned long long)eab << 24);
  }
}

// ---------------- bucket-LDS message + segment-min ----------------
// One block owns 128 destination nodes; min-state is fp32-monotone codes in LDS.
__global__ __launch_bounds__(512) void k_msg(const unsigned* __restrict__ mN32,
    const float* __restrict__ Wmsg, const int* __restrict__ offs,
    const unsigned long long* __restrict__ csr, const float* __restrict__ bmsg,
    unsigned short* __restrict__ agg) {
  __shared__ unsigned st[128 * 128];     // 64 KB
  __shared__ float bmsh[128];
  int tid = threadIdx.x;
  int b = blockIdx.x;
  for (int i = tid; i < 128 * 128; i += 512) st[i] = 0xFFFFFFFFu;
  if (tid < 128) bmsh[tid] = bmsg[tid];
  __syncthreads();

  int lane = tid & 63;
  int wv = tid >> 6;                     // 0..7
  int off = offs[b], end = offs[b + 1];
  int cntE = end - off;
  int per = (cntE + 7) >> 3;
  int i0 = off + wv * per;
  int i1 = i0 + per; if (i1 > end) i1 = end;
  float wl0 = Wmsg[128 * 128 + 2 * lane];
  float wl1 = Wmsg[128 * 128 + 2 * lane + 1];
  unsigned* st0 = &st[2 * lane];

  int i = i0;
  for (; i + 8 <= i1; i += 8) {
    unsigned long long pk[8];
    unsigned v[8];
#pragma unroll
    for (int j = 0; j < 8; ++j) pk[j] = csr[i + j];
#pragma unroll
    for (int j = 0; j < 8; ++j)
      v[j] = mN32[(size_t)(unsigned)(pk[j] & 0x1FFFFu) * 64 + lane];
#pragma unroll
    for (int j = 0; j < 8; ++j) {
      int loc = (int)((pk[j] >> 17) & 0x7Fu);
      float eav = __uint_as_float((unsigned)((pk[j] >> 24) & 0xFFFFu) << 16);
      float v0 = fmaf(eav, wl0, __uint_as_float(v[j] << 16));
      float v1 = fmaf(eav, wl1, __uint_as_float(v[j] & 0xFFFF0000u));
      atomicMin(&st0[loc * 128], fenc32(v0));
      atomicMin(&st0[loc * 128 + 1], fenc32(v1));
    }
  }
  for (; i < i1; ++i) {
    unsigned long long pk = csr[i];
    unsigned v = mN32[(size_t)(unsigned)(pk & 0x1FFFFu) * 64 + lane];
    int loc = (int)((pk >> 17) & 0x7Fu);
    float eav = __uint_as_float((unsigned)((pk >> 24) & 0xFFFFu) << 16);
    float v0 = fmaf(eav, wl0, __uint_as_float(v << 16));
    float v1 = fmaf(eav, wl1, __uint_as_float(v & 0xFFFF0000u));
    atomicMin(&st0[loc * 128], fenc32(v0));
    atomicMin(&st0[loc * 128 + 1], fenc32(v1));
  }
  __syncthreads();

  // finalize: decode + b_msg, write agg bf16 coalesced
  int node0 = b << 7;
  int nd = tid >> 2;
  int cg = (tid & 3) << 5;
  if (node0 + nd < NN) {
#pragma unroll
    for (int c0 = 0; c0 < 32; c0 += 8) {
      u16x8 o;
#pragma unroll
      for (int j = 0; j < 8; ++j) {
        unsigned e = st[nd * 128 + cg + c0 + j];
        float f = (e == 0xFFFFFFFFu) ? 0.f : (fdec32(e) + bmsh[cg + c0 + j]);
        o[j] = f2bf(f);
      }
      *(u16x8*)&agg[(size_t)(node0 + nd) * HID + cg + c0] = o;
    }
  }
}

// ---------------- update + decoder fused (recomputes h from x; agg is plain bf16) ----------------
__global__ __launch_bounds__(512) void k_upd(const float* __restrict__ x,
    const float* __restrict__ Wenc, const float* __restrict__ benc,
    const unsigned short* __restrict__ agg,
    const float* __restrict__ Wupd, const float* __restrict__ bupd,
    const float* __restrict__ Wdec, const float* __restrict__ bdec,
    float* __restrict__ out) {
  __shared__ unsigned short WtE[128 * 136];
  __shared__ unsigned short Wt1[128 * 136];
  __shared__ unsigned short Wt2[128 * 136];
  __shared__ float bshE[128];
  __shared__ float bsh[128];
  __shared__ float wd[128];
  __shared__ unsigned short bounce[8][16 * 136];
  int tid = threadIdx.x;
  for (int idx = tid; idx < 128 * 128; idx += 512) {
    int k = idx >> 7, j = idx & 127;
    WtE[j * 136 + k] = f2bf(Wenc[idx]);
    Wt1[j * 136 + k] = f2bf(Wupd[idx]);
    Wt2[j * 136 + k] = f2bf(Wupd[128 * 128 + idx]);
  }
  if (tid < 128) { bshE[tid] = benc[tid]; bsh[tid] = bupd[tid]; wd[tid] = Wdec[tid]; }
  __syncthreads();

  int wave = tid >> 6, lane = tid & 63;
  int l15 = lane & 15, lg = lane >> 4;
  int rowBase = blockIdx.x * 128 + wave * 16;
  int nodeA = rowBase + l15; if (nodeA > NN - 1) nodeA = NN - 1;

  // ---- stage 1: recompute h -> bounce ----
  u16x8 af[4];
#pragma unroll
  for (int kt = 0; kt < 4; ++kt) {
    const float* px = x + (long long)nodeA * HID + kt * 32 + lg * 8;
    f32x4 a0 = *(const f32x4*)px;
    f32x4 a1 = *(const f32x4*)(px + 4);
    u16x8 t;
    t[0] = f2bf(a0[0]); t[1] = f2bf(a0[1]); t[2] = f2bf(a0[2]); t[3] = f2bf(a0[3]);
    t[4] = f2bf(a1[0]); t[5] = f2bf(a1[1]); t[6] = f2bf(a1[2]); t[7] = f2bf(a1[3]);
    af[kt] = t;
  }
  f32x4 zero = {0.f, 0.f, 0.f, 0.f};
  f32x4 acc[8];
#pragma unroll
  for (int nt = 0; nt < 8; ++nt) acc[nt] = zero;
#pragma unroll
  for (int kt = 0; kt < 4; ++kt)
#pragma unroll
    for (int nt = 0; nt < 8; ++nt) {
      u16x8 bfv = *(const u16x8*)&WtE[(nt * 16 + l15) * 136 + kt * 32 + lg * 8];
      acc[nt] = mfma_bf16(af[kt], bfv, acc[nt]);
    }
#pragma unroll
  for (int nt = 0; nt < 8; ++nt) {
    int j = nt * 16 + l15;
    float bj = bshE[j];
#pragma unroll
    for (int r = 0; r < 4; ++r) {
      float v = acc[nt][r] + bj;
      v = v > 0.f ? v : 0.f;
      bounce[wave][(lg * 4 + r) * 136 + j] = f2bf(v);
    }
  }
  // ---- stage 2: u = [h, agg] @ W_upd + b_upd; out = sigmoid(u @ W_dec + b_dec) ----
  u16x8 a1[4], a2[4];
#pragma unroll
  for (int kt = 0; kt < 4; ++kt)
    a1[kt] = *(const u16x8*)&bounce[wave][l15 * 136 + kt * 32 + lg * 8];
#pragma unroll
  for (int kt = 0; kt < 4; ++kt)
    a2[kt] = *(const u16x8*)&agg[(size_t)nodeA * HID + kt * 32 + lg * 8];
  asm volatile("s_waitcnt lgkmcnt(0)" ::: "memory");
  __builtin_amdgcn_sched_barrier(0);
  f32x4 accu[8];
#pragma unroll
  for (int nt = 0; nt < 8; ++nt) accu[nt] = zero;
#pragma unroll
  for (int kt = 0; kt < 4; ++kt)
#pragma unroll
    for (int nt = 0; nt < 8; ++nt) {
      u16x8 b1 = *(const u16x8*)&Wt1[(nt * 16 + l15) * 136 + kt * 32 + lg * 8];
      accu[nt] = mfma_bf16(a1[kt], b1, accu[nt]);
    }
#pragma unroll
  for (int kt = 0; kt < 4; ++kt)
#pragma unroll
    for (int nt = 0; nt < 8; ++nt) {
      u16x8 b2 = *(const u16x8*)&Wt2[(nt * 16 + l15) * 136 + kt * 32 + lg * 8];
      accu[nt] = mfma_bf16(a2[kt], b2, accu[nt]);
    }
  float ps0 = 0.f, ps1 = 0.f, ps2 = 0.f, ps3 = 0.f;
#pragma unroll
  for (int nt = 0; nt < 8; ++nt) {
    int j = nt * 16 + l15;
    float bu = bsh[j], w = wd[j];
    ps0 += (accu[nt][0] + bu) * w;
    ps1 += (accu[nt][1] + bu) * w;
    ps2 += (accu[nt][2] + bu) * w;
    ps3 += (accu[nt][3] + bu) * w;
  }
#pragma unroll
  for (int m = 1; m < 16; m <<= 1) {
    ps0 += __shfl_xor(ps0, m);
    ps1 += __shfl_xor(ps1, m);
    ps2 += __shfl_xor(ps2, m);
    ps3 += __shfl_xor(ps3, m);
  }
  if (l15 == 0) {
    float bd = *bdec;
    float v0 = 1.f / (1.f + expf(-(ps0 + bd)));
    float v1 = 1.f / (1.f + expf(-(ps1 + bd)));
    float v2 = 1.f / (1.f + expf(-(ps2 + bd)));
    float v3 = 1.f / (1.f + expf(-(ps3 + bd)));
    int n0 = rowBase + lg * 4;
    if (n0 + 3 < NN) {
      float4 st4; st4.x = v0; st4.y = v1; st4.z = v2; st4.w = v3;
      *(float4*)&out[n0] = st4;
    } else {
      if (n0 + 0 < NN) out[n0 + 0] = v0;
      if (n0 + 1 < NN) out[n0 + 1] = v1;
      if (n0 + 2 < NN) out[n0 + 2] = v2;
      if (n0 + 3 < NN) out[n0 + 3] = v3;
    }
  }
}

extern "C" void kernel_launch(void* const* d_in, const int* in_sizes, int n_in,
                              void* d_out, int out_size, void* d_ws, size_t ws_size,
                              hipStream_t stream) {
  const float* x    = (const float*)d_in[0];
  const int*   ei   = (const int*)d_in[1];
  const float* ea   = (const float*)d_in[2];
  const float* Wenc = (const float*)d_in[3];
  const float* benc = (const float*)d_in[4];
  const float* Wmsg = (const float*)d_in[5];
  const float* bmsg = (const float*)d_in[6];
  const float* Wupd = (const float*)d_in[7];
  const float* bupd = (const float*)d_in[8];
  const float* Wdec = (const float*)d_in[9];
  const float* bdec = (const float*)d_in[10];
  float* out = (float*)d_out;

  // workspace carve (total ~64.0 MiB, below the empirically-safe 65.2 MB)
  char* w = (char*)d_ws;
  auto alloc = [&](size_t bytes) { char* p = w; w += (bytes + 255) & ~(size_t)255; return p; };
  unsigned short* mN  = (unsigned short*)alloc((size_t)NN * HID * 2);       // 25.6 MB
  unsigned short* agg = (unsigned short*)alloc((size_t)NN * HID * 2);       // 25.6 MB
  unsigned long long* csr = (unsigned long long*)alloc((size_t)NE * 8);     // 12.8 MB
  int* gh      = (int*)alloc((size_t)NBUCK * 4);
  int* offs    = (int*)alloc((size_t)(NBUCK + 1) * 4);
  int* gcursor = (int*)alloc((size_t)NBUCK * 4);
  int* flag    = (int*)alloc(256);

  k_detect<<<1, 64, 0, stream>>>(ei, flag);
  hipMemsetAsync(gh, 0, (size_t)NBUCK * 4, stream);
  k_enc2<<<(NN + 127) / 128, 512, 0, stream>>>(x, Wenc, benc, Wmsg, mN);
  k_hist<<<(NE + 4095) / 4096, 256, 0, stream>>>(ei, flag, gh);
  k_scan<<<1, 1024, 0, stream>>>(gh, offs, gcursor);
  k_sortscatter<<<(NE + 8191) / 8192, 256, 0, stream>>>(ei, ea, flag, gcursor, csr);
  k_msg<<<NBUCK, 512, 0, stream>>>((const unsigned*)mN, Wmsg, offs, csr, bmsg, agg);
  k_upd<<<(NN + 127) / 128, 512, 0, stream>>>(x, Wenc, benc, agg, Wupd, bupd, Wdec, bdec, out);
}

// Round 6
// 211.951 us; speedup vs baseline: 2.9340x; 1.1511x over previous
//
#include <hip/hip_runtime.h>

#define NN 100000
#define NE 1600000
#define HID 128
#define NBUCK 1563          // ceil(NN/64), 64-node buckets

typedef float f32x4 __attribute__((ext_vector_type(4)));
typedef __bf16 bf16x8 __attribute__((ext_vector_type(8)));
typedef unsigned short u16x8 __attribute__((ext_vector_type(8)));

static __device__ __forceinline__ unsigned short f2bf(float f) {
  union { float f; unsigned u; } v; v.f = f;
  unsigned u = v.u;
  return (unsigned short)((u + 0x7FFFu + ((u >> 16) & 1u)) >> 16);
}

static __device__ __forceinline__ f32x4 mfma_bf16(u16x8 a, u16x8 b, f32x4 c) {
  return __builtin_amdgcn_mfma_f32_16x16x32_bf16(
      __builtin_bit_cast(bf16x8, a), __builtin_bit_cast(bf16x8, b), c, 0, 0, 0);
}

// fp32 monotone code: unsigned compare == float compare. 0xFFFFFFFF = sentinel (> all finite).
static __device__ __forceinline__ unsigned fenc32(float f) {
  unsigned u = __float_as_uint(f);
  return (u >> 31) ? ~u : (u | 0x80000000u);
}
static __device__ __forceinline__ float fdec32(unsigned e) {
  unsigned u = (e & 0x80000000u) ? (e & 0x7FFFFFFFu) : ~e;
  return __uint_as_float(u);
}

// edge_index may arrive as int32 or int64 (values < 2^31, little-endian).
static __device__ __forceinline__ int gidx(const int* __restrict__ ei, int is64, long long pos) {
  return is64 ? ei[pos * 2] : ei[pos];
}

// ---------------- dtype detection ----------------
__global__ void k_detect(const int* __restrict__ ei, int* __restrict__ flag) {
  unsigned long long b = __ballot(ei[2 * threadIdx.x + 1] == 0);
  if (threadIdx.x == 0) *flag = (b == ~0ull) ? 1 : 0;
}

// ---------------- encoder + message projection fused ----------------
// h = relu(x @ W_enc + b_enc)  (LDS only);  mNp = perm(h @ W_msg[0:128]) bf16:
// word l of a node = (col l) | (col l+64)<<16  -> lane l of k_msg owns cols l, l+64
__global__ __launch_bounds__(512) void k_enc2(const float* __restrict__ x,
    const float* __restrict__ Wenc, const float* __restrict__ benc,
    const float* __restrict__ Wmsg, unsigned* __restrict__ mNp) {
  __shared__ unsigned short WtE[128 * 136];
  __shared__ unsigned short WtM[128 * 136];
  __shared__ float bshE[128];
  __shared__ unsigned short bounce[8][16 * 136];
  int tid = threadIdx.x;
  for (int idx = tid; idx < 128 * 128; idx += 512) {
    int k = idx >> 7, j = idx & 127;
    WtE[j * 136 + k] = f2bf(Wenc[idx]);
    WtM[j * 136 + k] = f2bf(Wmsg[idx]);
  }
  if (tid < 128) bshE[tid] = benc[tid];
  __syncthreads();

  int wave = tid >> 6, lane = tid & 63;
  int l15 = lane & 15, lg = lane >> 4;
  int rowBase = blockIdx.x * 128 + wave * 16;
  int nodeA = rowBase + l15; if (nodeA > NN - 1) nodeA = NN - 1;

  // ---- stage 1: h ----
  u16x8 af[4];
#pragma unroll
  for (int kt = 0; kt < 4; ++kt) {
    const float* px = x + (long long)nodeA * HID + kt * 32 + lg * 8;
    f32x4 a0 = *(const f32x4*)px;
    f32x4 a1 = *(const f32x4*)(px + 4);
    u16x8 t;
    t[0] = f2bf(a0[0]); t[1] = f2bf(a0[1]); t[2] = f2bf(a0[2]); t[3] = f2bf(a0[3]);
    t[4] = f2bf(a1[0]); t[5] = f2bf(a1[1]); t[6] = f2bf(a1[2]); t[7] = f2bf(a1[3]);
    af[kt] = t;
  }
  f32x4 zero = {0.f, 0.f, 0.f, 0.f};
  f32x4 acc[8];
#pragma unroll
  for (int nt = 0; nt < 8; ++nt) acc[nt] = zero;
#pragma unroll
  for (int kt = 0; kt < 4; ++kt)
#pragma unroll
    for (int nt = 0; nt < 8; ++nt) {
      u16x8 bfv = *(const u16x8*)&WtE[(nt * 16 + l15) * 136 + kt * 32 + lg * 8];
      acc[nt] = mfma_bf16(af[kt], bfv, acc[nt]);
    }
#pragma unroll
  for (int nt = 0; nt < 8; ++nt) {
    int j = nt * 16 + l15;
    float bj = bshE[j];
#pragma unroll
    for (int r = 0; r < 4; ++r) {
      float v = acc[nt][r] + bj;
      v = v > 0.f ? v : 0.f;
      bounce[wave][(lg * 4 + r) * 136 + j] = f2bf(v);
    }
  }
  // ---- stage 2: mN = h @ W_msg ----
  u16x8 ha[4];
#pragma unroll
  for (int kt = 0; kt < 4; ++kt)
    ha[kt] = *(const u16x8*)&bounce[wave][l15 * 136 + kt * 32 + lg * 8];
  asm volatile("s_waitcnt lgkmcnt(0)" ::: "memory");
  __builtin_amdgcn_sched_barrier(0);
  f32x4 acc2[8];
#pragma unroll
  for (int nt = 0; nt < 8; ++nt) acc2[nt] = zero;
#pragma unroll
  for (int kt = 0; kt < 4; ++kt)
#pragma unroll
    for (int nt = 0; nt < 8; ++nt) {
      u16x8 bfv = *(const u16x8*)&WtM[(nt * 16 + l15) * 136 + kt * 32 + lg * 8];
      acc2[nt] = mfma_bf16(ha[kt], bfv, acc2[nt]);
    }
#pragma unroll
  for (int nt = 0; nt < 8; ++nt) {
    int j = nt * 16 + l15;
#pragma unroll
    for (int r = 0; r < 4; ++r)
      bounce[wave][(lg * 4 + r) * 136 + j] = f2bf(acc2[nt][r]);
  }
  asm volatile("s_waitcnt lgkmcnt(0)" ::: "memory");
  __builtin_amdgcn_sched_barrier(0);
  // ---- permuted store: word l = col l | col(l+64)<<16 ----
#pragma unroll 4
  for (int row = 0; row < 16; ++row) {
    int node = rowBase + row;
    if (node < NN) {
      unsigned lo = bounce[wave][row * 136 + lane];
      unsigned hi = bounce[wave][row * 136 + 64 + lane];
      mNp[(size_t)node * 64 + lane] = lo | (hi << 16);
    }
  }
}

// ---------------- bucket histogram (LDS pre-aggregated) ----------------
__global__ __launch_bounds__(256) void k_hist(const int* __restrict__ ei,
    const int* __restrict__ flag, int* __restrict__ gh) {
  __shared__ unsigned cnt[NBUCK];
  int tid = threadIdx.x;
  for (int i = tid; i < NBUCK; i += 256) cnt[i] = 0;
  __syncthreads();
  int is64 = *flag;
  long long base = (long long)blockIdx.x * 4096;
  int n = (int)(((long long)NE - base < 4096) ? ((long long)NE - base) : 4096);
  for (int i = tid; i < n; i += 256) {
    int d = gidx(ei, is64, (long long)NE + base + i);
    atomicAdd(&cnt[d >> 6], 1u);
  }
  __syncthreads();
  for (int i = tid; i < NBUCK; i += 256)
    if (cnt[i]) atomicAdd(&gh[i], (int)cnt[i]);
}

// ---------------- scan 1563 buckets -> offsets + cursors ----------------
__global__ __launch_bounds__(1024) void k_scan(const int* __restrict__ gh,
    int* __restrict__ offs, int* __restrict__ gcursor) {
  __shared__ int sc[1024];
  int t = threadIdx.x;
  int e0 = (2 * t < NBUCK) ? gh[2 * t] : 0;
  int e1 = (2 * t + 1 < NBUCK) ? gh[2 * t + 1] : 0;
  int pair = e0 + e1;
  sc[t] = pair;
  __syncthreads();
  for (int s = 1; s < 1024; s <<= 1) {
    int a = (t >= s) ? sc[t - s] : 0;
    __syncthreads();
    sc[t] += a;
    __syncthreads();
  }
  int base = sc[t] - pair;
  if (2 * t < NBUCK)     { offs[2 * t] = base;          gcursor[2 * t] = base; }
  if (2 * t + 1 < NBUCK) { offs[2 * t + 1] = base + e0; gcursor[2 * t + 1] = base + e0; }
  if (t == 0) offs[NBUCK] = NE;
}

// ---------------- chunk-sorted scatter ----------------
// entry u64: src(17) | local(6)<<17 | ea_bf16(16)<<23
__global__ __launch_bounds__(256) void k_sortscatter(const int* __restrict__ ei,
    const float* __restrict__ ea, const int* __restrict__ flag,
    int* __restrict__ gcursor, unsigned long long* __restrict__ csr) {
  __shared__ unsigned cnt[NBUCK];
  __shared__ unsigned gbase[NBUCK];
  int tid = threadIdx.x;
  long long base = (long long)blockIdx.x * 8192;
  int n = (int)(((long long)NE - base < 8192) ? ((long long)NE - base) : 8192);
  for (int i = tid; i < NBUCK; i += 256) cnt[i] = 0;
  __syncthreads();
  int is64 = *flag;
  // pass 1: count this chunk's bucket sizes
  for (int i = tid; i < n; i += 256) {
    int d = gidx(ei, is64, (long long)NE + base + i);
    atomicAdd(&cnt[d >> 6], 1u);
  }
  __syncthreads();
  // claim contiguous runs
  for (int b = tid; b < NBUCK; b += 256) {
    unsigned c = cnt[b];
    gbase[b] = c ? (unsigned)atomicAdd(&gcursor[b], (int)c) : 0u;
  }
  __syncthreads();
  for (int i = tid; i < NBUCK; i += 256) cnt[i] = 0;   // reuse as local cursor
  __syncthreads();
  // pass 2: write entries into the claimed runs
  for (int i = tid; i < n; i += 256) {
    int s = gidx(ei, is64, base + i);
    int d = gidx(ei, is64, (long long)NE + base + i);
    unsigned eab = f2bf(ea[base + i]);
    int b = d >> 6;
    unsigned lp = atomicAdd(&cnt[b], 1u);
    csr[gbase[b] + lp] = (unsigned long long)(unsigned)s
                       | ((unsigned long long)(unsigned)(d & 63) << 17)
                       | ((unsigned long long)eab << 23);
  }
}

// ---------------- bucket-LDS message + segment-min ----------------
// One block owns 64 destination nodes; min-state = fp32-monotone codes in 32 KB LDS.
// Lane l owns cols (l, l+64): all LDS atomics are lane-stride-1 => 2-way (free).
__global__ __launch_bounds__(512) void k_msg(const unsigned* __restrict__ mNp,
    const float* __restrict__ Wmsg, const int* __restrict__ offs,
    const unsigned long long* __restrict__ csr, const float* __restrict__ bmsg,
    unsigned* __restrict__ agg32) {
  __shared__ unsigned st[64 * 128];     // 32 KB
  __shared__ float bmsh[128];
  int tid = threadIdx.x;
  int b = blockIdx.x;
  for (int i = tid; i < 64 * 128; i += 512) st[i] = 0xFFFFFFFFu;
  if (tid < 128) bmsh[tid] = bmsg[tid];
  __syncthreads();

  int lane = tid & 63;
  int wv = tid >> 6;                     // 0..7
  int off = offs[b], end = offs[b + 1];
  int cntE = end - off;
  int per = (cntE + 7) >> 3;
  int i0 = off + wv * per;
  int i1 = i0 + per; if (i1 > end) i1 = end;
  float wl0 = Wmsg[128 * 128 + lane];
  float wl1 = Wmsg[128 * 128 + 64 + lane];

  int i = i0;
  for (; i + 8 <= i1; i += 8) {
    unsigned long long pk[8];
    unsigned v[8];
#pragma unroll
    for (int j = 0; j < 8; ++j) pk[j] = csr[i + j];
#pragma unroll
    for (int j = 0; j < 8; ++j)
      v[j] = mNp[(size_t)(unsigned)(pk[j] & 0x1FFFFu) * 64 + lane];
#pragma unroll
    for (int j = 0; j < 8; ++j) {
      int loc = (int)((pk[j] >> 17) & 0x3Fu);
      float eav = __uint_as_float((unsigned)((pk[j] >> 23) & 0xFFFFu) << 16);
      float v0 = fmaf(eav, wl0, __uint_as_float(v[j] << 16));
      float v1 = fmaf(eav, wl1, __uint_as_float(v[j] & 0xFFFF0000u));
      atomicMin(&st[loc * 128 + lane], fenc32(v0));
      atomicMin(&st[loc * 128 + 64 + lane], fenc32(v1));
    }
  }
  for (; i < i1; ++i) {
    unsigned long long pk = csr[i];
    unsigned v = mNp[(size_t)(unsigned)(pk & 0x1FFFFu) * 64 + lane];
    int loc = (int)((pk >> 17) & 0x3Fu);
    float eav = __uint_as_float((unsigned)((pk >> 23) & 0xFFFFu) << 16);
    float v0 = fmaf(eav, wl0, __uint_as_float(v << 16));
    float v1 = fmaf(eav, wl1, __uint_as_float(v & 0xFFFF0000u));
    atomicMin(&st[loc * 128 + lane], fenc32(v0));
    atomicMin(&st[loc * 128 + 64 + lane], fenc32(v1));
  }
  __syncthreads();

  // finalize: decode + b_msg, write agg bf16 packed u32, conflict-free stride-1 reads
  int node0 = b << 6;
#pragma unroll
  for (int it = 0; it < 8; ++it) {
    int o = it * 512 + tid;              // word index into 64x64 output u32s
    int nd = o >> 6;
    int cp = o & 63;                     // colpair: cols 2cp, 2cp+1
    unsigned long long two = *(const unsigned long long*)&st[2 * o];
    unsigned eL = (unsigned)two, eH = (unsigned)(two >> 32);
    float f0 = (eL == 0xFFFFFFFFu) ? 0.f : (fdec32(eL) + bmsh[2 * cp]);
    float f1 = (eH == 0xFFFFFFFFu) ? 0.f : (fdec32(eH) + bmsh[2 * cp + 1]);
    unsigned pkd = (unsigned)f2bf(f0) | ((unsigned)f2bf(f1) << 16);
    if (node0 + nd < NN) agg32[(size_t)(node0 + nd) * 64 + cp] = pkd;
  }
}

// ---------------- update + decoder fused (recomputes h from x; agg is plain bf16) ----------------
__global__ __launch_bounds__(512) void k_upd(const float* __restrict__ x,
    const float* __restrict__ Wenc, const float* __restrict__ benc,
    const unsigned short* __restrict__ agg,
    const float* __restrict__ Wupd, const float* __restrict__ bupd,
    const float* __restrict__ Wdec, const float* __restrict__ bdec,
    float* __restrict__ out) {
  __shared__ unsigned short WtE[128 * 136];
  __shared__ unsigned short Wt1[128 * 136];
  __shared__ unsigned short Wt2[128 * 136];
  __shared__ float bshE[128];
  __shared__ float bsh[128];
  __shared__ float wd[128];
  __shared__ unsigned short bounce[8][16 * 136];
  int tid = threadIdx.x;
  for (int idx = tid; idx < 128 * 128; idx += 512) {
    int k = idx >> 7, j = idx & 127;
    WtE[j * 136 + k] = f2bf(Wenc[idx]);
    Wt1[j * 136 + k] = f2bf(Wupd[idx]);
    Wt2[j * 136 + k] = f2bf(Wupd[128 * 128 + idx]);
  }
  if (tid < 128) { bshE[tid] = benc[tid]; bsh[tid] = bupd[tid]; wd[tid] = Wdec[tid]; }
  __syncthreads();

  int wave = tid >> 6, lane = tid & 63;
  int l15 = lane & 15, lg = lane >> 4;
  int rowBase = blockIdx.x * 128 + wave * 16;
  int nodeA = rowBase + l15; if (nodeA > NN - 1) nodeA = NN - 1;

  // ---- stage 1: recompute h -> bounce ----
  u16x8 af[4];
#pragma unroll
  for (int kt = 0; kt < 4; ++kt) {
    const float* px = x + (long long)nodeA * HID + kt * 32 + lg * 8;
    f32x4 a0 = *(const f32x4*)px;
    f32x4 a1 = *(const f32x4*)(px + 4);
    u16x8 t;
    t[0] = f2bf(a0[0]); t[1] = f2bf(a0[1]); t[2] = f2bf(a0[2]); t[3] = f2bf(a0[3]);
    t[4] = f2bf(a1[0]); t[5] = f2bf(a1[1]); t[6] = f2bf(a1[2]); t[7] = f2bf(a1[3]);
    af[kt] = t;
  }
  f32x4 zero = {0.f, 0.f, 0.f, 0.f};
  f32x4 acc[8];
#pragma unroll
  for (int nt = 0; nt < 8; ++nt) acc[nt] = zero;
#pragma unroll
  for (int kt = 0; kt < 4; ++kt)
#pragma unroll
    for (int nt = 0; nt < 8; ++nt) {
      u16x8 bfv = *(const u16x8*)&WtE[(nt * 16 + l15) * 136 + kt * 32 + lg * 8];
      acc[nt] = mfma_bf16(af[kt], bfv, acc[nt]);
    }
#pragma unroll
  for (int nt = 0; nt < 8; ++nt) {
    int j = nt * 16 + l15;
    float bj = bshE[j];
#pragma unroll
    for (int r = 0; r < 4; ++r) {
      float v = acc[nt][r] + bj;
      v = v > 0.f ? v : 0.f;
      bounce[wave][(lg * 4 + r) * 136 + j] = f2bf(v);
    }
  }
  // ---- stage 2: u = [h, agg] @ W_upd + b_upd; out = sigmoid(u @ W_dec + b_dec) ----
  u16x8 a1[4], a2[4];
#pragma unroll
  for (int kt = 0; kt < 4; ++kt)
    a1[kt] = *(const u16x8*)&bounce[wave][l15 * 136 + kt * 32 + lg * 8];
#pragma unroll
  for (int kt = 0; kt < 4; ++kt)
    a2[kt] = *(const u16x8*)&agg[(size_t)nodeA * HID + kt * 32 + lg * 8];
  asm volatile("s_waitcnt lgkmcnt(0)" ::: "memory");
  __builtin_amdgcn_sched_barrier(0);
  f32x4 accu[8];
#pragma unroll
  for (int nt = 0; nt < 8; ++nt) accu[nt] = zero;
#pragma unroll
  for (int kt = 0; kt < 4; ++kt)
#pragma unroll
    for (int nt = 0; nt < 8; ++nt) {
      u16x8 b1 = *(const u16x8*)&Wt1[(nt * 16 + l15) * 136 + kt * 32 + lg * 8];
      accu[nt] = mfma_bf16(a1[kt], b1, accu[nt]);
    }
#pragma unroll
  for (int kt = 0; kt < 4; ++kt)
#pragma unroll
    for (int nt = 0; nt < 8; ++nt) {
      u16x8 b2 = *(const u16x8*)&Wt2[(nt * 16 + l15) * 136 + kt * 32 + lg * 8];
      accu[nt] = mfma_bf16(a2[kt], b2, accu[nt]);
    }
  float ps0 = 0.f, ps1 = 0.f, ps2 = 0.f, ps3 = 0.f;
#pragma unroll
  for (int nt = 0; nt < 8; ++nt) {
    int j = nt * 16 + l15;
    float bu = bsh[j], w = wd[j];
    ps0 += (accu[nt][0] + bu) * w;
    ps1 += (accu[nt][1] + bu) * w;
    ps2 += (accu[nt][2] + bu) * w;
    ps3 += (accu[nt][3] + bu) * w;
  }
#pragma unroll
  for (int m = 1; m < 16; m <<= 1) {
    ps0 += __shfl_xor(ps0, m);
    ps1 += __shfl_xor(ps1, m);
    ps2 += __shfl_xor(ps2, m);
    ps3 += __shfl_xor(ps3, m);
  }
  if (l15 == 0) {
    float bd = *bdec;
    float v0 = 1.f / (1.f + expf(-(ps0 + bd)));
    float v1 = 1.f / (1.f + expf(-(ps1 + bd)));
    float v2 = 1.f / (1.f + expf(-(ps2 + bd)));
    float v3 = 1.f / (1.f + expf(-(ps3 + bd)));
    int n0 = rowBase + lg * 4;
    if (n0 + 3 < NN) {
      float4 st4; st4.x = v0; st4.y = v1; st4.z = v2; st4.w = v3;
      *(float4*)&out[n0] = st4;
    } else {
      if (n0 + 0 < NN) out[n0 + 0] = v0;
      if (n0 + 1 < NN) out[n0 + 1] = v1;
      if (n0 + 2 < NN) out[n0 + 2] = v2;
      if (n0 + 3 < NN) out[n0 + 3] = v3;
    }
  }
}

extern "C" void kernel_launch(void* const* d_in, const int* in_sizes, int n_in,
                              void* d_out, int out_size, void* d_ws, size_t ws_size,
                              hipStream_t stream) {
  const float* x    = (const float*)d_in[0];
  const int*   ei   = (const int*)d_in[1];
  const float* ea   = (const float*)d_in[2];
  const float* Wenc = (const float*)d_in[3];
  const float* benc = (const float*)d_in[4];
  const float* Wmsg = (const float*)d_in[5];
  const float* bmsg = (const float*)d_in[6];
  const float* Wupd = (const float*)d_in[7];
  const float* bupd = (const float*)d_in[8];
  const float* Wdec = (const float*)d_in[9];
  const float* bdec = (const float*)d_in[10];
  float* out = (float*)d_out;

  // workspace carve (total ~64.1 MiB, below the empirically-safe 65.2 MB)
  char* w = (char*)d_ws;
  auto alloc = [&](size_t bytes) { char* p = w; w += (bytes + 255) & ~(size_t)255; return p; };
  unsigned* mNp       = (unsigned*)alloc((size_t)NN * 64 * 4);              // 25.6 MB (permuted bf16 pairs)
  unsigned* agg32     = (unsigned*)alloc((size_t)NN * 64 * 4);              // 25.6 MB (bf16 pairs, canonical)
  unsigned long long* csr = (unsigned long long*)alloc((size_t)NE * 8);     // 12.8 MB
  int* gh      = (int*)alloc((size_t)NBUCK * 4);
  int* offs    = (int*)alloc((size_t)(NBUCK + 1) * 4);
  int* gcursor = (int*)alloc((size_t)NBUCK * 4);
  int* flag    = (int*)alloc(256);

  k_detect<<<1, 64, 0, stream>>>(ei, flag);
  hipMemsetAsync(gh, 0, (size_t)NBUCK * 4, stream);
  k_enc2<<<(NN + 127) / 128, 512, 0, stream>>>(x, Wenc, benc, Wmsg, mNp);
  k_hist<<<(NE + 4095) / 4096, 256, 0, stream>>>(ei, flag, gh);
  k_scan<<<1, 1024, 0, stream>>>(gh, offs, gcursor);
  k_sortscatter<<<(NE + 8191) / 8192, 256, 0, stream>>>(ei, ea, flag, gcursor, csr);
  k_msg<<<NBUCK, 512, 0, stream>>>(mNp, Wmsg, offs, csr, bmsg, agg32);
  k_upd<<<(NN + 127) / 128, 512, 0, stream>>>(x, Wenc, benc, (const unsigned short*)agg32,
                                              Wupd, bupd, Wdec, bdec, out);
}

// Round 7
// 209.339 us; speedup vs baseline: 2.9706x; 1.0125x over previous
//
#include <hip/hip_runtime.h>

#define NN 100000
#define NE 1600000
#define HID 128
#define NBUCK 1563          // ceil(NN/64), 64-node buckets
#define STP 130             // padded LDS stride (u32 words) for min-state

typedef float f32x4 __attribute__((ext_vector_type(4)));
typedef __bf16 bf16x8 __attribute__((ext_vector_type(8)));
typedef unsigned short u16x8 __attribute__((ext_vector_type(8)));

static __device__ __forceinline__ unsigned short f2bf(float f) {
  union { float f; unsigned u; } v; v.f = f;
  unsigned u = v.u;
  return (unsigned short)((u + 0x7FFFu + ((u >> 16) & 1u)) >> 16);
}
static __device__ __forceinline__ unsigned short f2h(float f) {
  _Float16 h = (_Float16)f;
  return __builtin_bit_cast(unsigned short, h);
}
static __device__ __forceinline__ float h2f(unsigned short b) {
  return (float)__builtin_bit_cast(_Float16, b);
}

static __device__ __forceinline__ f32x4 mfma_bf16(u16x8 a, u16x8 b, f32x4 c) {
  return __builtin_amdgcn_mfma_f32_16x16x32_bf16(
      __builtin_bit_cast(bf16x8, a), __builtin_bit_cast(bf16x8, b), c, 0, 0, 0);
}

// fp32 monotone code: unsigned compare == float compare. 0xFFFFFFFF = sentinel (> all finite).
static __device__ __forceinline__ unsigned fenc32(float f) {
  unsigned u = __float_as_uint(f);
  return (u >> 31) ? ~u : (u | 0x80000000u);
}
static __device__ __forceinline__ float fdec32(unsigned e) {
  unsigned u = (e & 0x80000000u) ? (e & 0x7FFFFFFFu) : ~e;
  return __uint_as_float(u);
}

// edge_index may arrive as int32 or int64 (values < 2^31, little-endian).
static __device__ __forceinline__ int gidx(const int* __restrict__ ei, int is64, long long pos) {
  return is64 ? ei[pos * 2] : ei[pos];
}

// ---------------- dtype detection ----------------
__global__ void k_detect(const int* __restrict__ ei, int* __restrict__ flag) {
  unsigned long long b = __ballot(ei[2 * threadIdx.x + 1] == 0);
  if (threadIdx.x == 0) *flag = (b == ~0ull) ? 1 : 0;
}

// ---------------- one-time prep: W2t[j][k] = bf16(W_upd[128+k][j]) ----------------
__global__ __launch_bounds__(512) void k_prep(const float* __restrict__ Wupd,
                                              unsigned short* __restrict__ W2t) {
  int i = blockIdx.x * 512 + threadIdx.x;
  if (i < 128 * 128) {
    int j = i >> 7, k = i & 127;
    W2t[j * 128 + k] = f2bf(Wupd[(128 + k) * 128 + j]);
  }
}

// ---------------- encoder + message projection + update-top fused ----------------
// h = relu(x @ W_enc + b_enc)   (LDS only)
// mNp = perm(h @ W_msg[0:128])  bf16 pairs: word l = col l | col(l+64)<<16
// hu  = h @ W_upd[0:128] + b_upd  (f16, canonical row-major)
__global__ __launch_bounds__(512) void k_enc2(const float* __restrict__ x,
    const float* __restrict__ Wenc, const float* __restrict__ benc,
    const float* __restrict__ Wmsg, const float* __restrict__ Wupd,
    const float* __restrict__ bupd,
    unsigned* __restrict__ mNp, unsigned short* __restrict__ hu16) {
  __shared__ unsigned short WtE[128 * 136];
  __shared__ unsigned short WtM[128 * 136];
  __shared__ unsigned short WtU[128 * 136];
  __shared__ float bshE[128];
  __shared__ float bshU[128];
  __shared__ unsigned short bounce[8][16 * 136];
  int tid = threadIdx.x;
  for (int idx = tid; idx < 128 * 128; idx += 512) {
    int k = idx >> 7, j = idx & 127;
    WtE[j * 136 + k] = f2bf(Wenc[idx]);
    WtM[j * 136 + k] = f2bf(Wmsg[idx]);
    WtU[j * 136 + k] = f2bf(Wupd[idx]);
  }
  if (tid < 128) { bshE[tid] = benc[tid]; bshU[tid] = bupd[tid]; }
  __syncthreads();

  int wave = tid >> 6, lane = tid & 63;
  int l15 = lane & 15, lg = lane >> 4;
  int rowBase = blockIdx.x * 128 + wave * 16;
  int nodeA = rowBase + l15; if (nodeA > NN - 1) nodeA = NN - 1;

  // ---- stage 1: h ----
  u16x8 af[4];
#pragma unroll
  for (int kt = 0; kt < 4; ++kt) {
    const float* px = x + (long long)nodeA * HID + kt * 32 + lg * 8;
    f32x4 a0 = *(const f32x4*)px;
    f32x4 a1 = *(const f32x4*)(px + 4);
    u16x8 t;
    t[0] = f2bf(a0[0]); t[1] = f2bf(a0[1]); t[2] = f2bf(a0[2]); t[3] = f2bf(a0[3]);
    t[4] = f2bf(a1[0]); t[5] = f2bf(a1[1]); t[6] = f2bf(a1[2]); t[7] = f2bf(a1[3]);
    af[kt] = t;
  }
  f32x4 zero = {0.f, 0.f, 0.f, 0.f};
  f32x4 acc[8];
#pragma unroll
  for (int nt = 0; nt < 8; ++nt) acc[nt] = zero;
#pragma unroll
  for (int kt = 0; kt < 4; ++kt)
#pragma unroll
    for (int nt = 0; nt < 8; ++nt) {
      u16x8 bfv = *(const u16x8*)&WtE[(nt * 16 + l15) * 136 + kt * 32 + lg * 8];
      acc[nt] = mfma_bf16(af[kt], bfv, acc[nt]);
    }
#pragma unroll
  for (int nt = 0; nt < 8; ++nt) {
    int j = nt * 16 + l15;
    float bj = bshE[j];
#pragma unroll
    for (int r = 0; r < 4; ++r) {
      float v = acc[nt][r] + bj;
      v = v > 0.f ? v : 0.f;
      bounce[wave][(lg * 4 + r) * 136 + j] = f2bf(v);
    }
  }
  // h fragments (A for stages 2 & 3)
  u16x8 ha[4];
#pragma unroll
  for (int kt = 0; kt < 4; ++kt)
    ha[kt] = *(const u16x8*)&bounce[wave][l15 * 136 + kt * 32 + lg * 8];
  asm volatile("s_waitcnt lgkmcnt(0)" ::: "memory");
  __builtin_amdgcn_sched_barrier(0);

  // ---- stage 2: mN = h @ W_msg ----
  f32x4 acc2[8];
#pragma unroll
  for (int nt = 0; nt < 8; ++nt) acc2[nt] = zero;
#pragma unroll
  for (int kt = 0; kt < 4; ++kt)
#pragma unroll
    for (int nt = 0; nt < 8; ++nt) {
      u16x8 bfv = *(const u16x8*)&WtM[(nt * 16 + l15) * 136 + kt * 32 + lg * 8];
      acc2[nt] = mfma_bf16(ha[kt], bfv, acc2[nt]);
    }
#pragma unroll
  for (int nt = 0; nt < 8; ++nt) {
    int j = nt * 16 + l15;
#pragma unroll
    for (int r = 0; r < 4; ++r)
      bounce[wave][(lg * 4 + r) * 136 + j] = f2bf(acc2[nt][r]);
  }
  asm volatile("s_waitcnt lgkmcnt(0)" ::: "memory");
  __builtin_amdgcn_sched_barrier(0);
  // permuted store: word l = col l | col(l+64)<<16
#pragma unroll 4
  for (int row = 0; row < 16; ++row) {
    int node = rowBase + row;
    if (node < NN) {
      unsigned lo = bounce[wave][row * 136 + lane];
      unsigned hi = bounce[wave][row * 136 + 64 + lane];
      mNp[(size_t)node * 64 + lane] = lo | (hi << 16);
    }
  }
  asm volatile("s_waitcnt lgkmcnt(0)" ::: "memory");
  __builtin_amdgcn_sched_barrier(0);

  // ---- stage 3: hu = h @ W_upd_top + b_upd (f16) ----
  f32x4 acc3[8];
#pragma unroll
  for (int nt = 0; nt < 8; ++nt) acc3[nt] = zero;
#pragma unroll
  for (int kt = 0; kt < 4; ++kt)
#pragma unroll
    for (int nt = 0; nt < 8; ++nt) {
      u16x8 bfv = *(const u16x8*)&WtU[(nt * 16 + l15) * 136 + kt * 32 + lg * 8];
      acc3[nt] = mfma_bf16(ha[kt], bfv, acc3[nt]);
    }
#pragma unroll
  for (int nt = 0; nt < 8; ++nt) {
    int j = nt * 16 + l15;
    float bu = bshU[j];
#pragma unroll
    for (int r = 0; r < 4; ++r)
      bounce[wave][(lg * 4 + r) * 136 + j] = f2h(acc3[nt][r] + bu);
  }
  asm volatile("s_waitcnt lgkmcnt(0)" ::: "memory");
  __builtin_amdgcn_sched_barrier(0);
#pragma unroll
  for (int p = 0; p < 4; ++p) {
    int row = p * 4 + lg;
    int node = rowBase + row;
    if (node < NN) {
      u16x8 v = *(const u16x8*)&bounce[wave][row * 136 + l15 * 8];
      *(u16x8*)&hu16[(size_t)node * HID + l15 * 8] = v;
    }
  }
}

// ---------------- bucket histogram (LDS pre-aggregated) ----------------
__global__ __launch_bounds__(256) void k_hist(const int* __restrict__ ei,
    const int* __restrict__ flag, int* __restrict__ gh) {
  __shared__ unsigned cnt[NBUCK];
  int tid = threadIdx.x;
  for (int i = tid; i < NBUCK; i += 256) cnt[i] = 0;
  __syncthreads();
  int is64 = *flag;
  long long base = (long long)blockIdx.x * 4096;
  int n = (int)(((long long)NE - base < 4096) ? ((long long)NE - base) : 4096);
  for (int i = tid; i < n; i += 256) {
    int d = gidx(ei, is64, (long long)NE + base + i);
    atomicAdd(&cnt[d >> 6], 1u);
  }
  __syncthreads();
  for (int i = tid; i < NBUCK; i += 256)
    if (cnt[i]) atomicAdd(&gh[i], (int)cnt[i]);
}

// ---------------- scan 1563 buckets -> offsets + cursors ----------------
__global__ __launch_bounds__(1024) void k_scan(const int* __restrict__ gh,
    int* __restrict__ offs, int* __restrict__ gcursor) {
  __shared__ int sc[1024];
  int t = threadIdx.x;
  int e0 = (2 * t < NBUCK) ? gh[2 * t] : 0;
  int e1 = (2 * t + 1 < NBUCK) ? gh[2 * t + 1] : 0;
  int pair = e0 + e1;
  sc[t] = pair;
  __syncthreads();
  for (int s = 1; s < 1024; s <<= 1) {
    int a = (t >= s) ? sc[t - s] : 0;
    __syncthreads();
    sc[t] += a;
    __syncthreads();
  }
  int base = sc[t] - pair;
  if (2 * t < NBUCK)     { offs[2 * t] = base;          gcursor[2 * t] = base; }
  if (2 * t + 1 < NBUCK) { offs[2 * t + 1] = base + e0; gcursor[2 * t + 1] = base + e0; }
  if (t == 0) offs[NBUCK] = NE;
}

// ---------------- chunk-sorted scatter ----------------
// entry u64: src(17) | local(6)<<17 | ea_bf16(16)<<23
__global__ __launch_bounds__(256) void k_sortscatter(const int* __restrict__ ei,
    const float* __restrict__ ea, const int* __restrict__ flag,
    int* __restrict__ gcursor, unsigned long long* __restrict__ csr) {
  __shared__ unsigned cnt[NBUCK];
  __shared__ unsigned gbase[NBUCK];
  int tid = threadIdx.x;
  long long base = (long long)blockIdx.x * 8192;
  int n = (int)(((long long)NE - base < 8192) ? ((long long)NE - base) : 8192);
  for (int i = tid; i < NBUCK; i += 256) cnt[i] = 0;
  __syncthreads();
  int is64 = *flag;
  for (int i = tid; i < n; i += 256) {
    int d = gidx(ei, is64, (long long)NE + base + i);
    atomicAdd(&cnt[d >> 6], 1u);
  }
  __syncthreads();
  for (int b = tid; b < NBUCK; b += 256) {
    unsigned c = cnt[b];
    gbase[b] = c ? (unsigned)atomicAdd(&gcursor[b], (int)c) : 0u;
  }
  __syncthreads();
  for (int i = tid; i < NBUCK; i += 256) cnt[i] = 0;   // reuse as local cursor
  __syncthreads();
  for (int i = tid; i < n; i += 256) {
    int s = gidx(ei, is64, base + i);
    int d = gidx(ei, is64, (long long)NE + base + i);
    unsigned eab = f2bf(ea[base + i]);
    int b = d >> 6;
    unsigned lp = atomicAdd(&cnt[b], 1u);
    csr[gbase[b] + lp] = (unsigned long long)(unsigned)s
                       | ((unsigned long long)(unsigned)(d & 63) << 17)
                       | ((unsigned long long)eab << 23);
  }
}

// ---------------- fused: edge min (LDS) + update-bottom GEMM + decoder + sigmoid ----------------
// One block owns 64 destination nodes. Phase 1: per-edge gather+fma+ds_atomicMin
// (lane-stride-1, conflict-free). Phase 2: u = decode(st)+b_msg -> @W2t + hu -> sigmoid -> out.
__global__ __launch_bounds__(512, 8) void k_msg(const unsigned* __restrict__ mNp,
    const float* __restrict__ Wmsg, const int* __restrict__ offs,
    const unsigned long long* __restrict__ csr, const float* __restrict__ bmsg,
    const unsigned short* __restrict__ hu16, const unsigned short* __restrict__ W2t,
    const float* __restrict__ Wdec, const float* __restrict__ bdec,
    float* __restrict__ out) {
  __shared__ unsigned st[64 * STP];     // 33.3 KB, padded stride
  __shared__ float bmsh[128];
  int tid = threadIdx.x;
  int b = blockIdx.x;
  for (int i = tid; i < 64 * STP; i += 512) st[i] = 0xFFFFFFFFu;
  if (tid < 128) bmsh[tid] = bmsg[tid];
  __syncthreads();

  int lane = tid & 63;
  int wv = tid >> 6;                     // 0..7
  int off = offs[b], end = offs[b + 1];
  int cntE = end - off;
  int per = (cntE + 7) >> 3;
  int i0 = off + wv * per;
  int i1 = i0 + per; if (i1 > end) i1 = end;
  float wl0 = Wmsg[128 * 128 + lane];
  float wl1 = Wmsg[128 * 128 + 64 + lane];

  int i = i0;
  for (; i + 8 <= i1; i += 8) {
    unsigned long long pk[8];
    unsigned v[8];
#pragma unroll
    for (int j = 0; j < 8; ++j) pk[j] = csr[i + j];
#pragma unroll
    for (int j = 0; j < 8; ++j)
      v[j] = mNp[(size_t)(unsigned)(pk[j] & 0x1FFFFu) * 64 + lane];
#pragma unroll
    for (int j = 0; j < 8; ++j) {
      int loc = (int)((pk[j] >> 17) & 0x3Fu);
      float eav = __uint_as_float((unsigned)((pk[j] >> 23) & 0xFFFFu) << 16);
      float v0 = fmaf(eav, wl0, __uint_as_float(v[j] << 16));
      float v1 = fmaf(eav, wl1, __uint_as_float(v[j] & 0xFFFF0000u));
      atomicMin(&st[loc * STP + lane], fenc32(v0));
      atomicMin(&st[loc * STP + 64 + lane], fenc32(v1));
    }
  }
  for (; i < i1; ++i) {
    unsigned long long pk = csr[i];
    unsigned v = mNp[(size_t)(unsigned)(pk & 0x1FFFFu) * 64 + lane];
    int loc = (int)((pk >> 17) & 0x3Fu);
    float eav = __uint_as_float((unsigned)((pk >> 23) & 0xFFFFu) << 16);
    float v0 = fmaf(eav, wl0, __uint_as_float(v << 16));
    float v1 = fmaf(eav, wl1, __uint_as_float(v & 0xFFFF0000u));
    atomicMin(&st[loc * STP + lane], fenc32(v0));
    atomicMin(&st[loc * STP + 64 + lane], fenc32(v1));
  }
  __syncthreads();

  // ---- phase 2: 4 waves, each 16 nodes x 128 cols ----
  if (wv < 4) {
    int l15 = lane & 15, lg = lane >> 4;
    int nodeRowL = (wv << 4) + l15;
    // A-frags: decode min-state (+b_msg) to bf16
    u16x8 a2[4];
#pragma unroll
    for (int kt = 0; kt < 4; ++kt) {
      int cb = kt * 32 + lg * 8;
      const unsigned* pr = &st[nodeRowL * STP + cb];
      u16x8 t;
#pragma unroll
      for (int j = 0; j < 8; ++j) {
        unsigned e = pr[j];
        float f = (e == 0xFFFFFFFFu) ? 0.f : (fdec32(e) + bmsh[cb + j]);
        t[j] = f2bf(f);
      }
      a2[kt] = t;
    }
    int n0 = (b << 6) + (wv << 4);
    float ps[4] = {0.f, 0.f, 0.f, 0.f};
    f32x4 zero = {0.f, 0.f, 0.f, 0.f};
#pragma unroll
    for (int nh = 0; nh < 2; ++nh) {
      f32x4 acc[4];
#pragma unroll
      for (int q = 0; q < 4; ++q) acc[q] = zero;
#pragma unroll
      for (int kt = 0; kt < 4; ++kt)
#pragma unroll
        for (int q = 0; q < 4; ++q) {
          int nt = nh * 4 + q;
          u16x8 bf = *(const u16x8*)&W2t[((nt << 4) + l15) * 128 + kt * 32 + lg * 8];
          acc[q] = mfma_bf16(a2[kt], bf, acc[q]);
        }
#pragma unroll
      for (int q = 0; q < 4; ++q) {
        int j = (nh * 4 + q) * 16 + l15;
        float w = Wdec[j];
#pragma unroll
        for (int r = 0; r < 4; ++r) {
          int node = n0 + (lg << 2) + r; if (node > NN - 1) node = NN - 1;
          float huv = h2f(hu16[(size_t)node * HID + j]);
          ps[r] += (acc[q][r] + huv) * w;
        }
      }
    }
#pragma unroll
    for (int m = 1; m < 16; m <<= 1) {
#pragma unroll
      for (int r = 0; r < 4; ++r) ps[r] += __shfl_xor(ps[r], m);
    }
    if (l15 == 0) {
      float bd = *bdec;
      float v0 = 1.f / (1.f + expf(-(ps[0] + bd)));
      float v1 = 1.f / (1.f + expf(-(ps[1] + bd)));
      float v2 = 1.f / (1.f + expf(-(ps[2] + bd)));
      float v3 = 1.f / (1.f + expf(-(ps[3] + bd)));
      int nw = n0 + (lg << 2);
      if (nw + 3 < NN) {
        float4 st4; st4.x = v0; st4.y = v1; st4.z = v2; st4.w = v3;
        *(float4*)&out[nw] = st4;
      } else {
        if (nw + 0 < NN) out[nw + 0] = v0;
        if (nw + 1 < NN) out[nw + 1] = v1;
        if (nw + 2 < NN) out[nw + 2] = v2;
        if (nw + 3 < NN) out[nw + 3] = v3;
      }
    }
  }
}

extern "C" void kernel_launch(void* const* d_in, const int* in_sizes, int n_in,
                              void* d_out, int out_size, void* d_ws, size_t ws_size,
                              hipStream_t stream) {
  const float* x    = (const float*)d_in[0];
  const int*   ei   = (const int*)d_in[1];
  const float* ea   = (const float*)d_in[2];
  const float* Wenc = (const float*)d_in[3];
  const float* benc = (const float*)d_in[4];
  const float* Wmsg = (const float*)d_in[5];
  const float* bmsg = (const float*)d_in[6];
  const float* Wupd = (const float*)d_in[7];
  const float* bupd = (const float*)d_in[8];
  const float* Wdec = (const float*)d_in[9];
  const float* bdec = (const float*)d_in[10];
  float* out = (float*)d_out;

  // workspace carve (total ~64.1 MiB, below the empirically-safe 65.2 MB)
  char* w = (char*)d_ws;
  auto alloc = [&](size_t bytes) { char* p = w; w += (bytes + 255) & ~(size_t)255; return p; };
  unsigned* mNp        = (unsigned*)alloc((size_t)NN * 64 * 4);             // 25.6 MB (permuted bf16 pairs)
  unsigned short* hu16 = (unsigned short*)alloc((size_t)NN * HID * 2);      // 25.6 MB (f16 update-top)
  unsigned long long* csr = (unsigned long long*)alloc((size_t)NE * 8);     // 12.8 MB
  unsigned short* W2t  = (unsigned short*)alloc(128 * 128 * 2);             // 32 KB
  int* gh      = (int*)alloc((size_t)NBUCK * 4);
  int* offs    = (int*)alloc((size_t)(NBUCK + 1) * 4);
  int* gcursor = (int*)alloc((size_t)NBUCK * 4);
  int* flag    = (int*)alloc(256);

  k_detect<<<1, 64, 0, stream>>>(ei, flag);
  hipMemsetAsync(gh, 0, (size_t)NBUCK * 4, stream);
  k_prep<<<(128 * 128 + 511) / 512, 512, 0, stream>>>(Wupd, W2t);
  k_enc2<<<(NN + 127) / 128, 512, 0, stream>>>(x, Wenc, benc, Wmsg, Wupd, bupd, mNp, hu16);
  k_hist<<<(NE + 4095) / 4096, 256, 0, stream>>>(ei, flag, gh);
  k_scan<<<1, 1024, 0, stream>>>(gh, offs, gcursor);
  k_sortscatter<<<(NE + 8191) / 8192, 256, 0, stream>>>(ei, ea, flag, gcursor, csr);
  k_msg<<<NBUCK, 512, 0, stream>>>(mNp, Wmsg, offs, csr, bmsg, hu16, W2t, Wdec, bdec, out);
}

// Round 8
// 182.988 us; speedup vs baseline: 3.3984x; 1.1440x over previous
//
#include <hip/hip_runtime.h>

#define NN 100000
#define NE 1600000
#define HID 128
#define NBUCK 1563          // ceil(NN/64), 64-node buckets
#define STP 130             // padded LDS stride (f32 words) for min-state
#define SENT 3.0e38f

typedef float f32x4 __attribute__((ext_vector_type(4)));
typedef __bf16 bf16x8 __attribute__((ext_vector_type(8)));
typedef unsigned short u16x8 __attribute__((ext_vector_type(8)));

static __device__ __forceinline__ unsigned short f2bf(float f) {
  union { float f; unsigned u; } v; v.f = f;
  unsigned u = v.u;
  return (unsigned short)((u + 0x7FFFu + ((u >> 16) & 1u)) >> 16);
}

static __device__ __forceinline__ f32x4 mfma_bf16(u16x8 a, u16x8 b, f32x4 c) {
  return __builtin_amdgcn_mfma_f32_16x16x32_bf16(
      __builtin_bit_cast(bf16x8, a), __builtin_bit_cast(bf16x8, b), c, 0, 0, 0);
}

// edge_index may arrive as int32 or int64 (values < 2^31, little-endian).
static __device__ __forceinline__ int gidx(const int* __restrict__ ei, int is64, long long pos) {
  return is64 ? ei[pos * 2] : ei[pos];
}

// ---------------- dtype detection ----------------
__global__ void k_detect(const int* __restrict__ ei, int* __restrict__ flag) {
  unsigned long long b = __ballot(ei[2 * threadIdx.x + 1] == 0);
  if (threadIdx.x == 0) *flag = (b == ~0ull) ? 1 : 0;
}

// ---------------- one-time prep: v[k] = sum_j W_upd[128+k][j] * W_dec[j] ----------------
__global__ __launch_bounds__(128) void k_prep(const float* __restrict__ Wupd,
    const float* __restrict__ Wdec, float* __restrict__ vprep) {
  int k = threadIdx.x;
  const float* row = Wupd + (size_t)(128 + k) * 128;
  float s = 0.f;
#pragma unroll 8
  for (int j = 0; j < 128; ++j) s = fmaf(row[j], Wdec[j], s);
  vprep[k] = s;
}

// ---------------- encoder + message projection + update-top decode fused ----------------
// h = relu(x @ W_enc + b_enc)   (LDS only)
// mNp = perm(h @ W_msg[0:128])  bf16 pairs: word l = col l | col(l+64)<<16
// hdec = (h @ W_upd[0:128] + b_upd) . W_dec   (one f32 per node)
__global__ __launch_bounds__(512) void k_enc2(const float* __restrict__ x,
    const float* __restrict__ Wenc, const float* __restrict__ benc,
    const float* __restrict__ Wmsg, const float* __restrict__ Wupd,
    const float* __restrict__ bupd, const float* __restrict__ Wdec,
    unsigned* __restrict__ mNp, float* __restrict__ hdec) {
  __shared__ unsigned short WtE[128 * 136];
  __shared__ unsigned short WtM[128 * 136];
  __shared__ unsigned short WtU[128 * 136];
  __shared__ float bshE[128];
  __shared__ float bshU[128];
  __shared__ float wdsh[128];
  __shared__ unsigned short bounce[8][16 * 136];
  int tid = threadIdx.x;
  for (int idx = tid; idx < 128 * 128; idx += 512) {
    int k = idx >> 7, j = idx & 127;
    WtE[j * 136 + k] = f2bf(Wenc[idx]);
    WtM[j * 136 + k] = f2bf(Wmsg[idx]);
    WtU[j * 136 + k] = f2bf(Wupd[idx]);
  }
  if (tid < 128) { bshE[tid] = benc[tid]; bshU[tid] = bupd[tid]; wdsh[tid] = Wdec[tid]; }
  __syncthreads();

  int wave = tid >> 6, lane = tid & 63;
  int l15 = lane & 15, lg = lane >> 4;
  int rowBase = blockIdx.x * 128 + wave * 16;
  int nodeA = rowBase + l15; if (nodeA > NN - 1) nodeA = NN - 1;

  // ---- stage 1: h ----
  u16x8 af[4];
#pragma unroll
  for (int kt = 0; kt < 4; ++kt) {
    const float* px = x + (long long)nodeA * HID + kt * 32 + lg * 8;
    f32x4 a0 = *(const f32x4*)px;
    f32x4 a1 = *(const f32x4*)(px + 4);
    u16x8 t;
    t[0] = f2bf(a0[0]); t[1] = f2bf(a0[1]); t[2] = f2bf(a0[2]); t[3] = f2bf(a0[3]);
    t[4] = f2bf(a1[0]); t[5] = f2bf(a1[1]); t[6] = f2bf(a1[2]); t[7] = f2bf(a1[3]);
    af[kt] = t;
  }
  f32x4 zero = {0.f, 0.f, 0.f, 0.f};
  f32x4 acc[8];
#pragma unroll
  for (int nt = 0; nt < 8; ++nt) acc[nt] = zero;
#pragma unroll
  for (int kt = 0; kt < 4; ++kt)
#pragma unroll
    for (int nt = 0; nt < 8; ++nt) {
      u16x8 bfv = *(const u16x8*)&WtE[(nt * 16 + l15) * 136 + kt * 32 + lg * 8];
      acc[nt] = mfma_bf16(af[kt], bfv, acc[nt]);
    }
#pragma unroll
  for (int nt = 0; nt < 8; ++nt) {
    int j = nt * 16 + l15;
    float bj = bshE[j];
#pragma unroll
    for (int r = 0; r < 4; ++r) {
      float v = acc[nt][r] + bj;
      v = v > 0.f ? v : 0.f;
      bounce[wave][(lg * 4 + r) * 136 + j] = f2bf(v);
    }
  }
  // h fragments (A for stages 2 & 3)
  u16x8 ha[4];
#pragma unroll
  for (int kt = 0; kt < 4; ++kt)
    ha[kt] = *(const u16x8*)&bounce[wave][l15 * 136 + kt * 32 + lg * 8];
  asm volatile("s_waitcnt lgkmcnt(0)" ::: "memory");
  __builtin_amdgcn_sched_barrier(0);

  // ---- stage 2: mN = h @ W_msg ----
  f32x4 acc2[8];
#pragma unroll
  for (int nt = 0; nt < 8; ++nt) acc2[nt] = zero;
#pragma unroll
  for (int kt = 0; kt < 4; ++kt)
#pragma unroll
    for (int nt = 0; nt < 8; ++nt) {
      u16x8 bfv = *(const u16x8*)&WtM[(nt * 16 + l15) * 136 + kt * 32 + lg * 8];
      acc2[nt] = mfma_bf16(ha[kt], bfv, acc2[nt]);
    }
#pragma unroll
  for (int nt = 0; nt < 8; ++nt) {
    int j = nt * 16 + l15;
#pragma unroll
    for (int r = 0; r < 4; ++r)
      bounce[wave][(lg * 4 + r) * 136 + j] = f2bf(acc2[nt][r]);
  }
  asm volatile("s_waitcnt lgkmcnt(0)" ::: "memory");
  __builtin_amdgcn_sched_barrier(0);
  // permuted store: word l = col l | col(l+64)<<16
#pragma unroll 4
  for (int row = 0; row < 16; ++row) {
    int node = rowBase + row;
    if (node < NN) {
      unsigned lo = bounce[wave][row * 136 + lane];
      unsigned hi = bounce[wave][row * 136 + 64 + lane];
      mNp[(size_t)node * 64 + lane] = lo | (hi << 16);
    }
  }

  // ---- stage 3: hdec = (h @ W_upd_top + b_upd) . W_dec ----
  f32x4 acc3[8];
#pragma unroll
  for (int nt = 0; nt < 8; ++nt) acc3[nt] = zero;
#pragma unroll
  for (int kt = 0; kt < 4; ++kt)
#pragma unroll
    for (int nt = 0; nt < 8; ++nt) {
      u16x8 bfv = *(const u16x8*)&WtU[(nt * 16 + l15) * 136 + kt * 32 + lg * 8];
      acc3[nt] = mfma_bf16(ha[kt], bfv, acc3[nt]);
    }
  float hs0 = 0.f, hs1 = 0.f, hs2 = 0.f, hs3 = 0.f;
#pragma unroll
  for (int nt = 0; nt < 8; ++nt) {
    int j = nt * 16 + l15;
    float bu = bshU[j], wv = wdsh[j];
    hs0 += (acc3[nt][0] + bu) * wv;
    hs1 += (acc3[nt][1] + bu) * wv;
    hs2 += (acc3[nt][2] + bu) * wv;
    hs3 += (acc3[nt][3] + bu) * wv;
  }
#pragma unroll
  for (int m = 1; m < 16; m <<= 1) {
    hs0 += __shfl_xor(hs0, m);
    hs1 += __shfl_xor(hs1, m);
    hs2 += __shfl_xor(hs2, m);
    hs3 += __shfl_xor(hs3, m);
  }
  if (l15 == 0) {
    int n0 = rowBase + lg * 4;
    if (n0 + 3 < NN) {
      float4 st4; st4.x = hs0; st4.y = hs1; st4.z = hs2; st4.w = hs3;
      *(float4*)&hdec[n0] = st4;
    } else {
      if (n0 + 0 < NN) hdec[n0 + 0] = hs0;
      if (n0 + 1 < NN) hdec[n0 + 1] = hs1;
      if (n0 + 2 < NN) hdec[n0 + 2] = hs2;
      if (n0 + 3 < NN) hdec[n0 + 3] = hs3;
    }
  }
}

// ---------------- bucket histogram (LDS pre-aggregated) ----------------
__global__ __launch_bounds__(256) void k_hist(const int* __restrict__ ei,
    const int* __restrict__ flag, int* __restrict__ gh) {
  __shared__ unsigned cnt[NBUCK];
  int tid = threadIdx.x;
  for (int i = tid; i < NBUCK; i += 256) cnt[i] = 0;
  __syncthreads();
  int is64 = *flag;
  long long base = (long long)blockIdx.x * 4096;
  int n = (int)(((long long)NE - base < 4096) ? ((long long)NE - base) : 4096);
  for (int i = tid; i < n; i += 256) {
    int d = gidx(ei, is64, (long long)NE + base + i);
    atomicAdd(&cnt[d >> 6], 1u);
  }
  __syncthreads();
  for (int i = tid; i < NBUCK; i += 256)
    if (cnt[i]) atomicAdd(&gh[i], (int)cnt[i]);
}

// ---------------- scan 1563 buckets -> offsets + cursors ----------------
__global__ __launch_bounds__(1024) void k_scan(const int* __restrict__ gh,
    int* __restrict__ offs, int* __restrict__ gcursor) {
  __shared__ int sc[1024];
  int t = threadIdx.x;
  int e0 = (2 * t < NBUCK) ? gh[2 * t] : 0;
  int e1 = (2 * t + 1 < NBUCK) ? gh[2 * t + 1] : 0;
  int pair = e0 + e1;
  sc[t] = pair;
  __syncthreads();
  for (int s = 1; s < 1024; s <<= 1) {
    int a = (t >= s) ? sc[t - s] : 0;
    __syncthreads();
    sc[t] += a;
    __syncthreads();
  }
  int base = sc[t] - pair;
  if (2 * t < NBUCK)     { offs[2 * t] = base;          gcursor[2 * t] = base; }
  if (2 * t + 1 < NBUCK) { offs[2 * t + 1] = base + e0; gcursor[2 * t + 1] = base + e0; }
  if (t == 0) offs[NBUCK] = NE;
}

// ---------------- chunk-sorted scatter ----------------
// entry u64: src(17b @0) | local(6b @17) | ea_bf16(16b @48)  (hi word = ea f32 bits>>16<<16)
__global__ __launch_bounds__(256) void k_sortscatter(const int* __restrict__ ei,
    const float* __restrict__ ea, const int* __restrict__ flag,
    int* __restrict__ gcursor, unsigned long long* __restrict__ csr) {
  __shared__ unsigned cnt[NBUCK];
  __shared__ unsigned gbase[NBUCK];
  int tid = threadIdx.x;
  long long base = (long long)blockIdx.x * 8192;
  int n = (int)(((long long)NE - base < 8192) ? ((long long)NE - base) : 8192);
  for (int i = tid; i < NBUCK; i += 256) cnt[i] = 0;
  __syncthreads();
  int is64 = *flag;
  for (int i = tid; i < n; i += 256) {
    int d = gidx(ei, is64, (long long)NE + base + i);
    atomicAdd(&cnt[d >> 6], 1u);
  }
  __syncthreads();
  for (int b = tid; b < NBUCK; b += 256) {
    unsigned c = cnt[b];
    gbase[b] = c ? (unsigned)atomicAdd(&gcursor[b], (int)c) : 0u;
  }
  __syncthreads();
  for (int i = tid; i < NBUCK; i += 256) cnt[i] = 0;   // reuse as local cursor
  __syncthreads();
  for (int i = tid; i < n; i += 256) {
    int s = gidx(ei, is64, base + i);
    int d = gidx(ei, is64, (long long)NE + base + i);
    unsigned eab = f2bf(ea[base + i]);
    int b = d >> 6;
    unsigned lp = atomicAdd(&cnt[b], 1u);
    csr[gbase[b] + lp] = (unsigned long long)(unsigned)s
                       | ((unsigned long long)(unsigned)(d & 63) << 17)
                       | ((unsigned long long)eab << 48);
  }
}

// ---------------- fused: edge min (native f32 LDS atomicMin) + decoder dot + sigmoid ----------------
// One block owns 64 destination nodes. Phase 1: per-edge gather+fma+ds_min_f32
// (lane-stride-1, conflict-free). Phase 2: out = sigmoid((st+bmsg).v + hdec + bdec).
__global__ __launch_bounds__(512, 8) void k_msg(const unsigned* __restrict__ mNp,
    const float* __restrict__ Wmsg, const int* __restrict__ offs,
    const unsigned long long* __restrict__ csr, const float* __restrict__ bmsg,
    const float* __restrict__ vprep, const float* __restrict__ hdec,
    const float* __restrict__ bdec, float* __restrict__ out) {
  __shared__ float stf[64 * STP];     // 33.3 KB, padded stride
  __shared__ float bmsh[128];
  int tid = threadIdx.x;
  int b = blockIdx.x;
  for (int i = tid; i < 64 * STP; i += 512) stf[i] = SENT;
  if (tid < 128) bmsh[tid] = bmsg[tid];
  __syncthreads();

  int lane = tid & 63;
  int wv = tid >> 6;                     // 0..7
  int off = offs[b], end = offs[b + 1];
  int cntE = end - off;
  int per = (cntE + 7) >> 3;
  int i0 = off + wv * per;
  int i1 = i0 + per; if (i1 > end) i1 = end;
  float wl0 = Wmsg[128 * 128 + lane];
  float wl1 = Wmsg[128 * 128 + 64 + lane];

  int i = i0;
  for (; i + 8 <= i1; i += 8) {
    unsigned long long pk[8];
    unsigned v[8];
#pragma unroll
    for (int j = 0; j < 8; ++j) pk[j] = csr[i + j];
#pragma unroll
    for (int j = 0; j < 8; ++j)
      v[j] = mNp[(size_t)(unsigned)(pk[j] & 0x1FFFFu) * 64 + lane];
#pragma unroll
    for (int j = 0; j < 8; ++j) {
      unsigned lo32 = (unsigned)pk[j];
      int loc = (int)((lo32 >> 17) & 0x3Fu);
      float eav = __uint_as_float((unsigned)(pk[j] >> 32) & 0xFFFF0000u);
      float v0 = fmaf(eav, wl0, __uint_as_float(v[j] << 16));
      float v1 = fmaf(eav, wl1, __uint_as_float(v[j] & 0xFFFF0000u));
      atomicMin(&stf[loc * STP + lane], v0);
      atomicMin(&stf[loc * STP + 64 + lane], v1);
    }
  }
  for (; i < i1; ++i) {
    unsigned long long pk = csr[i];
    unsigned v = mNp[(size_t)(unsigned)(pk & 0x1FFFFu) * 64 + lane];
    int loc = (int)(((unsigned)pk >> 17) & 0x3Fu);
    float eav = __uint_as_float((unsigned)(pk >> 32) & 0xFFFF0000u);
    float v0 = fmaf(eav, wl0, __uint_as_float(v << 16));
    float v1 = fmaf(eav, wl1, __uint_as_float(v & 0xFFFF0000u));
    atomicMin(&stf[loc * STP + lane], v0);
    atomicMin(&stf[loc * STP + 64 + lane], v1);
  }
  __syncthreads();

  // ---- phase 2: out[node] = sigmoid((agg+bmsg).v + hdec + bdec) ----
  float vl0 = vprep[lane], vl1 = vprep[64 + lane];
  float bm0 = bmsh[lane], bm1 = bmsh[64 + lane];
  float bd = *bdec;
#pragma unroll
  for (int q = 0; q < 8; ++q) {
    int loc = (wv << 3) + q;
    float s0 = stf[loc * STP + lane];
    float s1 = stf[loc * STP + 64 + lane];
    float ps = ((s0 < 1.0e30f) ? (s0 + bm0) * vl0 : 0.f)
             + ((s1 < 1.0e30f) ? (s1 + bm1) * vl1 : 0.f);
#pragma unroll
    for (int m = 1; m < 64; m <<= 1) ps += __shfl_xor(ps, m);
    if (lane == 0) {
      int node = (b << 6) + loc;
      if (node < NN)
        out[node] = 1.f / (1.f + expf(-(ps + hdec[node] + bd)));
    }
  }
}

extern "C" void kernel_launch(void* const* d_in, const int* in_sizes, int n_in,
                              void* d_out, int out_size, void* d_ws, size_t ws_size,
                              hipStream_t stream) {
  const float* x    = (const float*)d_in[0];
  const int*   ei   = (const int*)d_in[1];
  const float* ea   = (const float*)d_in[2];
  const float* Wenc = (const float*)d_in[3];
  const float* benc = (const float*)d_in[4];
  const float* Wmsg = (const float*)d_in[5];
  const float* bmsg = (const float*)d_in[6];
  const float* Wupd = (const float*)d_in[7];
  const float* bupd = (const float*)d_in[8];
  const float* Wdec = (const float*)d_in[9];
  const float* bdec = (const float*)d_in[10];
  float* out = (float*)d_out;

  // workspace carve (total ~39 MiB, well below the empirically-safe 65.2 MB)
  char* w = (char*)d_ws;
  auto alloc = [&](size_t bytes) { char* p = w; w += (bytes + 255) & ~(size_t)255; return p; };
  unsigned* mNp        = (unsigned*)alloc((size_t)NN * 64 * 4);             // 25.6 MB (permuted bf16 pairs)
  unsigned long long* csr = (unsigned long long*)alloc((size_t)NE * 8);     // 12.8 MB
  float* hdec  = (float*)alloc((size_t)NN * 4);                             // 0.4 MB
  float* vprep = (float*)alloc(128 * 4);
  int* gh      = (int*)alloc((size_t)NBUCK * 4);
  int* offs    = (int*)alloc((size_t)(NBUCK + 1) * 4);
  int* gcursor = (int*)alloc((size_t)NBUCK * 4);
  int* flag    = (int*)alloc(256);

  k_detect<<<1, 64, 0, stream>>>(ei, flag);
  hipMemsetAsync(gh, 0, (size_t)NBUCK * 4, stream);
  k_prep<<<1, 128, 0, stream>>>(Wupd, Wdec, vprep);
  k_enc2<<<(NN + 127) / 128, 512, 0, stream>>>(x, Wenc, benc, Wmsg, Wupd, bupd, Wdec, mNp, hdec);
  k_hist<<<(NE + 4095) / 4096, 256, 0, stream>>>(ei, flag, gh);
  k_scan<<<1, 1024, 0, stream>>>(gh, offs, gcursor);
  k_sortscatter<<<(NE + 8191) / 8192, 256, 0, stream>>>(ei, ea, flag, gcursor, csr);
  k_msg<<<NBUCK, 512, 0, stream>>>(mNp, Wmsg, offs, csr, bmsg, vprep, hdec, bdec, out);
}

// Round 9
// 159.643 us; speedup vs baseline: 3.8953x; 1.1462x over previous
//
#include <hip/hip_runtime.h>

#define NN 100000
#define NE 1600000
#define HID 128
#define NBUCK 1563          // ceil(NN/64), 64-node buckets
#define STP 130             // padded LDS stride (f32 words) for min-state
#define SENT 3.0e38f
#define CH 8192             // edges per sort chunk
#define NCH 196             // ceil(NE/CH)
#define ENCB 782            // encoder blocks in k_enc2h

typedef float f32x4 __attribute__((ext_vector_type(4)));
typedef __bf16 bf16x8 __attribute__((ext_vector_type(8)));
typedef unsigned short u16x8 __attribute__((ext_vector_type(8)));

static __device__ __forceinline__ unsigned short f2bf(float f) {
  union { float f; unsigned u; } v; v.f = f;
  unsigned u = v.u;
  return (unsigned short)((u + 0x7FFFu + ((u >> 16) & 1u)) >> 16);
}

static __device__ __forceinline__ f32x4 mfma_bf16(u16x8 a, u16x8 b, f32x4 c) {
  return __builtin_amdgcn_mfma_f32_16x16x32_bf16(
      __builtin_bit_cast(bf16x8, a), __builtin_bit_cast(bf16x8, b), c, 0, 0, 0);
}

// edge_index may arrive as int32 or int64 (values < 2^31, little-endian).
static __device__ __forceinline__ int gidx(const int* __restrict__ ei, int is64, long long pos) {
  return is64 ? ei[pos * 2] : ei[pos];
}
// inline dtype detection: for int64, hi-words of src[0..63] are all zero
static __device__ __forceinline__ int detect64(const int* __restrict__ ei, int tid) {
  unsigned long long bl = __ballot(ei[2 * (tid & 63) + 1] == 0);
  return (bl == ~0ull) ? 1 : 0;
}

// ---------------- encoder(+msg proj+upd-top decode) blocks 0..781 | hist blocks 782..977 ----------------
__global__ __launch_bounds__(512) void k_enc2h(const float* __restrict__ x,
    const float* __restrict__ Wenc, const float* __restrict__ benc,
    const float* __restrict__ Wmsg, const float* __restrict__ Wupd,
    const float* __restrict__ bupd, const float* __restrict__ Wdec,
    const int* __restrict__ ei,
    unsigned* __restrict__ mNp, float* __restrict__ hdec,
    unsigned* __restrict__ C, int* __restrict__ gh) {
  __shared__ unsigned short WtE[128 * 136];
  __shared__ unsigned short WtM[128 * 136];
  __shared__ unsigned short WtU[128 * 136];
  __shared__ float bshE[128];
  __shared__ float bshU[128];
  __shared__ float wdsh[128];
  __shared__ unsigned short bounce[8][16 * 136];
  int tid = threadIdx.x;

  if (blockIdx.x >= ENCB) {
    // ---------- histogram chunk ----------
    int chunk = blockIdx.x - ENCB;
    long long base = (long long)chunk * CH;
    int n = (int)(((long long)NE - base < CH) ? ((long long)NE - base) : CH);
    int is64 = detect64(ei, tid);
    unsigned* cnt = (unsigned*)WtE;      // alias LDS
    for (int i = tid; i < NBUCK; i += 512) cnt[i] = 0;
    __syncthreads();
    for (int i = tid; i < n; i += 512) {
      int d = gidx(ei, is64, (long long)NE + base + i);
      atomicAdd(&cnt[d >> 6], 1u);
    }
    __syncthreads();
    for (int i = tid; i < NBUCK; i += 512) {
      unsigned c = cnt[i];
      C[(size_t)chunk * NBUCK + i] = c;
      if (c) atomicAdd(&gh[i], (int)c);
    }
    return;
  }

  // ---------- encoder path ----------
  for (int idx = tid; idx < 128 * 128; idx += 512) {
    int k = idx >> 7, j = idx & 127;
    WtE[j * 136 + k] = f2bf(Wenc[idx]);
    WtM[j * 136 + k] = f2bf(Wmsg[idx]);
    WtU[j * 136 + k] = f2bf(Wupd[idx]);
  }
  if (tid < 128) { bshE[tid] = benc[tid]; bshU[tid] = bupd[tid]; wdsh[tid] = Wdec[tid]; }
  __syncthreads();

  int wave = tid >> 6, lane = tid & 63;
  int l15 = lane & 15, lg = lane >> 4;
  int rowBase = blockIdx.x * 128 + wave * 16;
  int nodeA = rowBase + l15; if (nodeA > NN - 1) nodeA = NN - 1;

  // ---- stage 1: h ----
  u16x8 af[4];
#pragma unroll
  for (int kt = 0; kt < 4; ++kt) {
    const float* px = x + (long long)nodeA * HID + kt * 32 + lg * 8;
    f32x4 a0 = *(const f32x4*)px;
    f32x4 a1 = *(const f32x4*)(px + 4);
    u16x8 t;
    t[0] = f2bf(a0[0]); t[1] = f2bf(a0[1]); t[2] = f2bf(a0[2]); t[3] = f2bf(a0[3]);
    t[4] = f2bf(a1[0]); t[5] = f2bf(a1[1]); t[6] = f2bf(a1[2]); t[7] = f2bf(a1[3]);
    af[kt] = t;
  }
  f32x4 zero = {0.f, 0.f, 0.f, 0.f};
  f32x4 acc[8];
#pragma unroll
  for (int nt = 0; nt < 8; ++nt) acc[nt] = zero;
#pragma unroll
  for (int kt = 0; kt < 4; ++kt)
#pragma unroll
    for (int nt = 0; nt < 8; ++nt) {
      u16x8 bfv = *(const u16x8*)&WtE[(nt * 16 + l15) * 136 + kt * 32 + lg * 8];
      acc[nt] = mfma_bf16(af[kt], bfv, acc[nt]);
    }
#pragma unroll
  for (int nt = 0; nt < 8; ++nt) {
    int j = nt * 16 + l15;
    float bj = bshE[j];
#pragma unroll
    for (int r = 0; r < 4; ++r) {
      float v = acc[nt][r] + bj;
      v = v > 0.f ? v : 0.f;
      bounce[wave][(lg * 4 + r) * 136 + j] = f2bf(v);
    }
  }
  u16x8 ha[4];
#pragma unroll
  for (int kt = 0; kt < 4; ++kt)
    ha[kt] = *(const u16x8*)&bounce[wave][l15 * 136 + kt * 32 + lg * 8];
  asm volatile("s_waitcnt lgkmcnt(0)" ::: "memory");
  __builtin_amdgcn_sched_barrier(0);

  // ---- stage 2: mN = h @ W_msg ----
  f32x4 acc2[8];
#pragma unroll
  for (int nt = 0; nt < 8; ++nt) acc2[nt] = zero;
#pragma unroll
  for (int kt = 0; kt < 4; ++kt)
#pragma unroll
    for (int nt = 0; nt < 8; ++nt) {
      u16x8 bfv = *(const u16x8*)&WtM[(nt * 16 + l15) * 136 + kt * 32 + lg * 8];
      acc2[nt] = mfma_bf16(ha[kt], bfv, acc2[nt]);
    }
#pragma unroll
  for (int nt = 0; nt < 8; ++nt) {
    int j = nt * 16 + l15;
#pragma unroll
    for (int r = 0; r < 4; ++r)
      bounce[wave][(lg * 4 + r) * 136 + j] = f2bf(acc2[nt][r]);
  }
  asm volatile("s_waitcnt lgkmcnt(0)" ::: "memory");
  __builtin_amdgcn_sched_barrier(0);
  // permuted store: word l = col l | col(l+64)<<16
#pragma unroll 4
  for (int row = 0; row < 16; ++row) {
    int node = rowBase + row;
    if (node < NN) {
      unsigned lo = bounce[wave][row * 136 + lane];
      unsigned hi = bounce[wave][row * 136 + 64 + lane];
      mNp[(size_t)node * 64 + lane] = lo | (hi << 16);
    }
  }

  // ---- stage 3: hdec = (h @ W_upd_top + b_upd) . W_dec ----
  f32x4 acc3[8];
#pragma unroll
  for (int nt = 0; nt < 8; ++nt) acc3[nt] = zero;
#pragma unroll
  for (int kt = 0; kt < 4; ++kt)
#pragma unroll
    for (int nt = 0; nt < 8; ++nt) {
      u16x8 bfv = *(const u16x8*)&WtU[(nt * 16 + l15) * 136 + kt * 32 + lg * 8];
      acc3[nt] = mfma_bf16(ha[kt], bfv, acc3[nt]);
    }
  float hs0 = 0.f, hs1 = 0.f, hs2 = 0.f, hs3 = 0.f;
#pragma unroll
  for (int nt = 0; nt < 8; ++nt) {
    int j = nt * 16 + l15;
    float bu = bshU[j], wv = wdsh[j];
    hs0 += (acc3[nt][0] + bu) * wv;
    hs1 += (acc3[nt][1] + bu) * wv;
    hs2 += (acc3[nt][2] + bu) * wv;
    hs3 += (acc3[nt][3] + bu) * wv;
  }
#pragma unroll
  for (int m = 1; m < 16; m <<= 1) {
    hs0 += __shfl_xor(hs0, m);
    hs1 += __shfl_xor(hs1, m);
    hs2 += __shfl_xor(hs2, m);
    hs3 += __shfl_xor(hs3, m);
  }
  if (l15 == 0) {
    int n0 = rowBase + lg * 4;
    if (n0 + 3 < NN) {
      float4 st4; st4.x = hs0; st4.y = hs1; st4.z = hs2; st4.w = hs3;
      *(float4*)&hdec[n0] = st4;
    } else {
      if (n0 + 0 < NN) hdec[n0 + 0] = hs0;
      if (n0 + 1 < NN) hdec[n0 + 1] = hs1;
      if (n0 + 2 < NN) hdec[n0 + 2] = hs2;
      if (n0 + 3 < NN) hdec[n0 + 3] = hs3;
    }
  }
}

// ---------------- scan 1563 bucket totals -> offs; threads 0-127 also build vprep ----------------
__global__ __launch_bounds__(1024) void k_scan(const int* __restrict__ gh,
    int* __restrict__ offs, const float* __restrict__ Wupd,
    const float* __restrict__ Wdec, float* __restrict__ vprep) {
  __shared__ int sc[1024];
  int t = threadIdx.x;
  int e0 = (2 * t < NBUCK) ? gh[2 * t] : 0;
  int e1 = (2 * t + 1 < NBUCK) ? gh[2 * t + 1] : 0;
  int pair = e0 + e1;
  sc[t] = pair;
  __syncthreads();
  for (int s = 1; s < 1024; s <<= 1) {
    int a = (t >= s) ? sc[t - s] : 0;
    __syncthreads();
    sc[t] += a;
    __syncthreads();
  }
  int base = sc[t] - pair;
  if (2 * t < NBUCK)     offs[2 * t] = base;
  if (2 * t + 1 < NBUCK) offs[2 * t + 1] = base + e0;
  if (t == 0) offs[NBUCK] = NE;
  // vprep[k] = sum_j W_upd[128+k][j] * W_dec[j]
  if (t < 128) {
    const float* row = Wupd + (size_t)(128 + t) * 128;
    float s = 0.f;
#pragma unroll 8
    for (int j = 0; j < 128; ++j) s = fmaf(row[j], Wdec[j], s);
    vprep[t] = s;
  }
}

// ---------------- column scan: C[chunk][b] -> absolute base of that chunk's run in bucket b ----------------
__global__ __launch_bounds__(256) void k_scanC(unsigned* __restrict__ C,
    const int* __restrict__ offs) {
  int b = blockIdx.x * 256 + threadIdx.x;
  if (b >= NBUCK) return;
  unsigned run = (unsigned)offs[b];
  for (int c = 0; c < NCH; ++c) {
    size_t idx = (size_t)c * NBUCK + b;
    unsigned tmp = C[idx];
    C[idx] = run;
    run += tmp;
  }
}

// ---------------- single-pass sorted scatter ----------------
// entry u64: (src*64) 23b @0 | local(6b) @23 | ea_bf16(16b) @48
__global__ __launch_bounds__(512) void k_sortscatter(const int* __restrict__ ei,
    const float* __restrict__ ea, const unsigned* __restrict__ C,
    unsigned long long* __restrict__ csr) {
  __shared__ unsigned gbase[NBUCK];
  __shared__ unsigned cnt[NBUCK];
  int tid = threadIdx.x;
  int chunk = blockIdx.x;
  long long base = (long long)chunk * CH;
  int n = (int)(((long long)NE - base < CH) ? ((long long)NE - base) : CH);
  int is64 = detect64(ei, tid);
  for (int i = tid; i < NBUCK; i += 512) {
    gbase[i] = C[(size_t)chunk * NBUCK + i];
    cnt[i] = 0;
  }
  __syncthreads();
  for (int i = tid; i < n; i += 512) {
    int s = gidx(ei, is64, base + i);
    int d = gidx(ei, is64, (long long)NE + base + i);
    unsigned eab = f2bf(ea[base + i]);
    int b = d >> 6;
    unsigned lp = atomicAdd(&cnt[b], 1u);
    unsigned lo = (unsigned)(s << 6) | ((unsigned)(d & 63) << 23);
    csr[gbase[b] + lp] = (unsigned long long)lo | ((unsigned long long)eab << 48);
  }
}

// ---------------- fused: edge min (native f32 LDS atomicMin) + decoder dot + sigmoid ----------------
__global__ __launch_bounds__(512, 8) void k_msg(const unsigned* __restrict__ mNp,
    const float* __restrict__ Wmsg, const int* __restrict__ offs,
    const unsigned long long* __restrict__ csr, const float* __restrict__ bmsg,
    const float* __restrict__ vprep, const float* __restrict__ hdec,
    const float* __restrict__ bdec, float* __restrict__ out) {
  __shared__ float stf[64 * STP];     // 33.3 KB, padded stride
  __shared__ float bmsh[128];
  int tid = threadIdx.x;
  int b = blockIdx.x;
  for (int i = tid; i < 64 * STP; i += 512) stf[i] = SENT;
  if (tid < 128) bmsh[tid] = bmsg[tid];
  __syncthreads();

  int lane = tid & 63;
  int wv = tid >> 6;                     // 0..7
  int off = offs[b], end = offs[b + 1];
  int cntE = end - off;
  int per = (cntE + 7) >> 3;
  int i0 = off + wv * per;
  int i1 = i0 + per; if (i1 > end) i1 = end;
  float wl0 = Wmsg[128 * 128 + lane];
  float wl1 = Wmsg[128 * 128 + 64 + lane];

  int i = i0;
  for (; i + 8 <= i1; i += 8) {
    unsigned long long pk[8];
    unsigned v[8];
#pragma unroll
    for (int j = 0; j < 8; ++j) pk[j] = csr[i + j];
#pragma unroll
    for (int j = 0; j < 8; ++j)
      v[j] = mNp[((unsigned)pk[j] & 0x7FFFFFu) + lane];
#pragma unroll
    for (int j = 0; j < 8; ++j) {
      unsigned lo32 = (unsigned)pk[j];
      int loc = (int)((lo32 >> 23) & 0x3Fu);
      float eav = __uint_as_float((unsigned)(pk[j] >> 32) & 0xFFFF0000u);
      float v0 = fmaf(eav, wl0, __uint_as_float(v[j] << 16));
      float v1 = fmaf(eav, wl1, __uint_as_float(v[j] & 0xFFFF0000u));
      atomicMin(&stf[loc * STP + lane], v0);
      atomicMin(&stf[loc * STP + 64 + lane], v1);
    }
  }
  for (; i < i1; ++i) {
    unsigned long long pk = csr[i];
    unsigned v = mNp[((unsigned)pk & 0x7FFFFFu) + lane];
    int loc = (int)(((unsigned)pk >> 23) & 0x3Fu);
    float eav = __uint_as_float((unsigned)(pk >> 32) & 0xFFFF0000u);
    float v0 = fmaf(eav, wl0, __uint_as_float(v << 16));
    float v1 = fmaf(eav, wl1, __uint_as_float(v & 0xFFFF0000u));
    atomicMin(&stf[loc * STP + lane], v0);
    atomicMin(&stf[loc * STP + 64 + lane], v1);
  }
  __syncthreads();

  // ---- phase 2: out[node] = sigmoid((agg+bmsg).v + hdec + bdec) ----
  float vl0 = vprep[lane], vl1 = vprep[64 + lane];
  float bm0 = bmsh[lane], bm1 = bmsh[64 + lane];
  float bd = *bdec;
#pragma unroll
  for (int q = 0; q < 8; ++q) {
    int loc = (wv << 3) + q;
    float s0 = stf[loc * STP + lane];
    float s1 = stf[loc * STP + 64 + lane];
    float ps = ((s0 < 1.0e30f) ? (s0 + bm0) * vl0 : 0.f)
             + ((s1 < 1.0e30f) ? (s1 + bm1) * vl1 : 0.f);
#pragma unroll
    for (int m = 1; m < 64; m <<= 1) ps += __shfl_xor(ps, m);
    if (lane == 0) {
      int node = (b << 6) + loc;
      if (node < NN)
        out[node] = 1.f / (1.f + expf(-(ps + hdec[node] + bd)));
    }
  }
}

extern "C" void kernel_launch(void* const* d_in, const int* in_sizes, int n_in,
                              void* d_out, int out_size, void* d_ws, size_t ws_size,
                              hipStream_t stream) {
  const float* x    = (const float*)d_in[0];
  const int*   ei   = (const int*)d_in[1];
  const float* ea   = (const float*)d_in[2];
  const float* Wenc = (const float*)d_in[3];
  const float* benc = (const float*)d_in[4];
  const float* Wmsg = (const float*)d_in[5];
  const float* bmsg = (const float*)d_in[6];
  const float* Wupd = (const float*)d_in[7];
  const float* bupd = (const float*)d_in[8];
  const float* Wdec = (const float*)d_in[9];
  const float* bdec = (const float*)d_in[10];
  float* out = (float*)d_out;

  // workspace carve (total ~41 MiB, well below the empirically-safe 65.2 MB)
  char* w = (char*)d_ws;
  auto alloc = [&](size_t bytes) { char* p = w; w += (bytes + 255) & ~(size_t)255; return p; };
  unsigned* mNp        = (unsigned*)alloc((size_t)NN * 64 * 4);             // 25.6 MB
  unsigned long long* csr = (unsigned long long*)alloc((size_t)NE * 8);     // 12.8 MB
  unsigned* C   = (unsigned*)alloc((size_t)NCH * NBUCK * 4);                // 1.23 MB
  float* hdec   = (float*)alloc((size_t)NN * 4);                            // 0.4 MB
  float* vprep  = (float*)alloc(128 * 4);
  int* gh       = (int*)alloc((size_t)NBUCK * 4);
  int* offs     = (int*)alloc((size_t)(NBUCK + 1) * 4);

  hipMemsetAsync(gh, 0, (size_t)NBUCK * 4, stream);
  k_enc2h<<<ENCB + NCH, 512, 0, stream>>>(x, Wenc, benc, Wmsg, Wupd, bupd, Wdec,
                                          ei, mNp, hdec, C, gh);
  k_scan<<<1, 1024, 0, stream>>>(gh, offs, Wupd, Wdec, vprep);
  k_scanC<<<(NBUCK + 255) / 256, 256, 0, stream>>>(C, offs);
  k_sortscatter<<<NCH, 512, 0, stream>>>(ei, ea, C, csr);
  k_msg<<<NBUCK, 512, 0, stream>>>(mNp, Wmsg, offs, csr, bmsg, vprep, hdec, bdec, out);
}

// Round 10
// 146.046 us; speedup vs baseline: 4.2580x; 1.0931x over previous
//
#include <hip/hip_runtime.h>

#define NN 100000
#define NE 1600000
#define HID 128
#define NBUCK 1563          // ceil(NN/64), 64-node buckets
#define STP 130             // padded LDS stride (f32 words) for min-state
#define SENT 3.0e38f
#define CH 8192             // edges per sort chunk
#define NCH 196             // ceil(NE/CH)
#define ENCB 782            // encoder blocks in k_enc2h

typedef float f32x4 __attribute__((ext_vector_type(4)));
typedef __bf16 bf16x8 __attribute__((ext_vector_type(8)));
typedef unsigned short u16x8 __attribute__((ext_vector_type(8)));

static __device__ __forceinline__ unsigned short f2bf(float f) {
  union { float f; unsigned u; } v; v.f = f;
  unsigned u = v.u;
  return (unsigned short)((u + 0x7FFFu + ((u >> 16) & 1u)) >> 16);
}

static __device__ __forceinline__ f32x4 mfma_bf16(u16x8 a, u16x8 b, f32x4 c) {
  return __builtin_amdgcn_mfma_f32_16x16x32_bf16(
      __builtin_bit_cast(bf16x8, a), __builtin_bit_cast(bf16x8, b), c, 0, 0, 0);
}

// edge_index may arrive as int32 or int64 (values < 2^31, little-endian).
static __device__ __forceinline__ int gidx(const int* __restrict__ ei, int is64, long long pos) {
  return is64 ? ei[pos * 2] : ei[pos];
}
// inline dtype detection: for int64, hi-words of src[0..63] are all zero
static __device__ __forceinline__ int detect64(const int* __restrict__ ei, int tid) {
  unsigned long long bl = __ballot(ei[2 * (tid & 63) + 1] == 0);
  return (bl == ~0ull) ? 1 : 0;
}

// ---------------- encoder(+msg proj+upd-top decode) blocks 0..781 | hist blocks 782..977 ----------------
__global__ __launch_bounds__(512) void k_enc2h(const float* __restrict__ x,
    const float* __restrict__ Wenc, const float* __restrict__ benc,
    const float* __restrict__ Wmsg, const float* __restrict__ Wupd,
    const float* __restrict__ bupd, const float* __restrict__ Wdec,
    const int* __restrict__ ei,
    unsigned* __restrict__ mNp, float* __restrict__ hdec,
    unsigned* __restrict__ C) {
  __shared__ unsigned short WtE[128 * 136];
  __shared__ unsigned short WtM[128 * 136];
  __shared__ unsigned short WtU[128 * 136];
  __shared__ float bshE[128];
  __shared__ float bshU[128];
  __shared__ float wdsh[128];
  __shared__ unsigned short bounce[8][16 * 136];
  int tid = threadIdx.x;

  if (blockIdx.x >= ENCB) {
    // ---------- histogram chunk: write this chunk's bucket-count row ----------
    int chunk = blockIdx.x - ENCB;
    long long base = (long long)chunk * CH;
    int n = (int)(((long long)NE - base < CH) ? ((long long)NE - base) : CH);
    int is64 = detect64(ei, tid);
    unsigned* cnt = (unsigned*)WtE;      // alias LDS
    for (int i = tid; i < NBUCK; i += 512) cnt[i] = 0;
    __syncthreads();
    for (int i = tid; i < n; i += 512) {
      int d = gidx(ei, is64, (long long)NE + base + i);
      atomicAdd(&cnt[d >> 6], 1u);
    }
    __syncthreads();
    for (int i = tid; i < NBUCK; i += 512)
      C[(size_t)chunk * NBUCK + i] = cnt[i];
    return;
  }

  // ---------- encoder path ----------
  for (int idx = tid; idx < 128 * 128; idx += 512) {
    int k = idx >> 7, j = idx & 127;
    WtE[j * 136 + k] = f2bf(Wenc[idx]);
    WtM[j * 136 + k] = f2bf(Wmsg[idx]);
    WtU[j * 136 + k] = f2bf(Wupd[idx]);
  }
  if (tid < 128) { bshE[tid] = benc[tid]; bshU[tid] = bupd[tid]; wdsh[tid] = Wdec[tid]; }
  __syncthreads();

  int wave = tid >> 6, lane = tid & 63;
  int l15 = lane & 15, lg = lane >> 4;
  int rowBase = blockIdx.x * 128 + wave * 16;
  int nodeA = rowBase + l15; if (nodeA > NN - 1) nodeA = NN - 1;

  // ---- stage 1: h ----
  u16x8 af[4];
#pragma unroll
  for (int kt = 0; kt < 4; ++kt) {
    const float* px = x + (long long)nodeA * HID + kt * 32 + lg * 8;
    f32x4 a0 = *(const f32x4*)px;
    f32x4 a1 = *(const f32x4*)(px + 4);
    u16x8 t;
    t[0] = f2bf(a0[0]); t[1] = f2bf(a0[1]); t[2] = f2bf(a0[2]); t[3] = f2bf(a0[3]);
    t[4] = f2bf(a1[0]); t[5] = f2bf(a1[1]); t[6] = f2bf(a1[2]); t[7] = f2bf(a1[3]);
    af[kt] = t;
  }
  f32x4 zero = {0.f, 0.f, 0.f, 0.f};
  f32x4 acc[8];
#pragma unroll
  for (int nt = 0; nt < 8; ++nt) acc[nt] = zero;
#pragma unroll
  for (int kt = 0; kt < 4; ++kt)
#pragma unroll
    for (int nt = 0; nt < 8; ++nt) {
      u16x8 bfv = *(const u16x8*)&WtE[(nt * 16 + l15) * 136 + kt * 32 + lg * 8];
      acc[nt] = mfma_bf16(af[kt], bfv, acc[nt]);
    }
#pragma unroll
  for (int nt = 0; nt < 8; ++nt) {
    int j = nt * 16 + l15;
    float bj = bshE[j];
#pragma unroll
    for (int r = 0; r < 4; ++r) {
      float v = acc[nt][r] + bj;
      v = v > 0.f ? v : 0.f;
      bounce[wave][(lg * 4 + r) * 136 + j] = f2bf(v);
    }
  }
  u16x8 ha[4];
#pragma unroll
  for (int kt = 0; kt < 4; ++kt)
    ha[kt] = *(const u16x8*)&bounce[wave][l15 * 136 + kt * 32 + lg * 8];
  asm volatile("s_waitcnt lgkmcnt(0)" ::: "memory");
  __builtin_amdgcn_sched_barrier(0);

  // ---- stage 2: mN = h @ W_msg ----
  f32x4 acc2[8];
#pragma unroll
  for (int nt = 0; nt < 8; ++nt) acc2[nt] = zero;
#pragma unroll
  for (int kt = 0; kt < 4; ++kt)
#pragma unroll
    for (int nt = 0; nt < 8; ++nt) {
      u16x8 bfv = *(const u16x8*)&WtM[(nt * 16 + l15) * 136 + kt * 32 + lg * 8];
      acc2[nt] = mfma_bf16(ha[kt], bfv, acc2[nt]);
    }
#pragma unroll
  for (int nt = 0; nt < 8; ++nt) {
    int j = nt * 16 + l15;
#pragma unroll
    for (int r = 0; r < 4; ++r)
      bounce[wave][(lg * 4 + r) * 136 + j] = f2bf(acc2[nt][r]);
  }
  asm volatile("s_waitcnt lgkmcnt(0)" ::: "memory");
  __builtin_amdgcn_sched_barrier(0);
  // permuted store: word l = col l | col(l+64)<<16
#pragma unroll 4
  for (int row = 0; row < 16; ++row) {
    int node = rowBase + row;
    if (node < NN) {
      unsigned lo = bounce[wave][row * 136 + lane];
      unsigned hi = bounce[wave][row * 136 + 64 + lane];
      mNp[(size_t)node * 64 + lane] = lo | (hi << 16);
    }
  }

  // ---- stage 3: hdec = (h @ W_upd_top + b_upd) . W_dec ----
  f32x4 acc3[8];
#pragma unroll
  for (int nt = 0; nt < 8; ++nt) acc3[nt] = zero;
#pragma unroll
  for (int kt = 0; kt < 4; ++kt)
#pragma unroll
    for (int nt = 0; nt < 8; ++nt) {
      u16x8 bfv = *(const u16x8*)&WtU[(nt * 16 + l15) * 136 + kt * 32 + lg * 8];
      acc3[nt] = mfma_bf16(ha[kt], bfv, acc3[nt]);
    }
  float hs0 = 0.f, hs1 = 0.f, hs2 = 0.f, hs3 = 0.f;
#pragma unroll
  for (int nt = 0; nt < 8; ++nt) {
    int j = nt * 16 + l15;
    float bu = bshU[j], wv = wdsh[j];
    hs0 += (acc3[nt][0] + bu) * wv;
    hs1 += (acc3[nt][1] + bu) * wv;
    hs2 += (acc3[nt][2] + bu) * wv;
    hs3 += (acc3[nt][3] + bu) * wv;
  }
#pragma unroll
  for (int m = 1; m < 16; m <<= 1) {
    hs0 += __shfl_xor(hs0, m);
    hs1 += __shfl_xor(hs1, m);
    hs2 += __shfl_xor(hs2, m);
    hs3 += __shfl_xor(hs3, m);
  }
  if (l15 == 0) {
    int n0 = rowBase + lg * 4;
    if (n0 + 3 < NN) {
      float4 st4; st4.x = hs0; st4.y = hs1; st4.z = hs2; st4.w = hs3;
      *(float4*)&hdec[n0] = st4;
    } else {
      if (n0 + 0 < NN) hdec[n0 + 0] = hs0;
      if (n0 + 1 < NN) hdec[n0 + 1] = hs1;
      if (n0 + 2 < NN) hdec[n0 + 2] = hs2;
      if (n0 + 3 < NN) hdec[n0 + 3] = hs3;
    }
  }
}

// ---------------- per-bucket wave-parallel prefix over chunks; totals -> gh ----------------
// C[c][b] becomes the EXCLUSIVE prefix (local, no bucket base) of chunk c in bucket b.
__global__ __launch_bounds__(256) void k_colscan(unsigned* __restrict__ C,
    int* __restrict__ gh) {
  int lane = threadIdx.x & 63;
  int b = blockIdx.x * 4 + (threadIdx.x >> 6);
  if (b >= NBUCK) return;
  int cbase = lane * 4;                       // 4 chunks per lane; 49 lanes active
  unsigned vv[4] = {0u, 0u, 0u, 0u};
#pragma unroll
  for (int k = 0; k < 4; ++k)
    if (cbase + k < NCH) vv[k] = C[(size_t)(cbase + k) * NBUCK + b];
  unsigned s0 = vv[0];
  unsigned s1 = s0 + vv[1];
  unsigned s2 = s1 + vv[2];
  unsigned s3 = s2 + vv[3];                   // lane-inclusive sum
  unsigned run = s3;
#pragma unroll
  for (int m = 1; m < 64; m <<= 1) {
    unsigned t = __shfl_up(run, m);
    if (lane >= m) run += t;
  }
  unsigned excl = run - s3;                   // lane-exclusive prefix
  unsigned ee[4] = {excl, excl + s0, excl + s1, excl + s2};
#pragma unroll
  for (int k = 0; k < 4; ++k)
    if (cbase + k < NCH) C[(size_t)(cbase + k) * NBUCK + b] = ee[k];
  if (lane == 63) gh[b] = (int)run;           // bucket total
}

// ---------------- scan 1563 bucket totals -> offs; threads 0-127 also build vprep ----------------
__global__ __launch_bounds__(1024) void k_scan(const int* __restrict__ gh,
    int* __restrict__ offs, const float* __restrict__ Wupd,
    const float* __restrict__ Wdec, float* __restrict__ vprep) {
  __shared__ int sc[1024];
  int t = threadIdx.x;
  int e0 = (2 * t < NBUCK) ? gh[2 * t] : 0;
  int e1 = (2 * t + 1 < NBUCK) ? gh[2 * t + 1] : 0;
  int pair = e0 + e1;
  sc[t] = pair;
  __syncthreads();
  for (int s = 1; s < 1024; s <<= 1) {
    int a = (t >= s) ? sc[t - s] : 0;
    __syncthreads();
    sc[t] += a;
    __syncthreads();
  }
  int base = sc[t] - pair;
  if (2 * t < NBUCK)     offs[2 * t] = base;
  if (2 * t + 1 < NBUCK) offs[2 * t + 1] = base + e0;
  if (t == 0) offs[NBUCK] = NE;
  // vprep[k] = sum_j W_upd[128+k][j] * W_dec[j]
  if (t < 128) {
    const float* row = Wupd + (size_t)(128 + t) * 128;
    float s = 0.f;
#pragma unroll 8
    for (int j = 0; j < 128; ++j) s = fmaf(row[j], Wdec[j], s);
    vprep[t] = s;
  }
}

// ---------------- single-pass sorted scatter ----------------
// entry u64: (src*64) 23b @0 | local(6b) @23 | ea_bf16(16b) @48
__global__ __launch_bounds__(512) void k_sortscatter(const int* __restrict__ ei,
    const float* __restrict__ ea, const unsigned* __restrict__ C,
    const int* __restrict__ offs, unsigned long long* __restrict__ csr) {
  __shared__ unsigned gbase[NBUCK];
  __shared__ unsigned cnt[NBUCK];
  int tid = threadIdx.x;
  int chunk = blockIdx.x;
  long long base = (long long)chunk * CH;
  int n = (int)(((long long)NE - base < CH) ? ((long long)NE - base) : CH);
  int is64 = detect64(ei, tid);
  for (int i = tid; i < NBUCK; i += 512) {
    gbase[i] = C[(size_t)chunk * NBUCK + i] + (unsigned)offs[i];
    cnt[i] = 0;
  }
  __syncthreads();
  for (int i = tid; i < n; i += 512) {
    int s = gidx(ei, is64, base + i);
    int d = gidx(ei, is64, (long long)NE + base + i);
    unsigned eab = f2bf(ea[base + i]);
    int b = d >> 6;
    unsigned lp = atomicAdd(&cnt[b], 1u);
    unsigned lo = (unsigned)(s << 6) | ((unsigned)(d & 63) << 23);
    csr[gbase[b] + lp] = (unsigned long long)lo | ((unsigned long long)eab << 48);
  }
}

// ---------------- fused: edge min (native f32 LDS atomicMin) + decoder dot + sigmoid ----------------
// Wave-uniform csr processing: loop bounds scalarized so csr loads/decodes go to SALU/SMEM.
__global__ __launch_bounds__(512, 8) void k_msg(const unsigned* __restrict__ mNp,
    const float* __restrict__ Wmsg, const int* __restrict__ offs,
    const unsigned long long* __restrict__ csr, const float* __restrict__ bmsg,
    const float* __restrict__ vprep, const float* __restrict__ hdec,
    const float* __restrict__ bdec, float* __restrict__ out) {
  __shared__ float stf[64 * STP];     // 33.3 KB, padded stride
  int tid = threadIdx.x;
  int b = blockIdx.x;
  for (int i = tid; i < 64 * STP; i += 512) stf[i] = SENT;
  __syncthreads();

  int lane = tid & 63;
  int wv = tid >> 6;                     // 0..7
  int off = offs[b], end = offs[b + 1];
  int cntE = end - off;
  int per = (cntE + 7) >> 3;
  int i0 = off + wv * per;
  int i1 = i0 + per; if (i1 > end) i1 = end;
  // wave-uniform loop bounds -> scalar loads for csr
  int iu = __builtin_amdgcn_readfirstlane(i0);
  int ie = __builtin_amdgcn_readfirstlane(i1);
  float wl0 = Wmsg[128 * 128 + lane];
  float wl1 = Wmsg[128 * 128 + 64 + lane];

#define EDGE_DO(PK, VV) do { \
    int loc_ = (int)(((unsigned)(PK) >> 23) & 0x3Fu); \
    float ea_ = __uint_as_float((unsigned)((PK) >> 32) & 0xFFFF0000u); \
    float a0_ = fmaf(ea_, wl0, __uint_as_float((VV) << 16)); \
    float a1_ = fmaf(ea_, wl1, __uint_as_float((VV) & 0xFFFF0000u)); \
    atomicMin(&stf[loc_ * STP + lane], a0_); \
    atomicMin(&stf[loc_ * STP + 64 + lane], a1_); \
  } while (0)

  int i = iu;
  for (; i + 16 <= ie; i += 16) {
    unsigned long long pk[16];
#pragma unroll
    for (int j = 0; j < 16; ++j) pk[j] = csr[i + j];
    unsigned v[16];
#pragma unroll
    for (int j = 0; j < 16; ++j)
      v[j] = mNp[((unsigned)pk[j] & 0x7FFFFFu) + lane];
#pragma unroll
    for (int j = 0; j < 16; ++j) EDGE_DO(pk[j], v[j]);
  }
  for (; i + 4 <= ie; i += 4) {
    unsigned long long pk[4];
#pragma unroll
    for (int j = 0; j < 4; ++j) pk[j] = csr[i + j];
    unsigned v[4];
#pragma unroll
    for (int j = 0; j < 4; ++j)
      v[j] = mNp[((unsigned)pk[j] & 0x7FFFFFu) + lane];
#pragma unroll
    for (int j = 0; j < 4; ++j) EDGE_DO(pk[j], v[j]);
  }
  for (; i < ie; ++i) {
    unsigned long long pk = csr[i];
    unsigned v = mNp[((unsigned)pk & 0x7FFFFFu) + lane];
    EDGE_DO(pk, v);
  }
#undef EDGE_DO
  __syncthreads();

  // ---- phase 2: out[node] = sigmoid((agg+bmsg).v + hdec + bdec) ----
  float vl0 = vprep[lane], vl1 = vprep[64 + lane];
  float bm0 = bmsg[lane], bm1 = bmsg[64 + lane];
  float bd = *bdec;
#pragma unroll
  for (int q = 0; q < 8; ++q) {
    int loc = (wv << 3) + q;
    float s0 = stf[loc * STP + lane];
    float s1 = stf[loc * STP + 64 + lane];
    float ps = ((s0 < 1.0e30f) ? (s0 + bm0) * vl0 : 0.f)
             + ((s1 < 1.0e30f) ? (s1 + bm1) * vl1 : 0.f);
#pragma unroll
    for (int m = 1; m < 64; m <<= 1) ps += __shfl_xor(ps, m);
    if (lane == 0) {
      int node = (b << 6) + loc;
      if (node < NN)
        out[node] = 1.f / (1.f + expf(-(ps + hdec[node] + bd)));
    }
  }
}

extern "C" void kernel_launch(void* const* d_in, const int* in_sizes, int n_in,
                              void* d_out, int out_size, void* d_ws, size_t ws_size,
                              hipStream_t stream) {
  const float* x    = (const float*)d_in[0];
  const int*   ei   = (const int*)d_in[1];
  const float* ea   = (const float*)d_in[2];
  const float* Wenc = (const float*)d_in[3];
  const float* benc = (const float*)d_in[4];
  const float* Wmsg = (const float*)d_in[5];
  const float* bmsg = (const float*)d_in[6];
  const float* Wupd = (const float*)d_in[7];
  const float* bupd = (const float*)d_in[8];
  const float* Wdec = (const float*)d_in[9];
  const float* bdec = (const float*)d_in[10];
  float* out = (float*)d_out;

  // workspace carve (total ~41 MiB, well below the empirically-safe 65.2 MB)
  char* w = (char*)d_ws;
  auto alloc = [&](size_t bytes) { char* p = w; w += (bytes + 255) & ~(size_t)255; return p; };
  unsigned* mNp        = (unsigned*)alloc((size_t)NN * 64 * 4);             // 25.6 MB
  unsigned long long* csr = (unsigned long long*)alloc((size_t)NE * 8);     // 12.8 MB
  unsigned* C   = (unsigned*)alloc((size_t)NCH * NBUCK * 4);                // 1.23 MB
  float* hdec   = (float*)alloc((size_t)NN * 4);                            // 0.4 MB
  float* vprep  = (float*)alloc(128 * 4);
  int* gh       = (int*)alloc((size_t)NBUCK * 4);
  int* offs     = (int*)alloc((size_t)(NBUCK + 1) * 4);

  k_enc2h<<<ENCB + NCH, 512, 0, stream>>>(x, Wenc, benc, Wmsg, Wupd, bupd, Wdec,
                                          ei, mNp, hdec, C);
  k_colscan<<<(NBUCK + 3) / 4, 256, 0, stream>>>(C, gh);
  k_scan<<<1, 1024, 0, stream>>>(gh, offs, Wupd, Wdec, vprep);
  k_sortscatter<<<NCH, 512, 0, stream>>>(ei, ea, C, offs, csr);
  k_msg<<<NBUCK, 512, 0, stream>>>(mNp, Wmsg, offs, csr, bmsg, vprep, hdec, bdec, out);
}

// Round 11
// 142.037 us; speedup vs baseline: 4.3782x; 1.0282x over previous
//
#include <hip/hip_runtime.h>

#define NN 100000
#define NE 1600000
#define HID 128
#define NBUCK 1563          // ceil(NN/64), 64-node buckets
#define STP 130             // padded LDS stride (f32 words) for min-state
#define SENT 3.0e38f
#define CH 8192             // edges per sort chunk
#define NCH 196             // ceil(NE/CH)
#define ENCB 391            // encoder blocks (256 rows each) in k_enc2h

typedef float f32x4 __attribute__((ext_vector_type(4)));
typedef __bf16 bf16x8 __attribute__((ext_vector_type(8)));
typedef unsigned short u16x8 __attribute__((ext_vector_type(8)));

static __device__ __forceinline__ unsigned short f2bf(float f) {
  union { float f; unsigned u; } v; v.f = f;
  unsigned u = v.u;
  return (unsigned short)((u + 0x7FFFu + ((u >> 16) & 1u)) >> 16);
}

static __device__ __forceinline__ f32x4 mfma_bf16(u16x8 a, u16x8 b, f32x4 c) {
  return __builtin_amdgcn_mfma_f32_16x16x32_bf16(
      __builtin_bit_cast(bf16x8, a), __builtin_bit_cast(bf16x8, b), c, 0, 0, 0);
}

// edge_index may arrive as int32 or int64 (values < 2^31, little-endian).
static __device__ __forceinline__ int gidx(const int* __restrict__ ei, int is64, long long pos) {
  return is64 ? ei[pos * 2] : ei[pos];
}
// inline dtype detection: for int64, hi-words of src[0..63] are all zero
static __device__ __forceinline__ int detect64(const int* __restrict__ ei, int tid) {
  unsigned long long bl = __ballot(ei[2 * (tid & 63) + 1] == 0);
  return (bl == ~0ull) ? 1 : 0;
}

// ---------------- one-time weight prep: padded-bf16 image of Wenc/Wmsg/Wupd_top + vprep ----------------
// Wb[m][j*136+k] = bf16(W_m[k][j]);  vprep[k] = sum_j W_upd[128+k][j] * W_dec[j]
__global__ __launch_bounds__(512) void k_prepw(const float* __restrict__ Wenc,
    const float* __restrict__ Wmsg, const float* __restrict__ Wupd,
    const float* __restrict__ Wdec, unsigned short* __restrict__ Wb,
    float* __restrict__ vprep) {
  int b = blockIdx.x;
  if (b == 96) {
    int t = threadIdx.x;
    if (t < 128) {
      const float* row = Wupd + (size_t)(128 + t) * 128;
      float s = 0.f;
#pragma unroll 8
      for (int j = 0; j < 128; ++j) s = fmaf(row[j], Wdec[j], s);
      vprep[t] = s;
    }
    return;
  }
  int i = b * 512 + threadIdx.x;              // 0..49151
  int m = i >> 14, idx = i & 16383;
  const float* src = (m == 0) ? Wenc : ((m == 1) ? Wmsg : Wupd);
  int k = idx >> 7, j = idx & 127;
  Wb[m * 17408 + j * 136 + k] = f2bf(src[idx]);
}

// ---------------- encoder(+msg proj+upd-top decode) blocks 0..390 | hist blocks 391..586 ----------------
__global__ __launch_bounds__(512) void k_enc2h(const float* __restrict__ x,
    const float* __restrict__ benc, const float* __restrict__ bupd,
    const float* __restrict__ Wdec, const unsigned short* __restrict__ Wb,
    const int* __restrict__ ei,
    unsigned* __restrict__ mNp, float* __restrict__ hdec,
    unsigned* __restrict__ C, int* __restrict__ gh) {
  __shared__ __align__(16) unsigned short Wt3[3 * 17408];   // 104.4 KB
  __shared__ float bshE[128];
  __shared__ float bshU[128];
  __shared__ float wdsh[128];
  __shared__ unsigned short bounce[8][16 * 136];
  int tid = threadIdx.x;

  if (blockIdx.x >= ENCB) {
    // ---------- histogram chunk: write count row + bucket totals ----------
    int chunk = blockIdx.x - ENCB;
    long long base = (long long)chunk * CH;
    int n = (int)(((long long)NE - base < CH) ? ((long long)NE - base) : CH);
    int is64 = detect64(ei, tid);
    unsigned* cnt = (unsigned*)Wt3;      // alias LDS
    for (int i = tid; i < NBUCK; i += 512) cnt[i] = 0;
    __syncthreads();
    for (int i = tid; i < n; i += 512) {
      int d = gidx(ei, is64, (long long)NE + base + i);
      atomicAdd(&cnt[d >> 6], 1u);
    }
    __syncthreads();
    for (int i = tid; i < NBUCK; i += 512) {
      unsigned c = cnt[i];
      C[(size_t)chunk * NBUCK + i] = c;
      if (c) atomicAdd(&gh[i], (int)c);
    }
    return;
  }

  // ---------- encoder path: stage pre-converted bf16 weights (uint4 copies) ----------
  for (int i = tid; i < 6528; i += 512)
    ((uint4*)Wt3)[i] = ((const uint4*)Wb)[i];
  if (tid < 128) { bshE[tid] = benc[tid]; bshU[tid] = bupd[tid]; wdsh[tid] = Wdec[tid]; }
  __syncthreads();
  const unsigned short* WtE = Wt3;
  const unsigned short* WtM = Wt3 + 17408;
  const unsigned short* WtU = Wt3 + 2 * 17408;

  int wave = tid >> 6, lane = tid & 63;
  int l15 = lane & 15, lg = lane >> 4;
  f32x4 zero = {0.f, 0.f, 0.f, 0.f};

  for (int g = 0; g < 2; ++g) {
    int rowBase = blockIdx.x * 256 + g * 128 + wave * 16;
    int nodeA = rowBase + l15; if (nodeA > NN - 1) nodeA = NN - 1;

    // ---- stage 1: h ----
    u16x8 af[4];
#pragma unroll
    for (int kt = 0; kt < 4; ++kt) {
      const float* px = x + (long long)nodeA * HID + kt * 32 + lg * 8;
      f32x4 a0 = *(const f32x4*)px;
      f32x4 a1 = *(const f32x4*)(px + 4);
      u16x8 t;
      t[0] = f2bf(a0[0]); t[1] = f2bf(a0[1]); t[2] = f2bf(a0[2]); t[3] = f2bf(a0[3]);
      t[4] = f2bf(a1[0]); t[5] = f2bf(a1[1]); t[6] = f2bf(a1[2]); t[7] = f2bf(a1[3]);
      af[kt] = t;
    }
    f32x4 acc[8];
#pragma unroll
    for (int nt = 0; nt < 8; ++nt) acc[nt] = zero;
#pragma unroll
    for (int kt = 0; kt < 4; ++kt)
#pragma unroll
      for (int nt = 0; nt < 8; ++nt) {
        u16x8 bfv = *(const u16x8*)&WtE[(nt * 16 + l15) * 136 + kt * 32 + lg * 8];
        acc[nt] = mfma_bf16(af[kt], bfv, acc[nt]);
      }
#pragma unroll
    for (int nt = 0; nt < 8; ++nt) {
      int j = nt * 16 + l15;
      float bj = bshE[j];
#pragma unroll
      for (int r = 0; r < 4; ++r) {
        float v = acc[nt][r] + bj;
        v = v > 0.f ? v : 0.f;
        bounce[wave][(lg * 4 + r) * 136 + j] = f2bf(v);
      }
    }
    u16x8 ha[4];
#pragma unroll
    for (int kt = 0; kt < 4; ++kt)
      ha[kt] = *(const u16x8*)&bounce[wave][l15 * 136 + kt * 32 + lg * 8];
    asm volatile("s_waitcnt lgkmcnt(0)" ::: "memory");
    __builtin_amdgcn_sched_barrier(0);

    // ---- stage 2: mN = h @ W_msg ----
    f32x4 acc2[8];
#pragma unroll
    for (int nt = 0; nt < 8; ++nt) acc2[nt] = zero;
#pragma unroll
    for (int kt = 0; kt < 4; ++kt)
#pragma unroll
      for (int nt = 0; nt < 8; ++nt) {
        u16x8 bfv = *(const u16x8*)&WtM[(nt * 16 + l15) * 136 + kt * 32 + lg * 8];
        acc2[nt] = mfma_bf16(ha[kt], bfv, acc2[nt]);
      }
#pragma unroll
    for (int nt = 0; nt < 8; ++nt) {
      int j = nt * 16 + l15;
#pragma unroll
      for (int r = 0; r < 4; ++r)
        bounce[wave][(lg * 4 + r) * 136 + j] = f2bf(acc2[nt][r]);
    }
    asm volatile("s_waitcnt lgkmcnt(0)" ::: "memory");
    __builtin_amdgcn_sched_barrier(0);
    // permuted store: word l = col l | col(l+64)<<16
#pragma unroll 4
    for (int row = 0; row < 16; ++row) {
      int node = rowBase + row;
      if (node < NN) {
        unsigned lo = bounce[wave][row * 136 + lane];
        unsigned hi = bounce[wave][row * 136 + 64 + lane];
        mNp[(size_t)node * 64 + lane] = lo | (hi << 16);
      }
    }

    // ---- stage 3: hdec = (h @ W_upd_top + b_upd) . W_dec ----
    f32x4 acc3[8];
#pragma unroll
    for (int nt = 0; nt < 8; ++nt) acc3[nt] = zero;
#pragma unroll
    for (int kt = 0; kt < 4; ++kt)
#pragma unroll
      for (int nt = 0; nt < 8; ++nt) {
        u16x8 bfv = *(const u16x8*)&WtU[(nt * 16 + l15) * 136 + kt * 32 + lg * 8];
        acc3[nt] = mfma_bf16(ha[kt], bfv, acc3[nt]);
      }
    float hs0 = 0.f, hs1 = 0.f, hs2 = 0.f, hs3 = 0.f;
#pragma unroll
    for (int nt = 0; nt < 8; ++nt) {
      int j = nt * 16 + l15;
      float bu = bshU[j], wv = wdsh[j];
      hs0 += (acc3[nt][0] + bu) * wv;
      hs1 += (acc3[nt][1] + bu) * wv;
      hs2 += (acc3[nt][2] + bu) * wv;
      hs3 += (acc3[nt][3] + bu) * wv;
    }
#pragma unroll
    for (int m = 1; m < 16; m <<= 1) {
      hs0 += __shfl_xor(hs0, m);
      hs1 += __shfl_xor(hs1, m);
      hs2 += __shfl_xor(hs2, m);
      hs3 += __shfl_xor(hs3, m);
    }
    if (l15 == 0) {
      int n0 = rowBase + lg * 4;
      if (n0 + 3 < NN) {
        float4 st4; st4.x = hs0; st4.y = hs1; st4.z = hs2; st4.w = hs3;
        *(float4*)&hdec[n0] = st4;
      } else {
        if (n0 + 0 < NN) hdec[n0 + 0] = hs0;
        if (n0 + 1 < NN) hdec[n0 + 1] = hs1;
        if (n0 + 2 < NN) hdec[n0 + 2] = hs2;
        if (n0 + 3 < NN) hdec[n0 + 3] = hs3;
      }
    }
  }
}

// ---------------- scan 1563 bucket totals -> offs + gcursor ----------------
__global__ __launch_bounds__(1024) void k_scan(const int* __restrict__ gh,
    int* __restrict__ offs, int* __restrict__ gcursor) {
  __shared__ int sc[1024];
  int t = threadIdx.x;
  int e0 = (2 * t < NBUCK) ? gh[2 * t] : 0;
  int e1 = (2 * t + 1 < NBUCK) ? gh[2 * t + 1] : 0;
  int pair = e0 + e1;
  sc[t] = pair;
  __syncthreads();
  for (int s = 1; s < 1024; s <<= 1) {
    int a = (t >= s) ? sc[t - s] : 0;
    __syncthreads();
    sc[t] += a;
    __syncthreads();
  }
  int base = sc[t] - pair;
  if (2 * t < NBUCK)     { offs[2 * t] = base;          gcursor[2 * t] = base; }
  if (2 * t + 1 < NBUCK) { offs[2 * t + 1] = base + e0; gcursor[2 * t + 1] = base + e0; }
  if (t == 0) offs[NBUCK] = NE;
}

// ---------------- single-pass sorted scatter (claims runs via gcursor; order-free) ----------------
// entry u64: (src*64) 23b @0 | local(6b) @23 | ea_bf16(16b) @48
__global__ __launch_bounds__(512) void k_sortscatter(const int* __restrict__ ei,
    const float* __restrict__ ea, const unsigned* __restrict__ C,
    int* __restrict__ gcursor, unsigned long long* __restrict__ csr) {
  __shared__ unsigned gbase[NBUCK];
  __shared__ unsigned cnt[NBUCK];
  int tid = threadIdx.x;
  int chunk = blockIdx.x;
  long long base = (long long)chunk * CH;
  int n = (int)(((long long)NE - base < CH) ? ((long long)NE - base) : CH);
  int is64 = detect64(ei, tid);
  for (int i = tid; i < NBUCK; i += 512) {
    unsigned c = C[(size_t)chunk * NBUCK + i];
    gbase[i] = c ? (unsigned)atomicAdd(&gcursor[i], (int)c) : 0u;
    cnt[i] = 0;
  }
  __syncthreads();
  for (int i = tid; i < n; i += 512) {
    int s = gidx(ei, is64, base + i);
    int d = gidx(ei, is64, (long long)NE + base + i);
    unsigned eab = f2bf(ea[base + i]);
    int b = d >> 6;
    unsigned lp = atomicAdd(&cnt[b], 1u);
    unsigned lo = (unsigned)(s << 6) | ((unsigned)(d & 63) << 23);
    csr[gbase[b] + lp] = (unsigned long long)lo | ((unsigned long long)eab << 48);
  }
}

// ---------------- fused: edge min (native f32 LDS atomicMin) + decoder dot + sigmoid ----------------
// Wave-uniform csr processing: loop bounds scalarized so csr loads/decodes go to SALU/SMEM.
__global__ __launch_bounds__(512, 8) void k_msg(const unsigned* __restrict__ mNp,
    const float* __restrict__ Wmsg, const int* __restrict__ offs,
    const unsigned long long* __restrict__ csr, const float* __restrict__ bmsg,
    const float* __restrict__ vprep, const float* __restrict__ hdec,
    const float* __restrict__ bdec, float* __restrict__ out) {
  __shared__ float stf[64 * STP];     // 33.3 KB, padded stride
  int tid = threadIdx.x;
  int b = blockIdx.x;
  for (int i = tid; i < 64 * STP; i += 512) stf[i] = SENT;
  __syncthreads();

  int lane = tid & 63;
  int wv = tid >> 6;                     // 0..7
  int off = offs[b], end = offs[b + 1];
  int cntE = end - off;
  int per = (cntE + 7) >> 3;
  int i0 = off + wv * per;
  int i1 = i0 + per; if (i1 > end) i1 = end;
  // wave-uniform loop bounds -> scalar loads for csr
  int iu = __builtin_amdgcn_readfirstlane(i0);
  int ie = __builtin_amdgcn_readfirstlane(i1);
  float wl0 = Wmsg[128 * 128 + lane];
  float wl1 = Wmsg[128 * 128 + 64 + lane];

#define EDGE_DO(PK, VV) do { \
    int loc_ = (int)(((unsigned)(PK) >> 23) & 0x3Fu); \
    float ea_ = __uint_as_float((unsigned)((PK) >> 32) & 0xFFFF0000u); \
    float a0_ = fmaf(ea_, wl0, __uint_as_float((VV) << 16)); \
    float a1_ = fmaf(ea_, wl1, __uint_as_float((VV) & 0xFFFF0000u)); \
    atomicMin(&stf[loc_ * STP + lane], a0_); \
    atomicMin(&stf[loc_ * STP + 64 + lane], a1_); \
  } while (0)

  int i = iu;
  for (; i + 16 <= ie; i += 16) {
    unsigned long long pk[16];
#pragma unroll
    for (int j = 0; j < 16; ++j) pk[j] = csr[i + j];
    unsigned v[16];
#pragma unroll
    for (int j = 0; j < 16; ++j)
      v[j] = mNp[((unsigned)pk[j] & 0x7FFFFFu) + lane];
#pragma unroll
    for (int j = 0; j < 16; ++j) EDGE_DO(pk[j], v[j]);
  }
  for (; i + 4 <= ie; i += 4) {
    unsigned long long pk[4];
#pragma unroll
    for (int j = 0; j < 4; ++j) pk[j] = csr[i + j];
    unsigned v[4];
#pragma unroll
    for (int j = 0; j < 4; ++j)
      v[j] = mNp[((unsigned)pk[j] & 0x7FFFFFu) + lane];
#pragma unroll
    for (int j = 0; j < 4; ++j) EDGE_DO(pk[j], v[j]);
  }
  for (; i < ie; ++i) {
    unsigned long long pk = csr[i];
    unsigned v = mNp[((unsigned)pk & 0x7FFFFFu) + lane];
    EDGE_DO(pk, v);
  }
#undef EDGE_DO
  __syncthreads();

  // ---- phase 2: out[node] = sigmoid((agg+bmsg).v + hdec + bdec) ----
  float vl0 = vprep[lane], vl1 = vprep[64 + lane];
  float bm0 = bmsg[lane], bm1 = bmsg[64 + lane];
  float bd = *bdec;
#pragma unroll
  for (int q = 0; q < 8; ++q) {
    int loc = (wv << 3) + q;
    float s0 = stf[loc * STP + lane];
    float s1 = stf[loc * STP + 64 + lane];
    float ps = ((s0 < 1.0e30f) ? (s0 + bm0) * vl0 : 0.f)
             + ((s1 < 1.0e30f) ? (s1 + bm1) * vl1 : 0.f);
#pragma unroll
    for (int m = 1; m < 64; m <<= 1) ps += __shfl_xor(ps, m);
    if (lane == 0) {
      int node = (b << 6) + loc;
      if (node < NN)
        out[node] = 1.f / (1.f + expf(-(ps + hdec[node] + bd)));
    }
  }
}

extern "C" void kernel_launch(void* const* d_in, const int* in_sizes, int n_in,
                              void* d_out, int out_size, void* d_ws, size_t ws_size,
                              hipStream_t stream) {
  const float* x    = (const float*)d_in[0];
  const int*   ei   = (const int*)d_in[1];
  const float* ea   = (const float*)d_in[2];
  const float* Wenc = (const float*)d_in[3];
  const float* benc = (const float*)d_in[4];
  const float* Wmsg = (const float*)d_in[5];
  const float* bmsg = (const float*)d_in[6];
  const float* Wupd = (const float*)d_in[7];
  const float* bupd = (const float*)d_in[8];
  const float* Wdec = (const float*)d_in[9];
  const float* bdec = (const float*)d_in[10];
  float* out = (float*)d_out;

  // workspace carve (total ~41 MiB, well below the empirically-safe 65.2 MB)
  char* w = (char*)d_ws;
  auto alloc = [&](size_t bytes) { char* p = w; w += (bytes + 255) & ~(size_t)255; return p; };
  unsigned* mNp        = (unsigned*)alloc((size_t)NN * 64 * 4);             // 25.6 MB
  unsigned long long* csr = (unsigned long long*)alloc((size_t)NE * 8);     // 12.8 MB
  unsigned* C   = (unsigned*)alloc((size_t)NCH * NBUCK * 4);                // 1.23 MB
  unsigned short* Wb = (unsigned short*)alloc(3 * 17408 * 2);               // 104 KB
  float* hdec   = (float*)alloc((size_t)NN * 4);                            // 0.4 MB
  float* vprep  = (float*)alloc(128 * 4);
  int* gh       = (int*)alloc((size_t)NBUCK * 4);
  int* offs     = (int*)alloc((size_t)(NBUCK + 1) * 4);
  int* gcursor  = (int*)alloc((size_t)NBUCK * 4);

  hipMemsetAsync(gh, 0, (size_t)NBUCK * 4, stream);
  k_prepw<<<97, 512, 0, stream>>>(Wenc, Wmsg, Wupd, Wdec, Wb, vprep);
  k_enc2h<<<ENCB + NCH, 512, 0, stream>>>(x, benc, bupd, Wdec, Wb, ei, mNp, hdec, C, gh);
  k_scan<<<1, 1024, 0, stream>>>(gh, offs, gcursor);
  k_sortscatter<<<NCH, 512, 0, stream>>>(ei, ea, C, gcursor, csr);
  k_msg<<<NBUCK, 512, 0, stream>>>(mNp, Wmsg, offs, csr, bmsg, vprep, hdec, bdec, out);
}

// Round 12
// 132.489 us; speedup vs baseline: 4.6937x; 1.0721x over previous
//
#include <hip/hip_runtime.h>

#define NN 100000
#define NE 1600000
#define HID 128
#define NBUCK 1563          // ceil(NN/64), 64-node buckets
#define CAP 1280            // csr slots per bucket (Poisson(1024)+8 sigma)
#define STP 130             // padded LDS stride (f32 words) for min-state
#define SENT 3.0e38f
#define CH 8192             // edges per sort chunk
#define NCH 196             // ceil(NE/CH)
#define ENCB 391            // encoder blocks (256 rows each)

typedef float f32x4 __attribute__((ext_vector_type(4)));
typedef __bf16 bf16x8 __attribute__((ext_vector_type(8)));
typedef unsigned short u16x8 __attribute__((ext_vector_type(8)));

static __device__ __forceinline__ unsigned short f2bf(float f) {
  union { float f; unsigned u; } v; v.f = f;
  unsigned u = v.u;
  return (unsigned short)((u + 0x7FFFu + ((u >> 16) & 1u)) >> 16);
}

static __device__ __forceinline__ f32x4 mfma_bf16(u16x8 a, u16x8 b, f32x4 c) {
  return __builtin_amdgcn_mfma_f32_16x16x32_bf16(
      __builtin_bit_cast(bf16x8, a), __builtin_bit_cast(bf16x8, b), c, 0, 0, 0);
}

// edge_index may arrive as int32 or int64 (values < 2^31, little-endian).
static __device__ __forceinline__ int gidx(const int* __restrict__ ei, int is64, long long pos) {
  return is64 ? ei[pos * 2] : ei[pos];
}
// inline dtype detection: for int64, hi-words of src[0..63] are all zero
static __device__ __forceinline__ int detect64(const int* __restrict__ ei, int tid) {
  unsigned long long bl = __ballot(ei[2 * (tid & 63) + 1] == 0);
  return (bl == ~0ull) ? 1 : 0;
}

// ---------------- one-time prep: padded-bf16 weight image + vprep + gcursor init ----------------
// Wb[m][j*136+k] = bf16(W_m[k][j]);  vprep[k] = sum_j W_upd[128+k][j]*W_dec[j];  gcursor[b]=b*CAP
__global__ __launch_bounds__(512) void k_prepw(const float* __restrict__ Wenc,
    const float* __restrict__ Wmsg, const float* __restrict__ Wupd,
    const float* __restrict__ Wdec, unsigned short* __restrict__ Wb,
    float* __restrict__ vprep, int* __restrict__ gcursor) {
  int b = blockIdx.x;
  int t = threadIdx.x;
  if (b == 96) {
    if (t < 128) {
      const float* row = Wupd + (size_t)(128 + t) * 128;
      float s = 0.f;
#pragma unroll 8
      for (int j = 0; j < 128; ++j) s = fmaf(row[j], Wdec[j], s);
      vprep[t] = s;
    }
    for (int i = t; i < NBUCK; i += 512) gcursor[i] = i * CAP;
    return;
  }
  int i = b * 512 + t;                        // 0..49151
  int m = i >> 14, idx = i & 16383;
  const float* src = (m == 0) ? Wenc : ((m == 1) ? Wmsg : Wupd);
  int k = idx >> 7, j = idx & 127;
  Wb[m * 17408 + j * 136 + k] = f2bf(src[idx]);
}

// ---------------- encoder + message projection + update-top decode (pure, 391 blocks) ----------------
__global__ __launch_bounds__(512) void k_enc2(const float* __restrict__ x,
    const float* __restrict__ benc, const float* __restrict__ bupd,
    const float* __restrict__ Wdec, const unsigned short* __restrict__ Wb,
    unsigned* __restrict__ mNp, float* __restrict__ hdec) {
  __shared__ __align__(16) unsigned short Wt3[3 * 17408];   // 104.4 KB
  __shared__ float bshE[128];
  __shared__ float bshU[128];
  __shared__ float wdsh[128];
  __shared__ unsigned short bounce[8][16 * 136];
  int tid = threadIdx.x;

  for (int i = tid; i < 6528; i += 512)
    ((uint4*)Wt3)[i] = ((const uint4*)Wb)[i];
  if (tid < 128) { bshE[tid] = benc[tid]; bshU[tid] = bupd[tid]; wdsh[tid] = Wdec[tid]; }
  __syncthreads();
  const unsigned short* WtE = Wt3;
  const unsigned short* WtM = Wt3 + 17408;
  const unsigned short* WtU = Wt3 + 2 * 17408;

  int wave = tid >> 6, lane = tid & 63;
  int l15 = lane & 15, lg = lane >> 4;
  f32x4 zero = {0.f, 0.f, 0.f, 0.f};

  for (int g = 0; g < 2; ++g) {
    int rowBase = blockIdx.x * 256 + g * 128 + wave * 16;
    int nodeA = rowBase + l15; if (nodeA > NN - 1) nodeA = NN - 1;

    // ---- stage 1: h ----
    u16x8 af[4];
#pragma unroll
    for (int kt = 0; kt < 4; ++kt) {
      const float* px = x + (long long)nodeA * HID + kt * 32 + lg * 8;
      f32x4 a0 = *(const f32x4*)px;
      f32x4 a1 = *(const f32x4*)(px + 4);
      u16x8 t;
      t[0] = f2bf(a0[0]); t[1] = f2bf(a0[1]); t[2] = f2bf(a0[2]); t[3] = f2bf(a0[3]);
      t[4] = f2bf(a1[0]); t[5] = f2bf(a1[1]); t[6] = f2bf(a1[2]); t[7] = f2bf(a1[3]);
      af[kt] = t;
    }
    f32x4 acc[8];
#pragma unroll
    for (int nt = 0; nt < 8; ++nt) acc[nt] = zero;
#pragma unroll
    for (int kt = 0; kt < 4; ++kt)
#pragma unroll
      for (int nt = 0; nt < 8; ++nt) {
        u16x8 bfv = *(const u16x8*)&WtE[(nt * 16 + l15) * 136 + kt * 32 + lg * 8];
        acc[nt] = mfma_bf16(af[kt], bfv, acc[nt]);
      }
#pragma unroll
    for (int nt = 0; nt < 8; ++nt) {
      int j = nt * 16 + l15;
      float bj = bshE[j];
#pragma unroll
      for (int r = 0; r < 4; ++r) {
        float v = acc[nt][r] + bj;
        v = v > 0.f ? v : 0.f;
        bounce[wave][(lg * 4 + r) * 136 + j] = f2bf(v);
      }
    }
    u16x8 ha[4];
#pragma unroll
    for (int kt = 0; kt < 4; ++kt)
      ha[kt] = *(const u16x8*)&bounce[wave][l15 * 136 + kt * 32 + lg * 8];
    asm volatile("s_waitcnt lgkmcnt(0)" ::: "memory");
    __builtin_amdgcn_sched_barrier(0);

    // ---- stage 2: mN = h @ W_msg ----
    f32x4 acc2[8];
#pragma unroll
    for (int nt = 0; nt < 8; ++nt) acc2[nt] = zero;
#pragma unroll
    for (int kt = 0; kt < 4; ++kt)
#pragma unroll
      for (int nt = 0; nt < 8; ++nt) {
        u16x8 bfv = *(const u16x8*)&WtM[(nt * 16 + l15) * 136 + kt * 32 + lg * 8];
        acc2[nt] = mfma_bf16(ha[kt], bfv, acc2[nt]);
      }
#pragma unroll
    for (int nt = 0; nt < 8; ++nt) {
      int j = nt * 16 + l15;
#pragma unroll
      for (int r = 0; r < 4; ++r)
        bounce[wave][(lg * 4 + r) * 136 + j] = f2bf(acc2[nt][r]);
    }
    asm volatile("s_waitcnt lgkmcnt(0)" ::: "memory");
    __builtin_amdgcn_sched_barrier(0);
    // permuted store: word l = col l | col(l+64)<<16
#pragma unroll 4
    for (int row = 0; row < 16; ++row) {
      int node = rowBase + row;
      if (node < NN) {
        unsigned lo = bounce[wave][row * 136 + lane];
        unsigned hi = bounce[wave][row * 136 + 64 + lane];
        mNp[(size_t)node * 64 + lane] = lo | (hi << 16);
      }
    }

    // ---- stage 3: hdec = (h @ W_upd_top + b_upd) . W_dec ----
    f32x4 acc3[8];
#pragma unroll
    for (int nt = 0; nt < 8; ++nt) acc3[nt] = zero;
#pragma unroll
    for (int kt = 0; kt < 4; ++kt)
#pragma unroll
      for (int nt = 0; nt < 8; ++nt) {
        u16x8 bfv = *(const u16x8*)&WtU[(nt * 16 + l15) * 136 + kt * 32 + lg * 8];
        acc3[nt] = mfma_bf16(ha[kt], bfv, acc3[nt]);
      }
    float hs0 = 0.f, hs1 = 0.f, hs2 = 0.f, hs3 = 0.f;
#pragma unroll
    for (int nt = 0; nt < 8; ++nt) {
      int j = nt * 16 + l15;
      float bu = bshU[j], wv = wdsh[j];
      hs0 += (acc3[nt][0] + bu) * wv;
      hs1 += (acc3[nt][1] + bu) * wv;
      hs2 += (acc3[nt][2] + bu) * wv;
      hs3 += (acc3[nt][3] + bu) * wv;
    }
#pragma unroll
    for (int m = 1; m < 16; m <<= 1) {
      hs0 += __shfl_xor(hs0, m);
      hs1 += __shfl_xor(hs1, m);
      hs2 += __shfl_xor(hs2, m);
      hs3 += __shfl_xor(hs3, m);
    }
    if (l15 == 0) {
      int n0 = rowBase + lg * 4;
      if (n0 + 3 < NN) {
        float4 st4; st4.x = hs0; st4.y = hs1; st4.z = hs2; st4.w = hs3;
        *(float4*)&hdec[n0] = st4;
      } else {
        if (n0 + 0 < NN) hdec[n0 + 0] = hs0;
        if (n0 + 1 < NN) hdec[n0 + 1] = hs1;
        if (n0 + 2 < NN) hdec[n0 + 2] = hs2;
        if (n0 + 3 < NN) hdec[n0 + 3] = hs3;
      }
    }
  }
}

// ---------------- single-pass-over-edges sorted scatter into fixed-capacity bucket slots ----------------
// entry u64: (src*64) 23b @0 | local(6b) @23 | ea_bf16(16b) @48
__global__ __launch_bounds__(512) void k_sortscatter(const int* __restrict__ ei,
    const float* __restrict__ ea, int* __restrict__ gcursor,
    unsigned long long* __restrict__ csr) {
  __shared__ unsigned gbase[NBUCK];
  __shared__ unsigned cnt[NBUCK];
  int tid = threadIdx.x;
  int chunk = blockIdx.x;
  long long base = (long long)chunk * CH;
  int n = (int)(((long long)NE - base < CH) ? ((long long)NE - base) : CH);
  int is64 = detect64(ei, tid);
  for (int i = tid; i < NBUCK; i += 512) cnt[i] = 0;
  __syncthreads();
  // pass 1: count this chunk's bucket sizes
  for (int i = tid; i < n; i += 512) {
    int d = gidx(ei, is64, (long long)NE + base + i);
    atomicAdd(&cnt[d >> 6], 1u);
  }
  __syncthreads();
  // claim contiguous runs in each bucket's slot region
  for (int b = tid; b < NBUCK; b += 512) {
    unsigned c = cnt[b];
    gbase[b] = c ? (unsigned)atomicAdd(&gcursor[b], (int)c) : 0u;
  }
  __syncthreads();
  for (int i = tid; i < NBUCK; i += 512) cnt[i] = 0;   // reuse as local cursor
  __syncthreads();
  // pass 2: write entries into the claimed runs
  for (int i = tid; i < n; i += 512) {
    int s = gidx(ei, is64, base + i);
    int d = gidx(ei, is64, (long long)NE + base + i);
    unsigned eab = f2bf(ea[base + i]);
    int b = d >> 6;
    unsigned lp = atomicAdd(&cnt[b], 1u);
    unsigned lo = (unsigned)(s << 6) | ((unsigned)(d & 63) << 23);
    csr[gbase[b] + lp] = (unsigned long long)lo | ((unsigned long long)eab << 48);
  }
}

// ---------------- fused: edge min (native f32 LDS atomicMin) + decoder dot + sigmoid ----------------
// Wave-uniform csr processing: loop bounds scalarized so csr loads/decodes go to SALU/SMEM.
__global__ __launch_bounds__(512, 8) void k_msg(const unsigned* __restrict__ mNp,
    const float* __restrict__ Wmsg, const int* __restrict__ gcursor,
    const unsigned long long* __restrict__ csr, const float* __restrict__ bmsg,
    const float* __restrict__ vprep, const float* __restrict__ hdec,
    const float* __restrict__ bdec, float* __restrict__ out) {
  __shared__ float stf[64 * STP];     // 33.3 KB, padded stride
  int tid = threadIdx.x;
  int b = blockIdx.x;
  for (int i = tid; i < 64 * STP; i += 512) stf[i] = SENT;
  __syncthreads();

  int lane = tid & 63;
  int wv = tid >> 6;                     // 0..7
  int off = b * CAP, end = gcursor[b];
  int cntE = end - off;
  int per = (cntE + 7) >> 3;
  int i0 = off + wv * per;
  int i1 = i0 + per; if (i1 > end) i1 = end;
  // wave-uniform loop bounds -> scalar loads for csr
  int iu = __builtin_amdgcn_readfirstlane(i0);
  int ie = __builtin_amdgcn_readfirstlane(i1);
  float wl0 = Wmsg[128 * 128 + lane];
  float wl1 = Wmsg[128 * 128 + 64 + lane];

#define EDGE_DO(PK, VV) do { \
    int loc_ = (int)(((unsigned)(PK) >> 23) & 0x3Fu); \
    float ea_ = __uint_as_float((unsigned)((PK) >> 32) & 0xFFFF0000u); \
    float a0_ = fmaf(ea_, wl0, __uint_as_float((VV) << 16)); \
    float a1_ = fmaf(ea_, wl1, __uint_as_float((VV) & 0xFFFF0000u)); \
    atomicMin(&stf[loc_ * STP + lane], a0_); \
    atomicMin(&stf[loc_ * STP + 64 + lane], a1_); \
  } while (0)

  int i = iu;
  for (; i + 16 <= ie; i += 16) {
    unsigned long long pk[16];
#pragma unroll
    for (int j = 0; j < 16; ++j) pk[j] = csr[i + j];
    unsigned v[16];
#pragma unroll
    for (int j = 0; j < 16; ++j)
      v[j] = mNp[((unsigned)pk[j] & 0x7FFFFFu) + lane];
#pragma unroll
    for (int j = 0; j < 16; ++j) EDGE_DO(pk[j], v[j]);
  }
  for (; i + 4 <= ie; i += 4) {
    unsigned long long pk[4];
#pragma unroll
    for (int j = 0; j < 4; ++j) pk[j] = csr[i + j];
    unsigned v[4];
#pragma unroll
    for (int j = 0; j < 4; ++j)
      v[j] = mNp[((unsigned)pk[j] & 0x7FFFFFu) + lane];
#pragma unroll
    for (int j = 0; j < 4; ++j) EDGE_DO(pk[j], v[j]);
  }
  for (; i < ie; ++i) {
    unsigned long long pk = csr[i];
    unsigned v = mNp[((unsigned)pk & 0x7FFFFFu) + lane];
    EDGE_DO(pk, v);
  }
#undef EDGE_DO
  __syncthreads();

  // ---- phase 2: out[node] = sigmoid((agg+bmsg).v + hdec + bdec) ----
  float vl0 = vprep[lane], vl1 = vprep[64 + lane];
  float bm0 = bmsg[lane], bm1 = bmsg[64 + lane];
  float bd = *bdec;
#pragma unroll
  for (int q = 0; q < 8; ++q) {
    int loc = (wv << 3) + q;
    float s0 = stf[loc * STP + lane];
    float s1 = stf[loc * STP + 64 + lane];
    float ps = ((s0 < 1.0e30f) ? (s0 + bm0) * vl0 : 0.f)
             + ((s1 < 1.0e30f) ? (s1 + bm1) * vl1 : 0.f);
#pragma unroll
    for (int m = 1; m < 64; m <<= 1) ps += __shfl_xor(ps, m);
    if (lane == 0) {
      int node = (b << 6) + loc;
      if (node < NN)
        out[node] = 1.f / (1.f + expf(-(ps + hdec[node] + bd)));
    }
  }
}

extern "C" void kernel_launch(void* const* d_in, const int* in_sizes, int n_in,
                              void* d_out, int out_size, void* d_ws, size_t ws_size,
                              hipStream_t stream) {
  const float* x    = (const float*)d_in[0];
  const int*   ei   = (const int*)d_in[1];
  const float* ea   = (const float*)d_in[2];
  const float* Wenc = (const float*)d_in[3];
  const float* benc = (const float*)d_in[4];
  const float* Wmsg = (const float*)d_in[5];
  const float* bmsg = (const float*)d_in[6];
  const float* Wupd = (const float*)d_in[7];
  const float* bupd = (const float*)d_in[8];
  const float* Wdec = (const float*)d_in[9];
  const float* bdec = (const float*)d_in[10];
  float* out = (float*)d_out;

  // workspace carve (total ~42.2 MiB, well below the empirically-safe 65.2 MB)
  char* w = (char*)d_ws;
  auto alloc = [&](size_t bytes) { char* p = w; w += (bytes + 255) & ~(size_t)255; return p; };
  unsigned* mNp        = (unsigned*)alloc((size_t)NN * 64 * 4);             // 25.6 MB
  unsigned long long* csr = (unsigned long long*)alloc((size_t)NBUCK * CAP * 8); // 16.0 MB
  unsigned short* Wb = (unsigned short*)alloc(3 * 17408 * 2);               // 104 KB
  float* hdec   = (float*)alloc((size_t)NN * 4);                            // 0.4 MB
  float* vprep  = (float*)alloc(128 * 4);
  int* gcursor  = (int*)alloc((size_t)NBUCK * 4);

  k_prepw<<<97, 512, 0, stream>>>(Wenc, Wmsg, Wupd, Wdec, Wb, vprep, gcursor);
  k_enc2<<<ENCB, 512, 0, stream>>>(x, benc, bupd, Wdec, Wb, mNp, hdec);
  k_sortscatter<<<NCH, 512, 0, stream>>>(ei, ea, gcursor, csr);
  k_msg<<<NBUCK, 512, 0, stream>>>(mNp, Wmsg, gcursor, csr, bmsg, vprep, hdec, bdec, out);
}